// Round 1
// 621.753 us; speedup vs baseline: 1.3855x; 1.3855x over previous
//
#include <hip/hip_runtime.h>
#include <hip/hip_bf16.h>
#include <cstdint>

typedef float f4  __attribute__((ext_vector_type(4)));
typedef short s8v __attribute__((ext_vector_type(8)));   // 8 bf16 (4 VGPRs)
typedef int   i4v __attribute__((ext_vector_type(4)));

#define BHTD 3145728    // B*H*T*D = 2*12*2048*64
#define BTC  3145728
#define NT   2048
#define NC   768
#define NEG  -1e30f
// 0.125 (1/sqrt(64)) * log2(e): folded into Q at the producer so the flash
// kernel's scores are already in log2 domain (exp2 instead of expf, no scale mul)
#define QSCALE 0.18033688f

static __device__ __forceinline__ short bfbits(float f) {
    return __builtin_bit_cast(short, __float2bfloat16(f));
}
static __device__ __forceinline__ float bf2f(short s) {
    return __builtin_bit_cast(float, (int)(((unsigned int)(unsigned short)s) << 16));
}
static __device__ __forceinline__ float exp2fast(float x) {
    return __builtin_amdgcn_exp2f(x);
}
template <int ctrl>
static __device__ __forceinline__ float dppmov(float x) {
    return __builtin_bit_cast(float,
        __builtin_amdgcn_update_dpp(0, __builtin_bit_cast(int, x), ctrl, 0xF, 0xF, true));
}
// reductions over the 16 lanes of a quad (DPP row = 16 lanes)
static __device__ __forceinline__ float red16max(float x) {
    x = fmaxf(x, dppmov<0xB1>(x));    // quad_perm xor1
    x = fmaxf(x, dppmov<0x4E>(x));    // quad_perm xor2
    x = fmaxf(x, dppmov<0x141>(x));   // row_half_mirror (xor4)
    x = fmaxf(x, dppmov<0x140>(x));   // row_mirror      (xor8)
    return x;
}
static __device__ __forceinline__ float red16sum(float x) {
    x += dppmov<0xB1>(x);
    x += dppmov<0x4E>(x);
    x += dppmov<0x141>(x);
    x += dppmov<0x140>(x);
    return x;
}

// ---------------------------------------------------------------------------
// Kernel 1: MFMA QKV projection. nom=x@W^T, mid=m@W^T, rad=r@|W|^T (bf16 in,
// fp32 acc). Outputs bf16: Q,K in [var][part][B,H,T,D]; V in [B,H,D,T]
// (transposed at producer so flash needs no LDS transpose).
// Q (p==0) is pre-scaled by 0.125*log2e so flash works in exp2 domain.
// Block: 64(M)x64(N), 4 waves (16 M-rows each), K-step 32.
// ---------------------------------------------------------------------------
__global__ __launch_bounds__(256) void qkv_proj_mfma(
    const float* __restrict__ x, const float* __restrict__ xl,
    const float* __restrict__ xu, const float* __restrict__ W,
    short* __restrict__ qkvb)
{
    __shared__ short sm[4 * 64 * 40];   // 20 KB staging; epilogue reuses as [64][72]
    short* Ax = sm;
    short* Am = sm + 2560;
    short* Ar = sm + 5120;
    short* Bw = sm + 7680;
    short* Eb = sm;                     // epilogue [64][72] (4608 shorts)

    const int j0 = blockIdx.x * 64;     // N in [0,2304)
    const int n0 = blockIdx.y * 64;     // M in [0,4096)
    const int t  = threadIdx.x;
    const int wv = t >> 6, lane = t & 63, quad = lane >> 4, l16 = lane & 15;
    const int rw = t >> 2, koff = (t & 3) * 8;

    f4 aN[4], aM[4], aR[4];
#pragma unroll
    for (int i = 0; i < 4; i++) { aN[i] = f4{0,0,0,0}; aM[i] = f4{0,0,0,0}; aR[i] = f4{0,0,0,0}; }

    for (int k0 = 0; k0 < NC; k0 += 32) {
        const size_t xo = (size_t)(n0 + rw) * NC + k0 + koff;
        const f4 x0 = *(const f4*)&x[xo],  x1 = *(const f4*)&x[xo + 4];
        const f4 l0 = *(const f4*)&xl[xo], l1 = *(const f4*)&xl[xo + 4];
        const f4 u0 = *(const f4*)&xu[xo], u1 = *(const f4*)&xu[xo + 4];
        const size_t wo = (size_t)(j0 + rw) * NC + k0 + koff;
        const f4 w0 = *(const f4*)&W[wo], w1 = *(const f4*)&W[wo + 4];
        s8v vx, vm, vr, vw;
#pragma unroll
        for (int i = 0; i < 4; i++) {
            vx[i]     = bfbits(x0[i]);              vx[4 + i] = bfbits(x1[i]);
            vm[i]     = bfbits(0.5f * (l0[i] + u0[i])); vm[4 + i] = bfbits(0.5f * (l1[i] + u1[i]));
            vr[i]     = bfbits(0.5f * (u0[i] - l0[i])); vr[4 + i] = bfbits(0.5f * (u1[i] - l1[i]));
            vw[i]     = bfbits(w0[i]);              vw[4 + i] = bfbits(w1[i]);
        }
        __syncthreads();
        *(s8v*)&Ax[rw * 40 + koff] = vx;
        *(s8v*)&Am[rw * 40 + koff] = vm;
        *(s8v*)&Ar[rw * 40 + koff] = vr;
        *(s8v*)&Bw[rw * 40 + koff] = vw;
        __syncthreads();
        const s8v fx = *(const s8v*)&Ax[(wv * 16 + l16) * 40 + quad * 8];
        const s8v fm = *(const s8v*)&Am[(wv * 16 + l16) * 40 + quad * 8];
        const s8v fr = *(const s8v*)&Ar[(wv * 16 + l16) * 40 + quad * 8];
#pragma unroll
        for (int nt = 0; nt < 4; ++nt) {
            const s8v fb = *(const s8v*)&Bw[(nt * 16 + l16) * 40 + quad * 8];
            i4v bi = __builtin_bit_cast(i4v, fb);
#pragma unroll
            for (int i = 0; i < 4; i++) bi[i] &= 0x7fff7fff;
            const s8v fa = __builtin_bit_cast(s8v, bi);
            aN[nt] = __builtin_amdgcn_mfma_f32_16x16x32_bf16(fx, fb, aN[nt], 0, 0, 0);
            aM[nt] = __builtin_amdgcn_mfma_f32_16x16x32_bf16(fm, fb, aM[nt], 0, 0, 0);
            aR[nt] = __builtin_amdgcn_mfma_f32_16x16x32_bf16(fr, fa, aR[nt], 0, 0, 0);
        }
    }

    const int p = j0 / NC, hh = (j0 % NC) >> 6;
    const float osc = (p == 0) ? QSCALE : 1.0f;   // pre-scale Q for exp2-domain flash
    const int cc16 = (t & 3) * 16;
    for (int var = 0; var < 3; ++var) {
        __syncthreads();
#pragma unroll
        for (int nt = 0; nt < 4; ++nt)
#pragma unroll
            for (int r = 0; r < 4; ++r) {
                const float v = (var == 0) ? aN[nt][r]
                              : (var == 1) ? aM[nt][r] - aR[nt][r]
                                           : aM[nt][r] + aR[nt][r];
                Eb[(wv * 16 + quad * 4 + r) * 72 + nt * 16 + l16] = bfbits(v * osc);
            }
        __syncthreads();
        short* dst = qkvb + (size_t)(var * 3 + p) * BHTD;
        if (p < 2) {       // Q,K row-major [B,H,T,D]
            const int token = n0 + rw, b = token >> 11, tt = token & 2047;
            const size_t o = ((size_t)(b * 12 + hh) * NT + tt) * 64 + cc16;
            *(s8v*)&dst[o]     = *(const s8v*)&Eb[rw * 72 + cc16];
            *(s8v*)&dst[o + 8] = *(const s8v*)&Eb[rw * 72 + cc16 + 8];
        } else {           // V transposed [B,H,D,T]
            const int d = rw;
            s8v e0, e1;
#pragma unroll
            for (int i = 0; i < 8; i++) e0[i] = Eb[(cc16 + i) * 72 + d];
#pragma unroll
            for (int i = 0; i < 8; i++) e1[i] = Eb[(cc16 + 8 + i) * 72 + d];
            const int token0 = n0 + cc16, b = token0 >> 11, tt = token0 & 2047;
            const size_t o = ((size_t)(b * 12 + hh) * 64 + d) * NT + tt;
            *(s8v*)&dst[o]     = e0;
            *(s8v*)&dst[o + 8] = e1;
        }
    }
}

// ---------------------------------------------------------------------------
// Kernel 2: MFMA flash, merged nominal + 4 bound branches in one launch.
//   blockIdx.x encodes (qt heavy-first, z): x = (15-qt)*5 + z
//   z==0: sv0 (qn,kn,vn) -> y fp32
//   z>=1: sv=z in 1..4: (q lo/hi, k lo/hi) x {vlo,vhi} -> candLo/candHi bf16
// Block = 128 q-rows, 4 waves x 32 rows (2 m-tiles), K-tile 32.
// Softmax: defer-max (T13) in exp2 domain; li kept as lane-local partials
// (red16sum only in epilogue); rescale path only when row-max grows > 8.
// ---------------------------------------------------------------------------
__global__ __launch_bounds__(256) void flash_mfma(
    const short* __restrict__ qkvb, float* __restrict__ ybuf,
    short* __restrict__ cand)
{
    const int bx = blockIdx.x;             // 0..79: heavy qt first across all z
    const int qt = 15 - bx / 5;
    const int z  = bx % 5;
    const int bh = blockIdx.y;
    const int q0 = qt * 128;
    const int t  = threadIdx.x;
    const int wv = t >> 6, lane = t & 63, quad = lane >> 4, l16 = lane & 15;
    const bool TWO = (z != 0);

    __shared__ short Ks[32 * 72];          // [kpos][d] pad->2-way
    __shared__ short Vs[2][64 * 40];       // [d][kpos] pad->2-way (from global V^T)
    __shared__ short Ps[128 * 40];         // [qrow][kpos]

    int sv, qvi, kvi, v0i, v1i;
    if (TWO) { sv = z; qvi = (sv + 1) >> 1; kvi = 2 - (sv & 1); v0i = 1; v1i = 2; }
    else     { sv = 0; qvi = 0; kvi = 0; v0i = 0; v1i = 0; }

    const size_t hb = (size_t)bh * (NT * 64);
    const short* Qp  = qkvb + (size_t)(qvi * 3 + 0) * BHTD + hb;  // [t][d] (pre-scaled)
    const short* Kp  = qkvb + (size_t)(kvi * 3 + 1) * BHTD + hb;  // [t][d]
    const short* V0p = qkvb + (size_t)(v0i * 3 + 2) * BHTD + hb;  // [d][t] !
    const short* V1p = qkvb + (size_t)(v1i * 3 + 2) * BHTD + hb;

    s8v qf[2][2];
#pragma unroll
    for (int mt = 0; mt < 2; ++mt)
#pragma unroll
        for (int ch = 0; ch < 2; ++ch)
            qf[mt][ch] = *(const s8v*)&Qp[(size_t)(q0 + 32 * wv + 16 * mt + l16) * 64 + ch * 32 + quad * 8];

    float mi[2][4], li[2][4];              // li = LANE-LOCAL partial sums
    f4 acc0[2][4], acc1[2][4];
#pragma unroll
    for (int mt = 0; mt < 2; ++mt)
#pragma unroll
        for (int r = 0; r < 4; ++r) { mi[mt][r] = NEG; li[mt][r] = 0.f; }
#pragma unroll
    for (int mt = 0; mt < 2; ++mt)
#pragma unroll
        for (int i = 0; i < 4; ++i) { acc0[mt][i] = f4{0,0,0,0}; acc1[mt][i] = f4{0,0,0,0}; }

    const int ktn  = 4 * qt + 4;
    const int mykt = 4 * qt + wv + 1;      // last tile this wave's rows need
    const int skr = t >> 3, skc = (t & 7) * 8;   // K stage: 32 x 64
    const int svd = t >> 2, svc = (t & 3) * 8;   // V stage: 64 x 32

    for (int kt = 0; kt < ktn; ++kt) {
        const int k0 = kt * 32;
        __syncthreads();
        *(s8v*)&Ks[skr * 72 + skc]    = *(const s8v*)&Kp[(size_t)(k0 + skr) * 64 + skc];
        *(s8v*)&Vs[0][svd * 40 + svc] = *(const s8v*)&V0p[(size_t)svd * NT + k0 + svc];
        if (TWO)
            *(s8v*)&Vs[1][svd * 40 + svc] = *(const s8v*)&V1p[(size_t)svd * NT + k0 + svc];
        __syncthreads();
        if (kt >= mykt) continue;          // fully-masked for this wave (barrier already done)

        // ---- S = Q K^T (already in log2 domain via Q pre-scale) ----
        f4 s[2][2];
#pragma unroll
        for (int mt = 0; mt < 2; ++mt) { s[mt][0] = f4{0,0,0,0}; s[mt][1] = f4{0,0,0,0}; }
#pragma unroll
        for (int nt = 0; nt < 2; ++nt)
#pragma unroll
            for (int ch = 0; ch < 2; ++ch) {
                const s8v kf = *(const s8v*)&Ks[(nt * 16 + l16) * 72 + ch * 32 + quad * 8];
                s[0][nt] = __builtin_amdgcn_mfma_f32_16x16x32_bf16(qf[0][ch], kf, s[0][nt], 0, 0, 0);
                s[1][nt] = __builtin_amdgcn_mfma_f32_16x16x32_bf16(qf[1][ch], kf, s[1][nt], 0, 0, 0);
            }

        // ---- softmax per m-tile: defer-max fast path ----
#pragma unroll
        for (int mt = 0; mt < 2; ++mt) {
            const int rowb = q0 + 32 * wv + 16 * mt;
            float a0[4], a1[4];
#pragma unroll
            for (int r = 0; r < 4; ++r) { a0[r] = s[mt][0][r]; a1[r] = s[mt][1][r]; }
            if (k0 + 31 > rowb) {
#pragma unroll
                for (int r = 0; r < 4; ++r) {
                    const int row = rowb + quad * 4 + r;
                    if (k0 + l16 > row)      a0[r] = NEG;
                    if (k0 + 16 + l16 > row) a1[r] = NEG;
                }
            }
#pragma unroll
            for (int r = 0; r < 4; ++r) {
                const float c = fmaxf(a0[r], a1[r]);
                if (__any(c > mi[mt][r] + 8.0f)) {     // rare: row max grew — rescale
                    const float mx = red16max(c);
                    const float nm = fmaxf(mi[mt][r], mx);
                    const float al = exp2fast(mi[mt][r] - nm);
                    mi[mt][r] = nm;
                    li[mt][r] *= al;
#pragma unroll
                    for (int dt = 0; dt < 4; ++dt) acc0[mt][dt][r] *= al;
                    if (TWO) {
#pragma unroll
                        for (int dt = 0; dt < 4; ++dt) acc1[mt][dt][r] *= al;
                    }
                }
                a0[r] = exp2fast(a0[r] - mi[mt][r]);   // bounded by 2^8
                a1[r] = exp2fast(a1[r] - mi[mt][r]);
                li[mt][r] += a0[r] + a1[r];            // lane-local partial
                Ps[(32 * wv + 16 * mt + quad * 4 + r) * 40 + l16]      = bfbits(a0[r]);
                Ps[(32 * wv + 16 * mt + quad * 4 + r) * 40 + 16 + l16] = bfbits(a1[r]);
            }
        }
        // ---- O += P V ----
        const s8v pf0 = *(const s8v*)&Ps[(32 * wv + l16) * 40 + quad * 8];
        const s8v pf1 = *(const s8v*)&Ps[(32 * wv + 16 + l16) * 40 + quad * 8];
#pragma unroll
        for (int dt = 0; dt < 4; ++dt) {
            const s8v vf0 = *(const s8v*)&Vs[0][(dt * 16 + l16) * 40 + quad * 8];
            acc0[0][dt] = __builtin_amdgcn_mfma_f32_16x16x32_bf16(pf0, vf0, acc0[0][dt], 0, 0, 0);
            acc0[1][dt] = __builtin_amdgcn_mfma_f32_16x16x32_bf16(pf1, vf0, acc0[1][dt], 0, 0, 0);
            if (TWO) {
                const s8v vf1 = *(const s8v*)&Vs[1][(dt * 16 + l16) * 40 + quad * 8];
                acc1[0][dt] = __builtin_amdgcn_mfma_f32_16x16x32_bf16(pf0, vf1, acc1[0][dt], 0, 0, 0);
                acc1[1][dt] = __builtin_amdgcn_mfma_f32_16x16x32_bf16(pf1, vf1, acc1[1][dt], 0, 0, 0);
            }
        }
    }

#pragma unroll
    for (int mt = 0; mt < 2; ++mt) {
        float inv[4];
#pragma unroll
        for (int r = 0; r < 4; ++r) inv[r] = 1.f / red16sum(li[mt][r]);  // reduce once here
#pragma unroll
        for (int dt = 0; dt < 4; ++dt)
#pragma unroll
            for (int r = 0; r < 4; ++r) {
                const size_t o = hb + (size_t)(q0 + 32 * wv + 16 * mt + quad * 4 + r) * 64 + dt * 16 + l16;
                if (!TWO) {
                    ybuf[o] = acc0[mt][dt][r] * inv[r];
                } else {
                    const float xa = acc0[mt][dt][r] * inv[r];
                    const float xb = acc1[mt][dt][r] * inv[r];
                    cand[(size_t)(sv - 1) * BHTD + o] = bfbits(fminf(xa, xb));
                    cand[(size_t)(3 + sv) * BHTD + o] = bfbits(fmaxf(xa, xb));
                }
            }
    }
}

// ---------------------------------------------------------------------------
// Kernel 3: MFMA output projection. z=0: A=y fp32; z=1: A=min of 4 candLo;
// z=2: A=max of 4 candHi. B=Wp (bf16). out fp32 via LDS re-layout.
// ---------------------------------------------------------------------------
__global__ __launch_bounds__(256) void out_proj_mfma(
    const float* __restrict__ ybuf, const short* __restrict__ cand,
    const float* __restrict__ Wp, float* __restrict__ out)
{
    __shared__ float smf[64 * 68];          // 17.4 KB; staging aliases first 10.2 KB
    short* As = (short*)smf;                // [64][40]
    short* Bs = As + 2560;
    float* Eb = smf;                        // [64][68]

    const int o  = blockIdx.z;
    const int j0 = blockIdx.x * 64, n0 = blockIdx.y * 64;
    const int t  = threadIdx.x;
    const int wv = t >> 6, lane = t & 63, quad = lane >> 4, l16 = lane & 15;
    const int rw = t >> 2, koff = (t & 3) * 8;

    f4 acc[4];
#pragma unroll
    for (int i = 0; i < 4; i++) acc[i] = f4{0,0,0,0};

    const int token = n0 + rw, b = token >> 11, tt = token & 2047;

    for (int k0 = 0; k0 < NC; k0 += 32) {
        const int hh = k0 >> 6, d0 = (k0 & 63) + koff;
        const size_t aoff = ((size_t)(b * 12 + hh) * NT + tt) * 64 + d0;
        s8v av;
        if (o == 0) {
            const f4 y0 = *(const f4*)&ybuf[aoff];
            const f4 y1 = *(const f4*)&ybuf[aoff + 4];
#pragma unroll
            for (int i = 0; i < 4; i++) { av[i] = bfbits(y0[i]); av[4 + i] = bfbits(y1[i]); }
        } else {
            const short* cb = cand + (size_t)(o == 1 ? 0 : 4) * BHTD;
            float v[8];
            {
                const s8v c0 = *(const s8v*)&cb[aoff];
#pragma unroll
                for (int i = 0; i < 8; i++) v[i] = bf2f(c0[i]);
            }
#pragma unroll
            for (int q = 1; q < 4; ++q) {
                const s8v cq = *(const s8v*)&cb[(size_t)q * BHTD + aoff];
                if (o == 1) {
#pragma unroll
                    for (int i = 0; i < 8; i++) v[i] = fminf(v[i], bf2f(cq[i]));
                } else {
#pragma unroll
                    for (int i = 0; i < 8; i++) v[i] = fmaxf(v[i], bf2f(cq[i]));
                }
            }
#pragma unroll
            for (int i = 0; i < 8; i++) av[i] = bfbits(v[i]);
        }
        const size_t wo = (size_t)(j0 + rw) * NC + k0 + koff;
        const f4 w0 = *(const f4*)&Wp[wo], w1 = *(const f4*)&Wp[wo + 4];
        s8v bv;
#pragma unroll
        for (int i = 0; i < 4; i++) { bv[i] = bfbits(w0[i]); bv[4 + i] = bfbits(w1[i]); }
        __syncthreads();
        *(s8v*)&As[rw * 40 + koff] = av;
        *(s8v*)&Bs[rw * 40 + koff] = bv;
        __syncthreads();
        const s8v af = *(const s8v*)&As[(wv * 16 + l16) * 40 + quad * 8];
#pragma unroll
        for (int nt = 0; nt < 4; ++nt) {
            const s8v bf = *(const s8v*)&Bs[(nt * 16 + l16) * 40 + quad * 8];
            acc[nt] = __builtin_amdgcn_mfma_f32_16x16x32_bf16(af, bf, acc[nt], 0, 0, 0);
        }
    }
    __syncthreads();
#pragma unroll
    for (int nt = 0; nt < 4; ++nt)
#pragma unroll
        for (int r = 0; r < 4; ++r)
            Eb[(wv * 16 + quad * 4 + r) * 68 + nt * 16 + l16] = acc[nt][r];
    __syncthreads();
    const int cc = (t & 3) * 16;
#pragma unroll
    for (int i = 0; i < 4; ++i) {
        const f4 vo = *(const f4*)&Eb[rw * 68 + cc + 4 * i];
        *(f4*)&out[(size_t)o * BTC + (size_t)(n0 + rw) * NC + j0 + cc + 4 * i] = vo;
    }
}

extern "C" void kernel_launch(void* const* d_in, const int* in_sizes, int n_in,
                              void* d_out, int out_size, void* d_ws, size_t ws_size,
                              hipStream_t stream)
{
    const float* x  = (const float*)d_in[0];
    const float* xl = (const float*)d_in[1];
    const float* xu = (const float*)d_in[2];
    const float* Wa = (const float*)d_in[3];
    const float* Wp = (const float*)d_in[4];
    float* out = (float*)d_out;

    short* qkvb = (short*)d_ws;                       // 9*BHTD bf16  = 56.6 MB
    float* ybuf = (float*)(qkvb + (size_t)9 * BHTD);  // 1*BHTD f32   = 12.6 MB
    short* cand = (short*)(ybuf + (size_t)BHTD);      // 8*BHTD bf16  = 50.3 MB

    qkv_proj_mfma<<<dim3(36, 64),  256, 0, stream>>>(x, xl, xu, Wa, qkvb);
    flash_mfma   <<<dim3(80, 24),  256, 0, stream>>>(qkvb, ybuf, cand);
    out_proj_mfma<<<dim3(12, 64, 3), 256, 0, stream>>>(ybuf, cand, Wp, out);
}

// Round 2
// 578.752 us; speedup vs baseline: 1.4884x; 1.0743x over previous
//
#include <hip/hip_runtime.h>
#include <hip/hip_bf16.h>
#include <cstdint>

typedef float f4  __attribute__((ext_vector_type(4)));
typedef short s8v __attribute__((ext_vector_type(8)));   // 8 bf16 (4 VGPRs)
typedef int   i4v __attribute__((ext_vector_type(4)));

#define BHTD 3145728    // B*H*T*D = 2*12*2048*64
#define BTC  3145728
#define NT   2048
#define NC   768
#define NEG  -1e30f
// 0.125 (1/sqrt(64)) * log2(e): folded into Q at the producer so the flash
// kernel's scores are already in log2 domain (exp2 instead of expf, no scale mul)
#define QSCALE 0.18033688f

static __device__ __forceinline__ short bfbits(float f) {
    return __builtin_bit_cast(short, __float2bfloat16(f));
}
static __device__ __forceinline__ float bf2f(short s) {
    return __builtin_bit_cast(float, (int)(((unsigned int)(unsigned short)s) << 16));
}
static __device__ __forceinline__ float exp2fast(float x) {
    return __builtin_amdgcn_exp2f(x);
}
template <int ctrl>
static __device__ __forceinline__ float dppmov(float x) {
    return __builtin_bit_cast(float,
        __builtin_amdgcn_update_dpp(0, __builtin_bit_cast(int, x), ctrl, 0xF, 0xF, true));
}
// reductions over the 16 lanes of a quad (DPP row = 16 lanes)
static __device__ __forceinline__ float red16max(float x) {
    x = fmaxf(x, dppmov<0xB1>(x));    // quad_perm xor1
    x = fmaxf(x, dppmov<0x4E>(x));    // quad_perm xor2
    x = fmaxf(x, dppmov<0x141>(x));   // row_half_mirror (xor4)
    x = fmaxf(x, dppmov<0x140>(x));   // row_mirror      (xor8)
    return x;
}
static __device__ __forceinline__ float red16sum(float x) {
    x += dppmov<0xB1>(x);
    x += dppmov<0x4E>(x);
    x += dppmov<0x141>(x);
    x += dppmov<0x140>(x);
    return x;
}

// ---------------------------------------------------------------------------
// Kernel 1: MFMA QKV projection. nom=x@W^T, mid=m@W^T, rad=r@|W|^T (bf16 in,
// fp32 acc). Outputs bf16: Q,K in [var][part][B,H,T,D]; V in [B,H,D,T]
// (transposed at producer so flash needs no LDS transpose).
// Q (p==0) is pre-scaled by 0.125*log2e so flash works in exp2 domain.
// T14 async-stage: tile t+1 global loads issued under tile-t MFMA; only
// reg->LDS writes sit between the barriers.
// Block: 64(M)x64(N), 4 waves (16 M-rows each), K-step 32.
// ---------------------------------------------------------------------------
__global__ __launch_bounds__(256) void qkv_proj_mfma(
    const float* __restrict__ x, const float* __restrict__ xl,
    const float* __restrict__ xu, const float* __restrict__ W,
    short* __restrict__ qkvb)
{
    __shared__ short sm[4 * 64 * 40];   // 20 KB staging; epilogue reuses as [64][72]
    short* Ax = sm;
    short* Am = sm + 2560;
    short* Ar = sm + 5120;
    short* Bw = sm + 7680;
    short* Eb = sm;                     // epilogue [64][72] (4608 shorts)

    const int j0 = blockIdx.x * 64;     // N in [0,2304)
    const int n0 = blockIdx.y * 64;     // M in [0,4096)
    const int t  = threadIdx.x;
    const int wv = t >> 6, lane = t & 63, quad = lane >> 4, l16 = lane & 15;
    const int rw = t >> 2, koff = (t & 3) * 8;

    f4 aN[4], aM[4], aR[4];
#pragma unroll
    for (int i = 0; i < 4; i++) { aN[i] = f4{0,0,0,0}; aM[i] = f4{0,0,0,0}; aR[i] = f4{0,0,0,0}; }

    const size_t xbase = (size_t)(n0 + rw) * NC + koff;
    const size_t wbase = (size_t)(j0 + rw) * NC + koff;

    f4 rx0, rx1, rl0, rl1, ru0, ru1, rw0, rw1;
    rx0 = *(const f4*)&x[xbase];      rx1 = *(const f4*)&x[xbase + 4];
    rl0 = *(const f4*)&xl[xbase];     rl1 = *(const f4*)&xl[xbase + 4];
    ru0 = *(const f4*)&xu[xbase];     ru1 = *(const f4*)&xu[xbase + 4];
    rw0 = *(const f4*)&W[wbase];      rw1 = *(const f4*)&W[wbase + 4];

    for (int k0 = 0; k0 < NC; k0 += 32) {
        // convert current tile (register-only; runs before the LDS is free)
        s8v vx, vm, vr, vw;
#pragma unroll
        for (int i = 0; i < 4; i++) {
            vx[i]     = bfbits(rx0[i]);                  vx[4 + i] = bfbits(rx1[i]);
            vm[i]     = bfbits(0.5f * (rl0[i] + ru0[i])); vm[4 + i] = bfbits(0.5f * (rl1[i] + ru1[i]));
            vr[i]     = bfbits(0.5f * (ru0[i] - rl0[i])); vr[4 + i] = bfbits(0.5f * (ru1[i] - rl1[i]));
            vw[i]     = bfbits(rw0[i]);                  vw[4 + i] = bfbits(rw1[i]);
        }
        __syncthreads();
        *(s8v*)&Ax[rw * 40 + koff] = vx;
        *(s8v*)&Am[rw * 40 + koff] = vm;
        *(s8v*)&Ar[rw * 40 + koff] = vr;
        *(s8v*)&Bw[rw * 40 + koff] = vw;
        __syncthreads();
        // prefetch tile k0+32 (latency hides under MFMA below)
        if (k0 + 32 < NC) {
            const size_t xo = xbase + k0 + 32, wo = wbase + k0 + 32;
            rx0 = *(const f4*)&x[xo];    rx1 = *(const f4*)&x[xo + 4];
            rl0 = *(const f4*)&xl[xo];   rl1 = *(const f4*)&xl[xo + 4];
            ru0 = *(const f4*)&xu[xo];   ru1 = *(const f4*)&xu[xo + 4];
            rw0 = *(const f4*)&W[wo];    rw1 = *(const f4*)&W[wo + 4];
        }
        const s8v fx = *(const s8v*)&Ax[(wv * 16 + l16) * 40 + quad * 8];
        const s8v fm = *(const s8v*)&Am[(wv * 16 + l16) * 40 + quad * 8];
        const s8v fr = *(const s8v*)&Ar[(wv * 16 + l16) * 40 + quad * 8];
#pragma unroll
        for (int nt = 0; nt < 4; ++nt) {
            const s8v fb = *(const s8v*)&Bw[(nt * 16 + l16) * 40 + quad * 8];
            i4v bi = __builtin_bit_cast(i4v, fb);
#pragma unroll
            for (int i = 0; i < 4; i++) bi[i] &= 0x7fff7fff;
            const s8v fa = __builtin_bit_cast(s8v, bi);
            aN[nt] = __builtin_amdgcn_mfma_f32_16x16x32_bf16(fx, fb, aN[nt], 0, 0, 0);
            aM[nt] = __builtin_amdgcn_mfma_f32_16x16x32_bf16(fm, fb, aM[nt], 0, 0, 0);
            aR[nt] = __builtin_amdgcn_mfma_f32_16x16x32_bf16(fr, fa, aR[nt], 0, 0, 0);
        }
    }

    const int p = j0 / NC, hh = (j0 % NC) >> 6;
    const float osc = (p == 0) ? QSCALE : 1.0f;   // pre-scale Q for exp2-domain flash
    const int cc16 = (t & 3) * 16;
    for (int var = 0; var < 3; ++var) {
        __syncthreads();
#pragma unroll
        for (int nt = 0; nt < 4; ++nt)
#pragma unroll
            for (int r = 0; r < 4; ++r) {
                const float v = (var == 0) ? aN[nt][r]
                              : (var == 1) ? aM[nt][r] - aR[nt][r]
                                           : aM[nt][r] + aR[nt][r];
                Eb[(wv * 16 + quad * 4 + r) * 72 + nt * 16 + l16] = bfbits(v * osc);
            }
        __syncthreads();
        short* dst = qkvb + (size_t)(var * 3 + p) * BHTD;
        if (p < 2) {       // Q,K row-major [B,H,T,D]
            const int token = n0 + rw, b = token >> 11, tt = token & 2047;
            const size_t o = ((size_t)(b * 12 + hh) * NT + tt) * 64 + cc16;
            *(s8v*)&dst[o]     = *(const s8v*)&Eb[rw * 72 + cc16];
            *(s8v*)&dst[o + 8] = *(const s8v*)&Eb[rw * 72 + cc16 + 8];
        } else {           // V transposed [B,H,D,T]
            const int d = rw;
            s8v e0, e1;
#pragma unroll
            for (int i = 0; i < 8; i++) e0[i] = Eb[(cc16 + i) * 72 + d];
#pragma unroll
            for (int i = 0; i < 8; i++) e1[i] = Eb[(cc16 + 8 + i) * 72 + d];
            const int token0 = n0 + cc16, b = token0 >> 11, tt = token0 & 2047;
            const size_t o = ((size_t)(b * 12 + hh) * 64 + d) * NT + tt;
            *(s8v*)&dst[o]     = e0;
            *(s8v*)&dst[o + 8] = e1;
        }
    }
}

// ---------------------------------------------------------------------------
// Kernel 2: MFMA flash, merged nominal + 4 bound branches in one launch.
//   blockIdx.x encodes (qt heavy-first, z): x = (15-qt)*5 + z
//   z==0: sv0 (qn,kn,vn) -> y fp32
//   z>=1: sv=z in 1..4: (q lo/hi, k lo/hi) x {vlo,vhi} -> candLo/candHi bf16
// Block = 128 q-rows, 4 waves x 32 rows (2 m-tiles), K-tile 32.
// Softmax: defer-max (T13) in exp2 domain; li lane-local partials.
// T14 async-stage: next K/V tile loaded to regs under current compute;
// only ds_writes sit between the barriers.
// ---------------------------------------------------------------------------
__global__ __launch_bounds__(256) void flash_mfma(
    const short* __restrict__ qkvb, float* __restrict__ ybuf,
    short* __restrict__ cand)
{
    const int bx = blockIdx.x;             // 0..79: heavy qt first across all z
    const int qt = 15 - bx / 5;
    const int z  = bx % 5;
    const int bh = blockIdx.y;
    const int q0 = qt * 128;
    const int t  = threadIdx.x;
    const int wv = t >> 6, lane = t & 63, quad = lane >> 4, l16 = lane & 15;
    const bool TWO = (z != 0);

    __shared__ short Ks[32 * 72];          // [kpos][d] pad->2-way
    __shared__ short Vs[2][64 * 40];       // [d][kpos] pad->2-way (from global V^T)
    __shared__ short Ps[128 * 40];         // [qrow][kpos]

    int sv, qvi, kvi, v0i, v1i;
    if (TWO) { sv = z; qvi = (sv + 1) >> 1; kvi = 2 - (sv & 1); v0i = 1; v1i = 2; }
    else     { sv = 0; qvi = 0; kvi = 0; v0i = 0; v1i = 0; }

    const size_t hb = (size_t)bh * (NT * 64);
    const short* Qp  = qkvb + (size_t)(qvi * 3 + 0) * BHTD + hb;  // [t][d] (pre-scaled)
    const short* Kp  = qkvb + (size_t)(kvi * 3 + 1) * BHTD + hb;  // [t][d]
    const short* V0p = qkvb + (size_t)(v0i * 3 + 2) * BHTD + hb;  // [d][t] !
    const short* V1p = qkvb + (size_t)(v1i * 3 + 2) * BHTD + hb;

    s8v qf[2][2];
#pragma unroll
    for (int mt = 0; mt < 2; ++mt)
#pragma unroll
        for (int ch = 0; ch < 2; ++ch)
            qf[mt][ch] = *(const s8v*)&Qp[(size_t)(q0 + 32 * wv + 16 * mt + l16) * 64 + ch * 32 + quad * 8];

    float mi[2][4], li[2][4];              // li = LANE-LOCAL partial sums
    f4 acc0[2][4], acc1[2][4];
#pragma unroll
    for (int mt = 0; mt < 2; ++mt)
#pragma unroll
        for (int r = 0; r < 4; ++r) { mi[mt][r] = NEG; li[mt][r] = 0.f; }
#pragma unroll
    for (int mt = 0; mt < 2; ++mt)
#pragma unroll
        for (int i = 0; i < 4; ++i) { acc0[mt][i] = f4{0,0,0,0}; acc1[mt][i] = f4{0,0,0,0}; }

    const int ktn  = 4 * qt + 4;
    const int mykt = 4 * qt + wv + 1;      // last tile this wave's rows need
    const int skr = t >> 3, skc = (t & 7) * 8;   // K stage: 32 x 64
    const int svd = t >> 2, svc = (t & 3) * 8;   // V stage: 64 x 32

    // prologue: tile 0 into staging regs
    s8v rK, rV0, rV1;
    rK  = *(const s8v*)&Kp[(size_t)skr * 64 + skc];
    rV0 = *(const s8v*)&V0p[(size_t)svd * NT + svc];
    if (TWO) rV1 = *(const s8v*)&V1p[(size_t)svd * NT + svc];

    for (int kt = 0; kt < ktn; ++kt) {
        const int k0 = kt * 32;
        __syncthreads();
        *(s8v*)&Ks[skr * 72 + skc]    = rK;
        *(s8v*)&Vs[0][svd * 40 + svc] = rV0;
        if (TWO)
            *(s8v*)&Vs[1][svd * 40 + svc] = rV1;
        __syncthreads();
        // prefetch tile kt+1 (latency hides under compute below)
        if (kt + 1 < ktn) {
            const int k1 = k0 + 32;
            rK  = *(const s8v*)&Kp[(size_t)(k1 + skr) * 64 + skc];
            rV0 = *(const s8v*)&V0p[(size_t)svd * NT + k1 + svc];
            if (TWO) rV1 = *(const s8v*)&V1p[(size_t)svd * NT + k1 + svc];
        }
        if (kt >= mykt) continue;          // fully-masked for this wave (barrier already done)

        // ---- S = Q K^T (already in log2 domain via Q pre-scale) ----
        f4 s[2][2];
#pragma unroll
        for (int mt = 0; mt < 2; ++mt) { s[mt][0] = f4{0,0,0,0}; s[mt][1] = f4{0,0,0,0}; }
#pragma unroll
        for (int nt = 0; nt < 2; ++nt)
#pragma unroll
            for (int ch = 0; ch < 2; ++ch) {
                const s8v kf = *(const s8v*)&Ks[(nt * 16 + l16) * 72 + ch * 32 + quad * 8];
                s[0][nt] = __builtin_amdgcn_mfma_f32_16x16x32_bf16(qf[0][ch], kf, s[0][nt], 0, 0, 0);
                s[1][nt] = __builtin_amdgcn_mfma_f32_16x16x32_bf16(qf[1][ch], kf, s[1][nt], 0, 0, 0);
            }

        // ---- softmax per m-tile: defer-max fast path ----
#pragma unroll
        for (int mt = 0; mt < 2; ++mt) {
            const int rowb = q0 + 32 * wv + 16 * mt;
            float a0[4], a1[4];
#pragma unroll
            for (int r = 0; r < 4; ++r) { a0[r] = s[mt][0][r]; a1[r] = s[mt][1][r]; }
            if (k0 + 31 > rowb) {
#pragma unroll
                for (int r = 0; r < 4; ++r) {
                    const int row = rowb + quad * 4 + r;
                    if (k0 + l16 > row)      a0[r] = NEG;
                    if (k0 + 16 + l16 > row) a1[r] = NEG;
                }
            }
#pragma unroll
            for (int r = 0; r < 4; ++r) {
                const float c = fmaxf(a0[r], a1[r]);
                if (__any(c > mi[mt][r] + 8.0f)) {     // rare: row max grew — rescale
                    const float mx = red16max(c);
                    const float nm = fmaxf(mi[mt][r], mx);
                    const float al = exp2fast(mi[mt][r] - nm);
                    mi[mt][r] = nm;
                    li[mt][r] *= al;
#pragma unroll
                    for (int dt = 0; dt < 4; ++dt) acc0[mt][dt][r] *= al;
                    if (TWO) {
#pragma unroll
                        for (int dt = 0; dt < 4; ++dt) acc1[mt][dt][r] *= al;
                    }
                }
                a0[r] = exp2fast(a0[r] - mi[mt][r]);   // bounded by 2^8
                a1[r] = exp2fast(a1[r] - mi[mt][r]);
                li[mt][r] += a0[r] + a1[r];            // lane-local partial
                Ps[(32 * wv + 16 * mt + quad * 4 + r) * 40 + l16]      = bfbits(a0[r]);
                Ps[(32 * wv + 16 * mt + quad * 4 + r) * 40 + 16 + l16] = bfbits(a1[r]);
            }
        }
        // ---- O += P V ----
        const s8v pf0 = *(const s8v*)&Ps[(32 * wv + l16) * 40 + quad * 8];
        const s8v pf1 = *(const s8v*)&Ps[(32 * wv + 16 + l16) * 40 + quad * 8];
#pragma unroll
        for (int dt = 0; dt < 4; ++dt) {
            const s8v vf0 = *(const s8v*)&Vs[0][(dt * 16 + l16) * 40 + quad * 8];
            acc0[0][dt] = __builtin_amdgcn_mfma_f32_16x16x32_bf16(pf0, vf0, acc0[0][dt], 0, 0, 0);
            acc0[1][dt] = __builtin_amdgcn_mfma_f32_16x16x32_bf16(pf1, vf0, acc0[1][dt], 0, 0, 0);
            if (TWO) {
                const s8v vf1 = *(const s8v*)&Vs[1][(dt * 16 + l16) * 40 + quad * 8];
                acc1[0][dt] = __builtin_amdgcn_mfma_f32_16x16x32_bf16(pf0, vf1, acc1[0][dt], 0, 0, 0);
                acc1[1][dt] = __builtin_amdgcn_mfma_f32_16x16x32_bf16(pf1, vf1, acc1[1][dt], 0, 0, 0);
            }
        }
    }

#pragma unroll
    for (int mt = 0; mt < 2; ++mt) {
        float inv[4];
#pragma unroll
        for (int r = 0; r < 4; ++r) inv[r] = 1.f / red16sum(li[mt][r]);  // reduce once here
#pragma unroll
        for (int dt = 0; dt < 4; ++dt)
#pragma unroll
            for (int r = 0; r < 4; ++r) {
                const size_t o = hb + (size_t)(q0 + 32 * wv + 16 * mt + quad * 4 + r) * 64 + dt * 16 + l16;
                if (!TWO) {
                    ybuf[o] = acc0[mt][dt][r] * inv[r];
                } else {
                    const float xa = acc0[mt][dt][r] * inv[r];
                    const float xb = acc1[mt][dt][r] * inv[r];
                    cand[(size_t)(sv - 1) * BHTD + o] = bfbits(fminf(xa, xb));
                    cand[(size_t)(3 + sv) * BHTD + o] = bfbits(fmaxf(xa, xb));
                }
            }
    }
}

// ---------------------------------------------------------------------------
// Kernel 3: MFMA output projection. z=0: A=y fp32; z=1: A=min of 4 candLo;
// z=2: A=max of 4 candHi. B=Wp (bf16). out fp32 via LDS re-layout.
// T14 async-stage: next tile's A/W loads issued under current MFMA.
// ---------------------------------------------------------------------------
__global__ __launch_bounds__(256) void out_proj_mfma(
    const float* __restrict__ ybuf, const short* __restrict__ cand,
    const float* __restrict__ Wp, float* __restrict__ out)
{
    __shared__ float smf[64 * 68];          // 17.4 KB; staging aliases first 10.2 KB
    short* As = (short*)smf;                // [64][40]
    short* Bs = As + 2560;
    float* Eb = smf;                        // [64][68]

    const int o  = blockIdx.z;
    const int j0 = blockIdx.x * 64, n0 = blockIdx.y * 64;
    const int t  = threadIdx.x;
    const int wv = t >> 6, lane = t & 63, quad = lane >> 4, l16 = lane & 15;
    const int rw = t >> 2, koff = (t & 3) * 8;

    f4 acc[4];
#pragma unroll
    for (int i = 0; i < 4; i++) acc[i] = f4{0,0,0,0};

    const int token = n0 + rw, b = token >> 11, tt = token & 2047;
    const size_t wbase = (size_t)(j0 + rw) * NC + koff;
    const short* cb = cand + (size_t)(o == 1 ? 0 : 4) * BHTD;

    // prologue: tile 0 raw loads
    f4 ry0, ry1, rw0, rw1;
    s8v rc0, rc1, rc2, rc3;
    {
        const int hh = 0, d0 = koff;
        const size_t aoff = ((size_t)(b * 12 + hh) * NT + tt) * 64 + d0;
        if (o == 0) {
            ry0 = *(const f4*)&ybuf[aoff];
            ry1 = *(const f4*)&ybuf[aoff + 4];
        } else {
            rc0 = *(const s8v*)&cb[aoff];
            rc1 = *(const s8v*)&cb[(size_t)1 * BHTD + aoff];
            rc2 = *(const s8v*)&cb[(size_t)2 * BHTD + aoff];
            rc3 = *(const s8v*)&cb[(size_t)3 * BHTD + aoff];
        }
        rw0 = *(const f4*)&Wp[wbase];
        rw1 = *(const f4*)&Wp[wbase + 4];
    }

    for (int k0 = 0; k0 < NC; k0 += 32) {
        // convert current tile (register-only)
        s8v av, bv;
        if (o == 0) {
#pragma unroll
            for (int i = 0; i < 4; i++) { av[i] = bfbits(ry0[i]); av[4 + i] = bfbits(ry1[i]); }
        } else {
            float v[8];
#pragma unroll
            for (int i = 0; i < 8; i++) v[i] = bf2f(rc0[i]);
            if (o == 1) {
#pragma unroll
                for (int i = 0; i < 8; i++) v[i] = fminf(v[i], bf2f(rc1[i]));
#pragma unroll
                for (int i = 0; i < 8; i++) v[i] = fminf(v[i], bf2f(rc2[i]));
#pragma unroll
                for (int i = 0; i < 8; i++) v[i] = fminf(v[i], bf2f(rc3[i]));
            } else {
#pragma unroll
                for (int i = 0; i < 8; i++) v[i] = fmaxf(v[i], bf2f(rc1[i]));
#pragma unroll
                for (int i = 0; i < 8; i++) v[i] = fmaxf(v[i], bf2f(rc2[i]));
#pragma unroll
                for (int i = 0; i < 8; i++) v[i] = fmaxf(v[i], bf2f(rc3[i]));
            }
#pragma unroll
            for (int i = 0; i < 8; i++) av[i] = bfbits(v[i]);
        }
#pragma unroll
        for (int i = 0; i < 4; i++) { bv[i] = bfbits(rw0[i]); bv[4 + i] = bfbits(rw1[i]); }

        __syncthreads();
        *(s8v*)&As[rw * 40 + koff] = av;
        *(s8v*)&Bs[rw * 40 + koff] = bv;
        __syncthreads();
        // prefetch tile k0+32
        if (k0 + 32 < NC) {
            const int k1 = k0 + 32;
            const int hh = k1 >> 6, d0 = (k1 & 63) + koff;
            const size_t aoff = ((size_t)(b * 12 + hh) * NT + tt) * 64 + d0;
            if (o == 0) {
                ry0 = *(const f4*)&ybuf[aoff];
                ry1 = *(const f4*)&ybuf[aoff + 4];
            } else {
                rc0 = *(const s8v*)&cb[aoff];
                rc1 = *(const s8v*)&cb[(size_t)1 * BHTD + aoff];
                rc2 = *(const s8v*)&cb[(size_t)2 * BHTD + aoff];
                rc3 = *(const s8v*)&cb[(size_t)3 * BHTD + aoff];
            }
            const size_t wo = wbase + k1;
            rw0 = *(const f4*)&Wp[wo];
            rw1 = *(const f4*)&Wp[wo + 4];
        }
        const s8v af = *(const s8v*)&As[(wv * 16 + l16) * 40 + quad * 8];
#pragma unroll
        for (int nt = 0; nt < 4; ++nt) {
            const s8v bf = *(const s8v*)&Bs[(nt * 16 + l16) * 40 + quad * 8];
            acc[nt] = __builtin_amdgcn_mfma_f32_16x16x32_bf16(af, bf, acc[nt], 0, 0, 0);
        }
    }
    __syncthreads();
#pragma unroll
    for (int nt = 0; nt < 4; ++nt)
#pragma unroll
        for (int r = 0; r < 4; ++r)
            Eb[(wv * 16 + quad * 4 + r) * 68 + nt * 16 + l16] = acc[nt][r];
    __syncthreads();
    const int cc = (t & 3) * 16;
#pragma unroll
    for (int i = 0; i < 4; ++i) {
        const f4 vo = *(const f4*)&Eb[rw * 68 + cc + 4 * i];
        *(f4*)&out[(size_t)o * BTC + (size_t)(n0 + rw) * NC + j0 + cc + 4 * i] = vo;
    }
}

extern "C" void kernel_launch(void* const* d_in, const int* in_sizes, int n_in,
                              void* d_out, int out_size, void* d_ws, size_t ws_size,
                              hipStream_t stream)
{
    const float* x  = (const float*)d_in[0];
    const float* xl = (const float*)d_in[1];
    const float* xu = (const float*)d_in[2];
    const float* Wa = (const float*)d_in[3];
    const float* Wp = (const float*)d_in[4];
    float* out = (float*)d_out;

    short* qkvb = (short*)d_ws;                       // 9*BHTD bf16  = 56.6 MB
    float* ybuf = (float*)(qkvb + (size_t)9 * BHTD);  // 1*BHTD f32   = 12.6 MB
    short* cand = (short*)(ybuf + (size_t)BHTD);      // 8*BHTD bf16  = 50.3 MB

    qkv_proj_mfma<<<dim3(36, 64),  256, 0, stream>>>(x, xl, xu, Wa, qkvb);
    flash_mfma   <<<dim3(80, 24),  256, 0, stream>>>(qkvb, ybuf, cand);
    out_proj_mfma<<<dim3(12, 64, 3), 256, 0, stream>>>(ybuf, cand, Wp, out);
}

// Round 3
// 558.455 us; speedup vs baseline: 1.5425x; 1.0363x over previous
//
#include <hip/hip_runtime.h>
#include <hip/hip_bf16.h>
#include <cstdint>

typedef float f4  __attribute__((ext_vector_type(4)));
typedef short s8v __attribute__((ext_vector_type(8)));   // 8 bf16 (4 VGPRs)
typedef int   i4v __attribute__((ext_vector_type(4)));

#define BHTD 3145728    // B*H*T*D = 2*12*2048*64
#define BTC  3145728
#define NT   2048
#define NC   768
#define NEG  -1e30f
// 0.125 (1/sqrt(64)) * log2(e): folded into Q at the producer so the flash
// kernel's scores are already in log2 domain (exp2 instead of expf, no scale mul)
#define QSCALE 0.18033688f

static __device__ __forceinline__ short bfbits(float f) {
    return __builtin_bit_cast(short, __float2bfloat16(f));
}
static __device__ __forceinline__ float bf2f(short s) {
    return __builtin_bit_cast(float, (int)(((unsigned int)(unsigned short)s) << 16));
}
static __device__ __forceinline__ float exp2fast(float x) {
    return __builtin_amdgcn_exp2f(x);
}
template <int ctrl>
static __device__ __forceinline__ float dppmov(float x) {
    return __builtin_bit_cast(float,
        __builtin_amdgcn_update_dpp(0, __builtin_bit_cast(int, x), ctrl, 0xF, 0xF, true));
}
// reductions over the 16 lanes of a quad (DPP row = 16 lanes)
static __device__ __forceinline__ float red16max(float x) {
    x = fmaxf(x, dppmov<0xB1>(x));    // quad_perm xor1
    x = fmaxf(x, dppmov<0x4E>(x));    // quad_perm xor2
    x = fmaxf(x, dppmov<0x141>(x));   // row_half_mirror (xor4)
    x = fmaxf(x, dppmov<0x140>(x));   // row_mirror      (xor8)
    return x;
}
static __device__ __forceinline__ float red16sum(float x) {
    x += dppmov<0xB1>(x);
    x += dppmov<0x4E>(x);
    x += dppmov<0x141>(x);
    x += dppmov<0x140>(x);
    return x;
}

// ---------------------------------------------------------------------------
// Kernel 1: MFMA QKV projection. nom=x@W^T, mid=m@W^T, rad=r@|W|^T (bf16 in,
// fp32 acc). Outputs bf16: Q,K in [var][part][B,H,T,D]; V in [B,H,D,T].
// Q (p==0) is pre-scaled by 0.125*log2e so flash works in exp2 domain.
// Ping-pong LDS double-buffer: ONE barrier per K-step. Tile t+1 is loaded to
// regs right after the barrier (T14) and written to buf^1 after the MFMAs.
// Block: 64(M)x64(N), 4 waves (16 M-rows each), K-step 32.
// ---------------------------------------------------------------------------
__global__ __launch_bounds__(256) void qkv_proj_mfma(
    const float* __restrict__ x, const float* __restrict__ xl,
    const float* __restrict__ xu, const float* __restrict__ W,
    short* __restrict__ qkvb)
{
    // per-buffer layout (shorts): Ax=0, Am=2560, Ar=5120, Bw=7680 (each [64][40])
    __shared__ short sm[2][4 * 2560];   // 40 KB
    short* Eb = &sm[0][0];              // epilogue alias [64][72] (4608 shorts)

    const int j0 = blockIdx.x * 64;     // N in [0,2304)
    const int n0 = blockIdx.y * 64;     // M in [0,4096)
    const int t  = threadIdx.x;
    const int wv = t >> 6, lane = t & 63, quad = lane >> 4, l16 = lane & 15;
    const int rw = t >> 2, koff = (t & 3) * 8;

    f4 aN[4], aM[4], aR[4];
#pragma unroll
    for (int i = 0; i < 4; i++) { aN[i] = f4{0,0,0,0}; aM[i] = f4{0,0,0,0}; aR[i] = f4{0,0,0,0}; }

    const size_t xbase = (size_t)(n0 + rw) * NC + koff;
    const size_t wbase = (size_t)(j0 + rw) * NC + koff;

    f4 rx0, rx1, rl0, rl1, ru0, ru1, rw0, rw1;
    // prologue: tile 0 -> regs -> convert -> buf 0 (no barrier needed yet)
    rx0 = *(const f4*)&x[xbase];      rx1 = *(const f4*)&x[xbase + 4];
    rl0 = *(const f4*)&xl[xbase];     rl1 = *(const f4*)&xl[xbase + 4];
    ru0 = *(const f4*)&xu[xbase];     ru1 = *(const f4*)&xu[xbase + 4];
    rw0 = *(const f4*)&W[wbase];      rw1 = *(const f4*)&W[wbase + 4];
    {
        s8v vx, vm, vr, vw;
#pragma unroll
        for (int i = 0; i < 4; i++) {
            vx[i]     = bfbits(rx0[i]);                   vx[4 + i] = bfbits(rx1[i]);
            vm[i]     = bfbits(0.5f * (rl0[i] + ru0[i])); vm[4 + i] = bfbits(0.5f * (rl1[i] + ru1[i]));
            vr[i]     = bfbits(0.5f * (ru0[i] - rl0[i])); vr[4 + i] = bfbits(0.5f * (ru1[i] - rl1[i]));
            vw[i]     = bfbits(rw0[i]);                   vw[4 + i] = bfbits(rw1[i]);
        }
        *(s8v*)&sm[0][rw * 40 + koff]        = vx;
        *(s8v*)&sm[0][2560 + rw * 40 + koff] = vm;
        *(s8v*)&sm[0][5120 + rw * 40 + koff] = vr;
        *(s8v*)&sm[0][7680 + rw * 40 + koff] = vw;
    }

    for (int it = 0; it < NC / 32; ++it) {
        const int cb = it & 1, nb = cb ^ 1;
        __syncthreads();                       // buf[cb] complete
        const bool pf = (it + 1 < NC / 32);
        if (pf) {                              // issue next-tile loads early
            const size_t xo = xbase + (it + 1) * 32, wo = wbase + (it + 1) * 32;
            rx0 = *(const f4*)&x[xo];    rx1 = *(const f4*)&x[xo + 4];
            rl0 = *(const f4*)&xl[xo];   rl1 = *(const f4*)&xl[xo + 4];
            ru0 = *(const f4*)&xu[xo];   ru1 = *(const f4*)&xu[xo + 4];
            rw0 = *(const f4*)&W[wo];    rw1 = *(const f4*)&W[wo + 4];
        }
        const s8v fx = *(const s8v*)&sm[cb][(wv * 16 + l16) * 40 + quad * 8];
        const s8v fm = *(const s8v*)&sm[cb][2560 + (wv * 16 + l16) * 40 + quad * 8];
        const s8v fr = *(const s8v*)&sm[cb][5120 + (wv * 16 + l16) * 40 + quad * 8];
#pragma unroll
        for (int nt = 0; nt < 4; ++nt) {
            const s8v fb = *(const s8v*)&sm[cb][7680 + (nt * 16 + l16) * 40 + quad * 8];
            i4v bi = __builtin_bit_cast(i4v, fb);
#pragma unroll
            for (int i = 0; i < 4; i++) bi[i] &= 0x7fff7fff;
            const s8v fa = __builtin_bit_cast(s8v, bi);
            aN[nt] = __builtin_amdgcn_mfma_f32_16x16x32_bf16(fx, fb, aN[nt], 0, 0, 0);
            aM[nt] = __builtin_amdgcn_mfma_f32_16x16x32_bf16(fm, fb, aM[nt], 0, 0, 0);
            aR[nt] = __builtin_amdgcn_mfma_f32_16x16x32_bf16(fr, fa, aR[nt], 0, 0, 0);
        }
        if (pf) {                              // convert + stage into buf[nb]
            s8v vx, vm, vr, vw;
#pragma unroll
            for (int i = 0; i < 4; i++) {
                vx[i]     = bfbits(rx0[i]);                   vx[4 + i] = bfbits(rx1[i]);
                vm[i]     = bfbits(0.5f * (rl0[i] + ru0[i])); vm[4 + i] = bfbits(0.5f * (rl1[i] + ru1[i]));
                vr[i]     = bfbits(0.5f * (ru0[i] - rl0[i])); vr[4 + i] = bfbits(0.5f * (ru1[i] - rl1[i]));
                vw[i]     = bfbits(rw0[i]);                   vw[4 + i] = bfbits(rw1[i]);
            }
            *(s8v*)&sm[nb][rw * 40 + koff]        = vx;
            *(s8v*)&sm[nb][2560 + rw * 40 + koff] = vm;
            *(s8v*)&sm[nb][5120 + rw * 40 + koff] = vr;
            *(s8v*)&sm[nb][7680 + rw * 40 + koff] = vw;
        }
    }

    const int p = j0 / NC, hh = (j0 % NC) >> 6;
    const float osc = (p == 0) ? QSCALE : 1.0f;   // pre-scale Q for exp2-domain flash
    const int cc16 = (t & 3) * 16;
    for (int var = 0; var < 3; ++var) {
        __syncthreads();
#pragma unroll
        for (int nt = 0; nt < 4; ++nt)
#pragma unroll
            for (int r = 0; r < 4; ++r) {
                const float v = (var == 0) ? aN[nt][r]
                              : (var == 1) ? aM[nt][r] - aR[nt][r]
                                           : aM[nt][r] + aR[nt][r];
                Eb[(wv * 16 + quad * 4 + r) * 72 + nt * 16 + l16] = bfbits(v * osc);
            }
        __syncthreads();
        short* dst = qkvb + (size_t)(var * 3 + p) * BHTD;
        if (p < 2) {       // Q,K row-major [B,H,T,D]
            const int token = n0 + rw, b = token >> 11, tt = token & 2047;
            const size_t o = ((size_t)(b * 12 + hh) * NT + tt) * 64 + cc16;
            *(s8v*)&dst[o]     = *(const s8v*)&Eb[rw * 72 + cc16];
            *(s8v*)&dst[o + 8] = *(const s8v*)&Eb[rw * 72 + cc16 + 8];
        } else {           // V transposed [B,H,D,T]
            const int d = rw;
            s8v e0, e1;
#pragma unroll
            for (int i = 0; i < 8; i++) e0[i] = Eb[(cc16 + i) * 72 + d];
#pragma unroll
            for (int i = 0; i < 8; i++) e1[i] = Eb[(cc16 + 8 + i) * 72 + d];
            const int token0 = n0 + cc16, b = token0 >> 11, tt = token0 & 2047;
            const size_t o = ((size_t)(b * 12 + hh) * 64 + d) * NT + tt;
            *(s8v*)&dst[o]     = e0;
            *(s8v*)&dst[o + 8] = e1;
        }
    }
}

// ---------------------------------------------------------------------------
// Kernel 2: MFMA flash, merged nominal + 4 bound branches in one launch.
//   blockIdx.x encodes (qt heavy-first, z): x = (15-qt)*5 + z
//   z==0: sv0 (qn,kn,vn) -> y fp32
//   z>=1: sv=z in 1..4: (q lo/hi, k lo/hi) x {vlo,vhi} -> candLo/candHi bf16
// Block = 128 q-rows, 4 waves x 32 rows (2 m-tiles), K-tile 32.
// Ping-pong LDS double buffer: ONE barrier per k-tile. Tile t+1 is loaded
// into regs right after the barrier (T14) and staged to buf^1 after compute.
// Softmax: defer-max (T13) in exp2 domain; one rescale branch per m-tile;
// li lane-local partials (red16sum once in epilogue).
// ---------------------------------------------------------------------------
__global__ __launch_bounds__(256) void flash_mfma(
    const short* __restrict__ qkvb, float* __restrict__ ybuf,
    short* __restrict__ cand)
{
    const int bx = blockIdx.x;             // 0..79: heavy qt first across all z
    const int qt = 15 - bx / 5;
    const int z  = bx % 5;
    const int bh = blockIdx.y;
    const int q0 = qt * 128;
    const int t  = threadIdx.x;
    const int wv = t >> 6, lane = t & 63, quad = lane >> 4, l16 = lane & 15;
    const bool TWO = (z != 0);

    __shared__ short Ks[2][32 * 72];       // [buf][kpos][d] pad->2-way (9.2 KB)
    __shared__ short Vs[2][2][64 * 40];    // [buf][sv][d][kpos] (20.5 KB)
    __shared__ short Ps[128 * 40];         // [qrow][kpos] (10.2 KB)

    int sv, qvi, kvi, v0i, v1i;
    if (TWO) { sv = z; qvi = (sv + 1) >> 1; kvi = 2 - (sv & 1); v0i = 1; v1i = 2; }
    else     { sv = 0; qvi = 0; kvi = 0; v0i = 0; v1i = 0; }

    const size_t hb = (size_t)bh * (NT * 64);
    const short* Qp  = qkvb + (size_t)(qvi * 3 + 0) * BHTD + hb;  // [t][d] (pre-scaled)
    const short* Kp  = qkvb + (size_t)(kvi * 3 + 1) * BHTD + hb;  // [t][d]
    const short* V0p = qkvb + (size_t)(v0i * 3 + 2) * BHTD + hb;  // [d][t] !
    const short* V1p = qkvb + (size_t)(v1i * 3 + 2) * BHTD + hb;

    s8v qf[2][2];
#pragma unroll
    for (int mt = 0; mt < 2; ++mt)
#pragma unroll
        for (int ch = 0; ch < 2; ++ch)
            qf[mt][ch] = *(const s8v*)&Qp[(size_t)(q0 + 32 * wv + 16 * mt + l16) * 64 + ch * 32 + quad * 8];

    float mi[2][4], li[2][4];              // li = LANE-LOCAL partial sums
    f4 acc0[2][4], acc1[2][4];
#pragma unroll
    for (int mt = 0; mt < 2; ++mt)
#pragma unroll
        for (int r = 0; r < 4; ++r) { mi[mt][r] = NEG; li[mt][r] = 0.f; }
#pragma unroll
    for (int mt = 0; mt < 2; ++mt)
#pragma unroll
        for (int i = 0; i < 4; ++i) { acc0[mt][i] = f4{0,0,0,0}; acc1[mt][i] = f4{0,0,0,0}; }

    const int ktn  = 4 * qt + 4;
    const int mykt = 4 * qt + wv + 1;      // last tile this wave's rows need
    const int skr = t >> 3, skc = (t & 7) * 8;   // K stage: 32 x 64
    const int svd = t >> 2, svc = (t & 3) * 8;   // V stage: 64 x 32

    // prologue: tile 0 -> regs -> buf 0
    s8v rK, rV0, rV1;
    rK  = *(const s8v*)&Kp[(size_t)skr * 64 + skc];
    rV0 = *(const s8v*)&V0p[(size_t)svd * NT + svc];
    if (TWO) rV1 = *(const s8v*)&V1p[(size_t)svd * NT + svc];
    *(s8v*)&Ks[0][skr * 72 + skc]    = rK;
    *(s8v*)&Vs[0][0][svd * 40 + svc] = rV0;
    if (TWO) *(s8v*)&Vs[0][1][svd * 40 + svc] = rV1;

    for (int kt = 0; kt < ktn; ++kt) {
        const int k0 = kt * 32;
        const int cb = kt & 1, nb = cb ^ 1;
        __syncthreads();                   // buf[cb] complete for all waves
        const bool pf = (kt + 1 < ktn);
        if (pf) {                          // issue next-tile loads early
            const int k1 = k0 + 32;
            rK  = *(const s8v*)&Kp[(size_t)(k1 + skr) * 64 + skc];
            rV0 = *(const s8v*)&V0p[(size_t)svd * NT + k1 + svc];
            if (TWO) rV1 = *(const s8v*)&V1p[(size_t)svd * NT + k1 + svc];
        }
        if (kt < mykt) {
            // ---- S = Q K^T (already in log2 domain via Q pre-scale) ----
            f4 s[2][2];
#pragma unroll
            for (int mt = 0; mt < 2; ++mt) { s[mt][0] = f4{0,0,0,0}; s[mt][1] = f4{0,0,0,0}; }
#pragma unroll
            for (int nt = 0; nt < 2; ++nt)
#pragma unroll
                for (int ch = 0; ch < 2; ++ch) {
                    const s8v kf = *(const s8v*)&Ks[cb][(nt * 16 + l16) * 72 + ch * 32 + quad * 8];
                    s[0][nt] = __builtin_amdgcn_mfma_f32_16x16x32_bf16(qf[0][ch], kf, s[0][nt], 0, 0, 0);
                    s[1][nt] = __builtin_amdgcn_mfma_f32_16x16x32_bf16(qf[1][ch], kf, s[1][nt], 0, 0, 0);
                }

            // ---- softmax per m-tile: defer-max, single branch per m-tile ----
#pragma unroll
            for (int mt = 0; mt < 2; ++mt) {
                const int rowb = q0 + 32 * wv + 16 * mt;
                float a0[4], a1[4], c[4];
#pragma unroll
                for (int r = 0; r < 4; ++r) { a0[r] = s[mt][0][r]; a1[r] = s[mt][1][r]; }
                if (k0 + 31 > rowb) {
#pragma unroll
                    for (int r = 0; r < 4; ++r) {
                        const int row = rowb + quad * 4 + r;
                        if (k0 + l16 > row)      a0[r] = NEG;
                        if (k0 + 16 + l16 > row) a1[r] = NEG;
                    }
                }
#pragma unroll
                for (int r = 0; r < 4; ++r) c[r] = fmaxf(a0[r], a1[r]);
                const float g = fmaxf(fmaxf(c[0] - mi[mt][0], c[1] - mi[mt][1]),
                                      fmaxf(c[2] - mi[mt][2], c[3] - mi[mt][3]));
                if (__any(g > 8.0f)) {         // rare: some row max grew
#pragma unroll
                    for (int r = 0; r < 4; ++r) {
                        const float mx = red16max(c[r]);
                        const float nm = fmaxf(mi[mt][r], mx);
                        const float al = exp2fast(mi[mt][r] - nm);
                        mi[mt][r] = nm;
                        li[mt][r] *= al;
#pragma unroll
                        for (int dt = 0; dt < 4; ++dt) acc0[mt][dt][r] *= al;
                        if (TWO) {
#pragma unroll
                            for (int dt = 0; dt < 4; ++dt) acc1[mt][dt][r] *= al;
                        }
                    }
                }
#pragma unroll
                for (int r = 0; r < 4; ++r) {
                    a0[r] = exp2fast(a0[r] - mi[mt][r]);   // bounded by 2^8
                    a1[r] = exp2fast(a1[r] - mi[mt][r]);
                    li[mt][r] += a0[r] + a1[r];            // lane-local partial
                    Ps[(32 * wv + 16 * mt + quad * 4 + r) * 40 + l16]      = bfbits(a0[r]);
                    Ps[(32 * wv + 16 * mt + quad * 4 + r) * 40 + 16 + l16] = bfbits(a1[r]);
                }
            }
            // ---- O += P V ----
            const s8v pf0 = *(const s8v*)&Ps[(32 * wv + l16) * 40 + quad * 8];
            const s8v pf1 = *(const s8v*)&Ps[(32 * wv + 16 + l16) * 40 + quad * 8];
#pragma unroll
            for (int dt = 0; dt < 4; ++dt) {
                const s8v vf0 = *(const s8v*)&Vs[cb][0][(dt * 16 + l16) * 40 + quad * 8];
                acc0[0][dt] = __builtin_amdgcn_mfma_f32_16x16x32_bf16(pf0, vf0, acc0[0][dt], 0, 0, 0);
                acc0[1][dt] = __builtin_amdgcn_mfma_f32_16x16x32_bf16(pf1, vf0, acc0[1][dt], 0, 0, 0);
                if (TWO) {
                    const s8v vf1 = *(const s8v*)&Vs[cb][1][(dt * 16 + l16) * 40 + quad * 8];
                    acc1[0][dt] = __builtin_amdgcn_mfma_f32_16x16x32_bf16(pf0, vf1, acc1[0][dt], 0, 0, 0);
                    acc1[1][dt] = __builtin_amdgcn_mfma_f32_16x16x32_bf16(pf1, vf1, acc1[1][dt], 0, 0, 0);
                }
            }
        }
        if (pf) {                          // stage next tile into buf[nb]
            *(s8v*)&Ks[nb][skr * 72 + skc]    = rK;
            *(s8v*)&Vs[nb][0][svd * 40 + svc] = rV0;
            if (TWO) *(s8v*)&Vs[nb][1][svd * 40 + svc] = rV1;
        }
    }

#pragma unroll
    for (int mt = 0; mt < 2; ++mt) {
        float inv[4];
#pragma unroll
        for (int r = 0; r < 4; ++r) inv[r] = 1.f / red16sum(li[mt][r]);  // reduce once here
#pragma unroll
        for (int dt = 0; dt < 4; ++dt)
#pragma unroll
            for (int r = 0; r < 4; ++r) {
                const size_t o = hb + (size_t)(q0 + 32 * wv + 16 * mt + quad * 4 + r) * 64 + dt * 16 + l16;
                if (!TWO) {
                    ybuf[o] = acc0[mt][dt][r] * inv[r];
                } else {
                    const float xa = acc0[mt][dt][r] * inv[r];
                    const float xb = acc1[mt][dt][r] * inv[r];
                    cand[(size_t)(sv - 1) * BHTD + o] = bfbits(fminf(xa, xb));
                    cand[(size_t)(3 + sv) * BHTD + o] = bfbits(fmaxf(xa, xb));
                }
            }
    }
}

// ---------------------------------------------------------------------------
// Kernel 3: MFMA output projection. z=0: A=y fp32; z=1: A=min of 4 candLo;
// z=2: A=max of 4 candHi. B=Wp (bf16). out fp32 via LDS re-layout.
// Ping-pong LDS double buffer: ONE barrier per K-step (same pattern).
// ---------------------------------------------------------------------------
__global__ __launch_bounds__(256) void out_proj_mfma(
    const float* __restrict__ ybuf, const short* __restrict__ cand,
    const float* __restrict__ Wp, float* __restrict__ out)
{
    // per-buffer layout (shorts): As=0, Bs=2560 (each [64][40])
    __shared__ short sm3[2][2 * 2560];      // 20.5 KB
    float* Eb = (float*)sm3;                // epilogue alias [64][68] (17.4 KB)

    const int o  = blockIdx.z;
    const int j0 = blockIdx.x * 64, n0 = blockIdx.y * 64;
    const int t  = threadIdx.x;
    const int wv = t >> 6, lane = t & 63, quad = lane >> 4, l16 = lane & 15;
    const int rw = t >> 2, koff = (t & 3) * 8;

    f4 acc[4];
#pragma unroll
    for (int i = 0; i < 4; i++) acc[i] = f4{0,0,0,0};

    const int token = n0 + rw, b = token >> 11, tt = token & 2047;
    const size_t wbase = (size_t)(j0 + rw) * NC + koff;
    const short* cb = cand + (size_t)(o == 1 ? 0 : 4) * BHTD;

    f4 ry0, ry1, rw0, rw1;
    s8v rc0, rc1, rc2, rc3;

    // tile-raw -> (av,bv) conversion
    auto convert = [&](s8v& av, s8v& bv) {
        if (o == 0) {
#pragma unroll
            for (int i = 0; i < 4; i++) { av[i] = bfbits(ry0[i]); av[4 + i] = bfbits(ry1[i]); }
        } else {
            float v[8];
#pragma unroll
            for (int i = 0; i < 8; i++) v[i] = bf2f(rc0[i]);
            if (o == 1) {
#pragma unroll
                for (int i = 0; i < 8; i++) v[i] = fminf(v[i], bf2f(rc1[i]));
#pragma unroll
                for (int i = 0; i < 8; i++) v[i] = fminf(v[i], bf2f(rc2[i]));
#pragma unroll
                for (int i = 0; i < 8; i++) v[i] = fminf(v[i], bf2f(rc3[i]));
            } else {
#pragma unroll
                for (int i = 0; i < 8; i++) v[i] = fmaxf(v[i], bf2f(rc1[i]));
#pragma unroll
                for (int i = 0; i < 8; i++) v[i] = fmaxf(v[i], bf2f(rc2[i]));
#pragma unroll
                for (int i = 0; i < 8; i++) v[i] = fmaxf(v[i], bf2f(rc3[i]));
            }
#pragma unroll
            for (int i = 0; i < 8; i++) av[i] = bfbits(v[i]);
        }
#pragma unroll
        for (int i = 0; i < 4; i++) { bv[i] = bfbits(rw0[i]); bv[4 + i] = bfbits(rw1[i]); }
    };
    auto loadTile = [&](int k1) {
        const int hh = k1 >> 6, d0 = (k1 & 63) + koff;
        const size_t aoff = ((size_t)(b * 12 + hh) * NT + tt) * 64 + d0;
        if (o == 0) {
            ry0 = *(const f4*)&ybuf[aoff];
            ry1 = *(const f4*)&ybuf[aoff + 4];
        } else {
            rc0 = *(const s8v*)&cb[aoff];
            rc1 = *(const s8v*)&cb[(size_t)1 * BHTD + aoff];
            rc2 = *(const s8v*)&cb[(size_t)2 * BHTD + aoff];
            rc3 = *(const s8v*)&cb[(size_t)3 * BHTD + aoff];
        }
        rw0 = *(const f4*)&Wp[wbase + k1];
        rw1 = *(const f4*)&Wp[wbase + k1 + 4];
    };

    // prologue: tile 0 -> regs -> convert -> buf 0
    loadTile(0);
    {
        s8v av, bv;
        convert(av, bv);
        *(s8v*)&sm3[0][rw * 40 + koff]        = av;
        *(s8v*)&sm3[0][2560 + rw * 40 + koff] = bv;
    }

    for (int it = 0; it < NC / 32; ++it) {
        const int cbuf = it & 1, nbuf = cbuf ^ 1;
        __syncthreads();
        const bool pf = (it + 1 < NC / 32);
        if (pf) loadTile((it + 1) * 32);
        const s8v af = *(const s8v*)&sm3[cbuf][(wv * 16 + l16) * 40 + quad * 8];
#pragma unroll
        for (int nt = 0; nt < 4; ++nt) {
            const s8v bf = *(const s8v*)&sm3[cbuf][2560 + (nt * 16 + l16) * 40 + quad * 8];
            acc[nt] = __builtin_amdgcn_mfma_f32_16x16x32_bf16(af, bf, acc[nt], 0, 0, 0);
        }
        if (pf) {
            s8v av, bv;
            convert(av, bv);
            *(s8v*)&sm3[nbuf][rw * 40 + koff]        = av;
            *(s8v*)&sm3[nbuf][2560 + rw * 40 + koff] = bv;
        }
    }
    __syncthreads();
#pragma unroll
    for (int nt = 0; nt < 4; ++nt)
#pragma unroll
        for (int r = 0; r < 4; ++r)
            Eb[(wv * 16 + quad * 4 + r) * 68 + nt * 16 + l16] = acc[nt][r];
    __syncthreads();
    const int cc = (t & 3) * 16;
#pragma unroll
    for (int i = 0; i < 4; ++i) {
        const f4 vo = *(const f4*)&Eb[rw * 68 + cc + 4 * i];
        *(f4*)&out[(size_t)o * BTC + (size_t)(n0 + rw) * NC + j0 + cc + 4 * i] = vo;
    }
}

extern "C" void kernel_launch(void* const* d_in, const int* in_sizes, int n_in,
                              void* d_out, int out_size, void* d_ws, size_t ws_size,
                              hipStream_t stream)
{
    const float* x  = (const float*)d_in[0];
    const float* xl = (const float*)d_in[1];
    const float* xu = (const float*)d_in[2];
    const float* Wa = (const float*)d_in[3];
    const float* Wp = (const float*)d_in[4];
    float* out = (float*)d_out;

    short* qkvb = (short*)d_ws;                       // 9*BHTD bf16  = 56.6 MB
    float* ybuf = (float*)(qkvb + (size_t)9 * BHTD);  // 1*BHTD f32   = 12.6 MB
    short* cand = (short*)(ybuf + (size_t)BHTD);      // 8*BHTD bf16  = 50.3 MB

    qkv_proj_mfma<<<dim3(36, 64),  256, 0, stream>>>(x, xl, xu, Wa, qkvb);
    flash_mfma   <<<dim3(80, 24),  256, 0, stream>>>(qkvb, ybuf, cand);
    out_proj_mfma<<<dim3(12, 64, 3), 256, 0, stream>>>(ybuf, cand, Wp, out);
}

// Round 4
// 524.226 us; speedup vs baseline: 1.6432x; 1.0653x over previous
//
#include <hip/hip_runtime.h>
#include <hip/hip_bf16.h>
#include <cstdint>

typedef float f4  __attribute__((ext_vector_type(4)));
typedef short s8v __attribute__((ext_vector_type(8)));   // 8 bf16 (4 VGPRs)
typedef int   i4v __attribute__((ext_vector_type(4)));

#define BHTD 3145728    // B*H*T*D = 2*12*2048*64
#define BTC  3145728
#define NT   2048
#define NC   768
#define NWA  1769472    // 3C*C = 2304*768
#define NEG  -1e30f
// 0.125 (1/sqrt(64)) * log2(e): folded into Q at the producer so the flash
// kernel's scores are already in log2 domain (exp2 instead of expf, no scale mul)
#define QSCALE 0.18033688f

static __device__ __forceinline__ short bfbits(float f) {
    return __builtin_bit_cast(short, __float2bfloat16(f));
}
static __device__ __forceinline__ float bf2f(short s) {
    return __builtin_bit_cast(float, (int)(((unsigned int)(unsigned short)s) << 16));
}
static __device__ __forceinline__ float exp2fast(float x) {
    return __builtin_amdgcn_exp2f(x);
}
template <int ctrl>
static __device__ __forceinline__ float dppmov(float x) {
    return __builtin_bit_cast(float,
        __builtin_amdgcn_update_dpp(0, __builtin_bit_cast(int, x), ctrl, 0xF, 0xF, true));
}
// reductions over the 16 lanes of a quad (DPP row = 16 lanes)
static __device__ __forceinline__ float red16max(float x) {
    x = fmaxf(x, dppmov<0xB1>(x));    // quad_perm xor1
    x = fmaxf(x, dppmov<0x4E>(x));    // quad_perm xor2
    x = fmaxf(x, dppmov<0x141>(x));   // row_half_mirror (xor4)
    x = fmaxf(x, dppmov<0x140>(x));   // row_mirror      (xor8)
    return x;
}
static __device__ __forceinline__ float red16sum(float x) {
    x += dppmov<0xB1>(x);
    x += dppmov<0x4E>(x);
    x += dppmov<0x141>(x);
    x += dppmov<0x140>(x);
    return x;
}

// ---------------------------------------------------------------------------
// Kernel 0: one-shot fp32->bf16 conversion. xn=x, xm=(xl+xu)/2, xr=(xu-xl)/2,
// wb=W. Removes the 36x-redundant per-block conversion from qkv_proj.
// 1536 blocks x 256 thr; threads with flat id < NWA/8 also convert W.
// ---------------------------------------------------------------------------
__global__ __launch_bounds__(256) void prep_cvt(
    const float* __restrict__ x, const float* __restrict__ xl,
    const float* __restrict__ xu, const float* __restrict__ W,
    short* __restrict__ xn, short* __restrict__ xm, short* __restrict__ xr,
    short* __restrict__ wb)
{
    const size_t flat = (size_t)blockIdx.x * 256 + threadIdx.x;
    const size_t i = flat * 8;        // 1536*256*8 == BTC exactly
    {
        const f4 a0 = *(const f4*)&x[i],  a1 = *(const f4*)&x[i + 4];
        const f4 l0 = *(const f4*)&xl[i], l1 = *(const f4*)&xl[i + 4];
        const f4 u0 = *(const f4*)&xu[i], u1 = *(const f4*)&xu[i + 4];
        s8v vn, vm, vr;
#pragma unroll
        for (int j = 0; j < 4; j++) {
            vn[j]     = bfbits(a0[j]);                   vn[4 + j] = bfbits(a1[j]);
            vm[j]     = bfbits(0.5f * (l0[j] + u0[j]));  vm[4 + j] = bfbits(0.5f * (l1[j] + u1[j]));
            vr[j]     = bfbits(0.5f * (u0[j] - l0[j]));  vr[4 + j] = bfbits(0.5f * (u1[j] - l1[j]));
        }
        *(s8v*)&xn[i] = vn;
        *(s8v*)&xm[i] = vm;
        *(s8v*)&xr[i] = vr;
    }
    if (flat < NWA / 8) {
        const size_t wi = flat * 8;
        const f4 w0 = *(const f4*)&W[wi], w1 = *(const f4*)&W[wi + 4];
        s8v vw;
#pragma unroll
        for (int j = 0; j < 4; j++) { vw[j] = bfbits(w0[j]); vw[4 + j] = bfbits(w1[j]); }
        *(s8v*)&wb[wi] = vw;
    }
}

// ---------------------------------------------------------------------------
// Kernel 1: MFMA QKV projection from pre-converted bf16 inputs.
// nom=xn@wb^T, mid=xm@wb^T, rad=xr@|wb|^T (|wb| derived in-reg).
// Outputs bf16: Q,K in [var][part][B,H,T,D]; V in [B,H,D,T].
// Q (p==0) pre-scaled by 0.125*log2e. Ping-pong LDS dbuf, ONE barrier/K-step.
// Block: 64(M)x64(N), 4 waves (16 M-rows each), K-step 32.
// ---------------------------------------------------------------------------
__global__ __launch_bounds__(256) void qkv_proj_mfma(
    const short* __restrict__ xn, const short* __restrict__ xm,
    const short* __restrict__ xr, const short* __restrict__ wb,
    short* __restrict__ qkvb)
{
    // per-buffer layout (shorts): Ax=0, Am=2560, Ar=5120, Bw=7680 (each [64][40])
    __shared__ short sm[2][4 * 2560];   // 40 KB
    short* Eb = &sm[0][0];              // epilogue alias [64][72] (4608 shorts)

    const int j0 = blockIdx.x * 64;     // N in [0,2304)
    const int n0 = blockIdx.y * 64;     // M in [0,4096)
    const int t  = threadIdx.x;
    const int wv = t >> 6, lane = t & 63, quad = lane >> 4, l16 = lane & 15;
    const int rw = t >> 2, koff = (t & 3) * 8;

    f4 aN[4], aM[4], aR[4];
#pragma unroll
    for (int i = 0; i < 4; i++) { aN[i] = f4{0,0,0,0}; aM[i] = f4{0,0,0,0}; aR[i] = f4{0,0,0,0}; }

    const size_t abase = (size_t)(n0 + rw) * NC + koff;
    const size_t bbase = (size_t)(j0 + rw) * NC + koff;

    s8v rn, rm, rr, rb;
    rn = *(const s8v*)&xn[abase];
    rm = *(const s8v*)&xm[abase];
    rr = *(const s8v*)&xr[abase];
    rb = *(const s8v*)&wb[bbase];
    *(s8v*)&sm[0][rw * 40 + koff]        = rn;
    *(s8v*)&sm[0][2560 + rw * 40 + koff] = rm;
    *(s8v*)&sm[0][5120 + rw * 40 + koff] = rr;
    *(s8v*)&sm[0][7680 + rw * 40 + koff] = rb;

    for (int it = 0; it < NC / 32; ++it) {
        const int cb = it & 1, nb = cb ^ 1;
        __syncthreads();                       // buf[cb] complete
        const bool pf = (it + 1 < NC / 32);
        if (pf) {                              // issue next-tile loads early
            const size_t k1 = (size_t)(it + 1) * 32;
            rn = *(const s8v*)&xn[abase + k1];
            rm = *(const s8v*)&xm[abase + k1];
            rr = *(const s8v*)&xr[abase + k1];
            rb = *(const s8v*)&wb[bbase + k1];
        }
        const s8v fx = *(const s8v*)&sm[cb][(wv * 16 + l16) * 40 + quad * 8];
        const s8v fm = *(const s8v*)&sm[cb][2560 + (wv * 16 + l16) * 40 + quad * 8];
        const s8v fr = *(const s8v*)&sm[cb][5120 + (wv * 16 + l16) * 40 + quad * 8];
#pragma unroll
        for (int nt = 0; nt < 4; ++nt) {
            const s8v fb = *(const s8v*)&sm[cb][7680 + (nt * 16 + l16) * 40 + quad * 8];
            i4v bi = __builtin_bit_cast(i4v, fb);
#pragma unroll
            for (int i = 0; i < 4; i++) bi[i] &= 0x7fff7fff;
            const s8v fa = __builtin_bit_cast(s8v, bi);
            aN[nt] = __builtin_amdgcn_mfma_f32_16x16x32_bf16(fx, fb, aN[nt], 0, 0, 0);
            aM[nt] = __builtin_amdgcn_mfma_f32_16x16x32_bf16(fm, fb, aM[nt], 0, 0, 0);
            aR[nt] = __builtin_amdgcn_mfma_f32_16x16x32_bf16(fr, fa, aR[nt], 0, 0, 0);
        }
        if (pf) {                              // stage into buf[nb]
            *(s8v*)&sm[nb][rw * 40 + koff]        = rn;
            *(s8v*)&sm[nb][2560 + rw * 40 + koff] = rm;
            *(s8v*)&sm[nb][5120 + rw * 40 + koff] = rr;
            *(s8v*)&sm[nb][7680 + rw * 40 + koff] = rb;
        }
    }

    const int p = j0 / NC, hh = (j0 % NC) >> 6;
    const float osc = (p == 0) ? QSCALE : 1.0f;   // pre-scale Q for exp2-domain flash
    const int cc16 = (t & 3) * 16;
    for (int var = 0; var < 3; ++var) {
        __syncthreads();
#pragma unroll
        for (int nt = 0; nt < 4; ++nt)
#pragma unroll
            for (int r = 0; r < 4; ++r) {
                const float v = (var == 0) ? aN[nt][r]
                              : (var == 1) ? aM[nt][r] - aR[nt][r]
                                           : aM[nt][r] + aR[nt][r];
                Eb[(wv * 16 + quad * 4 + r) * 72 + nt * 16 + l16] = bfbits(v * osc);
            }
        __syncthreads();
        short* dst = qkvb + (size_t)(var * 3 + p) * BHTD;
        if (p < 2) {       // Q,K row-major [B,H,T,D]
            const int token = n0 + rw, b = token >> 11, tt = token & 2047;
            const size_t o = ((size_t)(b * 12 + hh) * NT + tt) * 64 + cc16;
            *(s8v*)&dst[o]     = *(const s8v*)&Eb[rw * 72 + cc16];
            *(s8v*)&dst[o + 8] = *(const s8v*)&Eb[rw * 72 + cc16 + 8];
        } else {           // V transposed [B,H,D,T]
            const int d = rw;
            s8v e0, e1;
#pragma unroll
            for (int i = 0; i < 8; i++) e0[i] = Eb[(cc16 + i) * 72 + d];
#pragma unroll
            for (int i = 0; i < 8; i++) e1[i] = Eb[(cc16 + 8 + i) * 72 + d];
            const int token0 = n0 + cc16, b = token0 >> 11, tt = token0 & 2047;
            const size_t o = ((size_t)(b * 12 + hh) * 64 + d) * NT + tt;
            *(s8v*)&dst[o]     = e0;
            *(s8v*)&dst[o + 8] = e1;
        }
    }
}

// ---------------------------------------------------------------------------
// Kernel 2: MFMA flash, merged nominal + 4 bound branches in one launch.
//   blockIdx.x encodes (qt heavy-first, z): x = (15-qt)*5 + z
// Block = 128 q-rows, 4 waves x 32 rows (2 m-tiles), K-tile 32.
// Ping-pong LDS dbuf, ONE barrier per k-tile; T14 reg prefetch.
// Interleaved-k Ks fragments: s[][0]=even kpos (2*l16), s[][1]=odd -> the
// (a0,a1) pair is consecutive kpos and stores as ONE b32 in natural k-order.
// Softmax: defer-max (T13) in exp2 domain; li lane-local partials.
// T5 setprio(1) around MFMA clusters.
// ---------------------------------------------------------------------------
__global__ __launch_bounds__(256) void flash_mfma(
    const short* __restrict__ qkvb, float* __restrict__ ybuf,
    short* __restrict__ cand)
{
    const int bx = blockIdx.x;             // 0..79: heavy qt first across all z
    const int qt = 15 - bx / 5;
    const int z  = bx % 5;
    const int bh = blockIdx.y;
    const int q0 = qt * 128;
    const int t  = threadIdx.x;
    const int wv = t >> 6, lane = t & 63, quad = lane >> 4, l16 = lane & 15;
    const bool TWO = (z != 0);

    __shared__ short Ks[2][32 * 72];       // [buf][kpos][d] pad->2-way (9.2 KB)
    __shared__ short Vs[2][2][64 * 40];    // [buf][sv][d][kpos] (20.5 KB)
    __shared__ short Ps[128 * 40];         // [qrow][kpos] (10.2 KB)

    int sv, qvi, kvi, v0i, v1i;
    if (TWO) { sv = z; qvi = (sv + 1) >> 1; kvi = 2 - (sv & 1); v0i = 1; v1i = 2; }
    else     { sv = 0; qvi = 0; kvi = 0; v0i = 0; v1i = 0; }

    const size_t hb = (size_t)bh * (NT * 64);
    const short* Qp  = qkvb + (size_t)(qvi * 3 + 0) * BHTD + hb;  // [t][d] (pre-scaled)
    const short* Kp  = qkvb + (size_t)(kvi * 3 + 1) * BHTD + hb;  // [t][d]
    const short* V0p = qkvb + (size_t)(v0i * 3 + 2) * BHTD + hb;  // [d][t] !
    const short* V1p = qkvb + (size_t)(v1i * 3 + 2) * BHTD + hb;

    s8v qf[2][2];
#pragma unroll
    for (int mt = 0; mt < 2; ++mt)
#pragma unroll
        for (int ch = 0; ch < 2; ++ch)
            qf[mt][ch] = *(const s8v*)&Qp[(size_t)(q0 + 32 * wv + 16 * mt + l16) * 64 + ch * 32 + quad * 8];

    float mi[2][4], li[2][4];              // li = LANE-LOCAL partial sums
    f4 acc0[2][4], acc1[2][4];
#pragma unroll
    for (int mt = 0; mt < 2; ++mt)
#pragma unroll
        for (int r = 0; r < 4; ++r) { mi[mt][r] = NEG; li[mt][r] = 0.f; }
#pragma unroll
    for (int mt = 0; mt < 2; ++mt)
#pragma unroll
        for (int i = 0; i < 4; ++i) { acc0[mt][i] = f4{0,0,0,0}; acc1[mt][i] = f4{0,0,0,0}; }

    const int ktn  = 4 * qt + 4;
    const int mykt = 4 * qt + wv + 1;      // last tile this wave's rows need
    const int skr = t >> 3, skc = (t & 7) * 8;   // K stage: 32 x 64
    const int svd = t >> 2, svc = (t & 3) * 8;   // V stage: 64 x 32

    // prologue: tile 0 -> regs -> buf 0
    s8v rK, rV0, rV1;
    rK  = *(const s8v*)&Kp[(size_t)skr * 64 + skc];
    rV0 = *(const s8v*)&V0p[(size_t)svd * NT + svc];
    if (TWO) rV1 = *(const s8v*)&V1p[(size_t)svd * NT + svc];
    *(s8v*)&Ks[0][skr * 72 + skc]    = rK;
    *(s8v*)&Vs[0][0][svd * 40 + svc] = rV0;
    if (TWO) *(s8v*)&Vs[0][1][svd * 40 + svc] = rV1;

    for (int kt = 0; kt < ktn; ++kt) {
        const int k0 = kt * 32;
        const int cb = kt & 1, nb = cb ^ 1;
        __syncthreads();                   // buf[cb] complete for all waves
        const bool pf = (kt + 1 < ktn);
        if (pf) {                          // issue next-tile loads early
            const int k1 = k0 + 32;
            rK  = *(const s8v*)&Kp[(size_t)(k1 + skr) * 64 + skc];
            rV0 = *(const s8v*)&V0p[(size_t)svd * NT + k1 + svc];
            if (TWO) rV1 = *(const s8v*)&V1p[(size_t)svd * NT + k1 + svc];
        }
        if (kt < mykt) {
            // ---- S = Q K^T; col of s[.][nt] = kpos k0 + 2*l16 + nt ----
            f4 s[2][2];
#pragma unroll
            for (int mt = 0; mt < 2; ++mt) { s[mt][0] = f4{0,0,0,0}; s[mt][1] = f4{0,0,0,0}; }
            __builtin_amdgcn_s_setprio(1);
#pragma unroll
            for (int nt = 0; nt < 2; ++nt)
#pragma unroll
                for (int ch = 0; ch < 2; ++ch) {
                    const s8v kf = *(const s8v*)&Ks[cb][(2 * l16 + nt) * 72 + ch * 32 + quad * 8];
                    s[0][nt] = __builtin_amdgcn_mfma_f32_16x16x32_bf16(qf[0][ch], kf, s[0][nt], 0, 0, 0);
                    s[1][nt] = __builtin_amdgcn_mfma_f32_16x16x32_bf16(qf[1][ch], kf, s[1][nt], 0, 0, 0);
                }
            __builtin_amdgcn_s_setprio(0);

            // ---- softmax per m-tile: defer-max, single branch per m-tile ----
#pragma unroll
            for (int mt = 0; mt < 2; ++mt) {
                const int rowb = q0 + 32 * wv + 16 * mt;
                float a0[4], a1[4], c[4];
#pragma unroll
                for (int r = 0; r < 4; ++r) { a0[r] = s[mt][0][r]; a1[r] = s[mt][1][r]; }
                if (k0 + 31 > rowb) {
#pragma unroll
                    for (int r = 0; r < 4; ++r) {
                        const int row = rowb + quad * 4 + r;
                        if (k0 + 2 * l16 > row)     a0[r] = NEG;
                        if (k0 + 2 * l16 + 1 > row) a1[r] = NEG;
                    }
                }
#pragma unroll
                for (int r = 0; r < 4; ++r) c[r] = fmaxf(a0[r], a1[r]);
                const float g = fmaxf(fmaxf(c[0] - mi[mt][0], c[1] - mi[mt][1]),
                                      fmaxf(c[2] - mi[mt][2], c[3] - mi[mt][3]));
                if (__any(g > 8.0f)) {         // rare: some row max grew
#pragma unroll
                    for (int r = 0; r < 4; ++r) {
                        const float mx = red16max(c[r]);
                        const float nm = fmaxf(mi[mt][r], mx);
                        const float al = exp2fast(mi[mt][r] - nm);
                        mi[mt][r] = nm;
                        li[mt][r] *= al;
#pragma unroll
                        for (int dt = 0; dt < 4; ++dt) acc0[mt][dt][r] *= al;
                        if (TWO) {
#pragma unroll
                            for (int dt = 0; dt < 4; ++dt) acc1[mt][dt][r] *= al;
                        }
                    }
                }
#pragma unroll
                for (int r = 0; r < 4; ++r) {
                    a0[r] = exp2fast(a0[r] - mi[mt][r]);   // bounded by 2^8
                    a1[r] = exp2fast(a1[r] - mi[mt][r]);
                    li[mt][r] += a0[r] + a1[r];            // lane-local partial
                    // packed pair = consecutive kpos (2*l16, 2*l16+1), natural order
                    const int pb = ((int)(unsigned short)bfbits(a1[r]) << 16)
                                 | (int)(unsigned short)bfbits(a0[r]);
                    *(int*)&Ps[(32 * wv + 16 * mt + quad * 4 + r) * 40 + 2 * l16] = pb;
                }
            }
            // ---- O += P V ----
            const s8v pf0 = *(const s8v*)&Ps[(32 * wv + l16) * 40 + quad * 8];
            const s8v pf1 = *(const s8v*)&Ps[(32 * wv + 16 + l16) * 40 + quad * 8];
            __builtin_amdgcn_s_setprio(1);
#pragma unroll
            for (int dt = 0; dt < 4; ++dt) {
                const s8v vf0 = *(const s8v*)&Vs[cb][0][(dt * 16 + l16) * 40 + quad * 8];
                acc0[0][dt] = __builtin_amdgcn_mfma_f32_16x16x32_bf16(pf0, vf0, acc0[0][dt], 0, 0, 0);
                acc0[1][dt] = __builtin_amdgcn_mfma_f32_16x16x32_bf16(pf1, vf0, acc0[1][dt], 0, 0, 0);
                if (TWO) {
                    const s8v vf1 = *(const s8v*)&Vs[cb][1][(dt * 16 + l16) * 40 + quad * 8];
                    acc1[0][dt] = __builtin_amdgcn_mfma_f32_16x16x32_bf16(pf0, vf1, acc1[0][dt], 0, 0, 0);
                    acc1[1][dt] = __builtin_amdgcn_mfma_f32_16x16x32_bf16(pf1, vf1, acc1[1][dt], 0, 0, 0);
                }
            }
            __builtin_amdgcn_s_setprio(0);
        }
        if (pf) {                          // stage next tile into buf[nb]
            *(s8v*)&Ks[nb][skr * 72 + skc]    = rK;
            *(s8v*)&Vs[nb][0][svd * 40 + svc] = rV0;
            if (TWO) *(s8v*)&Vs[nb][1][svd * 40 + svc] = rV1;
        }
    }

#pragma unroll
    for (int mt = 0; mt < 2; ++mt) {
        float inv[4];
#pragma unroll
        for (int r = 0; r < 4; ++r) inv[r] = 1.f / red16sum(li[mt][r]);  // reduce once here
#pragma unroll
        for (int dt = 0; dt < 4; ++dt)
#pragma unroll
            for (int r = 0; r < 4; ++r) {
                const size_t o = hb + (size_t)(q0 + 32 * wv + 16 * mt + quad * 4 + r) * 64 + dt * 16 + l16;
                if (!TWO) {
                    ybuf[o] = acc0[mt][dt][r] * inv[r];
                } else {
                    const float xa = acc0[mt][dt][r] * inv[r];
                    const float xb = acc1[mt][dt][r] * inv[r];
                    cand[(size_t)(sv - 1) * BHTD + o] = bfbits(fminf(xa, xb));
                    cand[(size_t)(3 + sv) * BHTD + o] = bfbits(fmaxf(xa, xb));
                }
            }
    }
}

// ---------------------------------------------------------------------------
// Kernel 3: MFMA output projection. z=0: A=y fp32; z=1: A=min of 4 candLo;
// z=2: A=max of 4 candHi. B=Wp (bf16). out fp32 via LDS re-layout.
// Ping-pong LDS double buffer: ONE barrier per K-step.
// ---------------------------------------------------------------------------
__global__ __launch_bounds__(256) void out_proj_mfma(
    const float* __restrict__ ybuf, const short* __restrict__ cand,
    const float* __restrict__ Wp, float* __restrict__ out)
{
    // per-buffer layout (shorts): As=0, Bs=2560 (each [64][40])
    __shared__ short sm3[2][2 * 2560];      // 20.5 KB
    float* Eb = (float*)sm3;                // epilogue alias [64][68] (17.4 KB)

    const int o  = blockIdx.z;
    const int j0 = blockIdx.x * 64, n0 = blockIdx.y * 64;
    const int t  = threadIdx.x;
    const int wv = t >> 6, lane = t & 63, quad = lane >> 4, l16 = lane & 15;
    const int rw = t >> 2, koff = (t & 3) * 8;

    f4 acc[4];
#pragma unroll
    for (int i = 0; i < 4; i++) acc[i] = f4{0,0,0,0};

    const int token = n0 + rw, b = token >> 11, tt = token & 2047;
    const size_t wbase = (size_t)(j0 + rw) * NC + koff;
    const short* cb = cand + (size_t)(o == 1 ? 0 : 4) * BHTD;

    f4 ry0, ry1, rw0, rw1;
    s8v rc0, rc1, rc2, rc3;

    // tile-raw -> (av,bv) conversion
    auto convert = [&](s8v& av, s8v& bv) {
        if (o == 0) {
#pragma unroll
            for (int i = 0; i < 4; i++) { av[i] = bfbits(ry0[i]); av[4 + i] = bfbits(ry1[i]); }
        } else {
            float v[8];
#pragma unroll
            for (int i = 0; i < 8; i++) v[i] = bf2f(rc0[i]);
            if (o == 1) {
#pragma unroll
                for (int i = 0; i < 8; i++) v[i] = fminf(v[i], bf2f(rc1[i]));
#pragma unroll
                for (int i = 0; i < 8; i++) v[i] = fminf(v[i], bf2f(rc2[i]));
#pragma unroll
                for (int i = 0; i < 8; i++) v[i] = fminf(v[i], bf2f(rc3[i]));
            } else {
#pragma unroll
                for (int i = 0; i < 8; i++) v[i] = fmaxf(v[i], bf2f(rc1[i]));
#pragma unroll
                for (int i = 0; i < 8; i++) v[i] = fmaxf(v[i], bf2f(rc2[i]));
#pragma unroll
                for (int i = 0; i < 8; i++) v[i] = fmaxf(v[i], bf2f(rc3[i]));
            }
#pragma unroll
            for (int i = 0; i < 8; i++) av[i] = bfbits(v[i]);
        }
#pragma unroll
        for (int i = 0; i < 4; i++) { bv[i] = bfbits(rw0[i]); bv[4 + i] = bfbits(rw1[i]); }
    };
    auto loadTile = [&](int k1) {
        const int hh = k1 >> 6, d0 = (k1 & 63) + koff;
        const size_t aoff = ((size_t)(b * 12 + hh) * NT + tt) * 64 + d0;
        if (o == 0) {
            ry0 = *(const f4*)&ybuf[aoff];
            ry1 = *(const f4*)&ybuf[aoff + 4];
        } else {
            rc0 = *(const s8v*)&cb[aoff];
            rc1 = *(const s8v*)&cb[(size_t)1 * BHTD + aoff];
            rc2 = *(const s8v*)&cb[(size_t)2 * BHTD + aoff];
            rc3 = *(const s8v*)&cb[(size_t)3 * BHTD + aoff];
        }
        rw0 = *(const f4*)&Wp[wbase + k1];
        rw1 = *(const f4*)&Wp[wbase + k1 + 4];
    };

    // prologue: tile 0 -> regs -> convert -> buf 0
    loadTile(0);
    {
        s8v av, bv;
        convert(av, bv);
        *(s8v*)&sm3[0][rw * 40 + koff]        = av;
        *(s8v*)&sm3[0][2560 + rw * 40 + koff] = bv;
    }

    for (int it = 0; it < NC / 32; ++it) {
        const int cbuf = it & 1, nbuf = cbuf ^ 1;
        __syncthreads();
        const bool pf = (it + 1 < NC / 32);
        if (pf) loadTile((it + 1) * 32);
        const s8v af = *(const s8v*)&sm3[cbuf][(wv * 16 + l16) * 40 + quad * 8];
#pragma unroll
        for (int nt = 0; nt < 4; ++nt) {
            const s8v bf = *(const s8v*)&sm3[cbuf][2560 + (nt * 16 + l16) * 40 + quad * 8];
            acc[nt] = __builtin_amdgcn_mfma_f32_16x16x32_bf16(af, bf, acc[nt], 0, 0, 0);
        }
        if (pf) {
            s8v av, bv;
            convert(av, bv);
            *(s8v*)&sm3[nbuf][rw * 40 + koff]        = av;
            *(s8v*)&sm3[nbuf][2560 + rw * 40 + koff] = bv;
        }
    }
    __syncthreads();
#pragma unroll
    for (int nt = 0; nt < 4; ++nt)
#pragma unroll
        for (int r = 0; r < 4; ++r)
            Eb[(wv * 16 + quad * 4 + r) * 68 + nt * 16 + l16] = acc[nt][r];
    __syncthreads();
    const int cc = (t & 3) * 16;
#pragma unroll
    for (int i = 0; i < 4; ++i) {
        const f4 vo = *(const f4*)&Eb[rw * 68 + cc + 4 * i];
        *(f4*)&out[(size_t)o * BTC + (size_t)(n0 + rw) * NC + j0 + cc + 4 * i] = vo;
    }
}

extern "C" void kernel_launch(void* const* d_in, const int* in_sizes, int n_in,
                              void* d_out, int out_size, void* d_ws, size_t ws_size,
                              hipStream_t stream)
{
    const float* x  = (const float*)d_in[0];
    const float* xl = (const float*)d_in[1];
    const float* xu = (const float*)d_in[2];
    const float* Wa = (const float*)d_in[3];
    const float* Wp = (const float*)d_in[4];
    float* out = (float*)d_out;

    short* qkvb = (short*)d_ws;                       // 9*BHTD bf16  = 56.6 MB
    float* ybuf = (float*)(qkvb + (size_t)9 * BHTD);  // 1*BHTD f32   = 12.6 MB
    short* cand = (short*)(ybuf + (size_t)BHTD);      // 8*BHTD bf16  = 50.3 MB

    // prep arrays alias cand (dead until flash writes it; consumed by qkv_proj)
    short* xn = cand;                      // BTC shorts
    short* xm = cand + (size_t)1 * BHTD;   // BTC shorts
    short* xr = cand + (size_t)2 * BHTD;   // BTC shorts
    short* wb = cand + (size_t)3 * BHTD;   // NWA shorts (fits in BHTD)

    prep_cvt     <<<dim3(1536),      256, 0, stream>>>(x, xl, xu, Wa, xn, xm, xr, wb);
    qkv_proj_mfma<<<dim3(36, 64),    256, 0, stream>>>(xn, xm, xr, wb, qkvb);
    flash_mfma   <<<dim3(80, 24),    256, 0, stream>>>(qkvb, ybuf, cand);
    out_proj_mfma<<<dim3(12, 64, 3), 256, 0, stream>>>(ybuf, cand, Wp, out);
}

// Round 6
// 497.465 us; speedup vs baseline: 1.7316x; 1.0538x over previous
//
#include <hip/hip_runtime.h>
#include <hip/hip_bf16.h>
#include <cstdint>

typedef float f4  __attribute__((ext_vector_type(4)));
typedef short s8v __attribute__((ext_vector_type(8)));   // 8 bf16 (4 VGPRs)
typedef int   i4v __attribute__((ext_vector_type(4)));

#define BHTD 3145728    // B*H*T*D = 2*12*2048*64
#define BTC  3145728
#define NT   2048
#define NC   768
#define NWA  1769472    // 3C*C = 2304*768
#define NEG  -1e30f
// 0.125 (1/sqrt(64)) * log2(e): folded into Q at the producer so the flash
// kernel's scores are already in log2 domain (exp2 instead of expf, no scale mul)
#define QSCALE 0.18033688f

static __device__ __forceinline__ short bfbits(float f) {
    return __builtin_bit_cast(short, __float2bfloat16(f));
}
static __device__ __forceinline__ float bf2f(short s) {
    return __builtin_bit_cast(float, (int)(((unsigned int)(unsigned short)s) << 16));
}
static __device__ __forceinline__ float exp2fast(float x) {
    return __builtin_amdgcn_exp2f(x);
}
// row reductions across the 4 quads (lanes l16, l16+16, l16+32, l16+48)
static __device__ __forceinline__ float rowred_max(float x) {
    x = fmaxf(x, __shfl_xor(x, 16, 64));
    x = fmaxf(x, __shfl_xor(x, 32, 64));
    return x;
}
static __device__ __forceinline__ float rowred_sum(float x) {
    x += __shfl_xor(x, 16, 64);
    x += __shfl_xor(x, 32, 64);
    return x;
}

// ---------------------------------------------------------------------------
// Kernel 0: one-shot fp32->bf16 conversion. xn=x, xm=(xl+xu)/2, xr=(xu-xl)/2,
// wb=W. Removes the 36x-redundant per-block conversion from qkv_proj.
// ---------------------------------------------------------------------------
__global__ __launch_bounds__(256) void prep_cvt(
    const float* __restrict__ x, const float* __restrict__ xl,
    const float* __restrict__ xu, const float* __restrict__ W,
    short* __restrict__ xn, short* __restrict__ xm, short* __restrict__ xr,
    short* __restrict__ wb)
{
    const size_t flat = (size_t)blockIdx.x * 256 + threadIdx.x;
    const size_t i = flat * 8;        // 1536*256*8 == BTC exactly
    {
        const f4 a0 = *(const f4*)&x[i],  a1 = *(const f4*)&x[i + 4];
        const f4 l0 = *(const f4*)&xl[i], l1 = *(const f4*)&xl[i + 4];
        const f4 u0 = *(const f4*)&xu[i], u1 = *(const f4*)&xu[i + 4];
        s8v vn, vm, vr;
#pragma unroll
        for (int j = 0; j < 4; j++) {
            vn[j]     = bfbits(a0[j]);                   vn[4 + j] = bfbits(a1[j]);
            vm[j]     = bfbits(0.5f * (l0[j] + u0[j]));  vm[4 + j] = bfbits(0.5f * (l1[j] + u1[j]));
            vr[j]     = bfbits(0.5f * (u0[j] - l0[j]));  vr[4 + j] = bfbits(0.5f * (u1[j] - l1[j]));
        }
        *(s8v*)&xn[i] = vn;
        *(s8v*)&xm[i] = vm;
        *(s8v*)&xr[i] = vr;
    }
    if (flat < NWA / 8) {
        const size_t wi = flat * 8;
        const f4 w0 = *(const f4*)&W[wi], w1 = *(const f4*)&W[wi + 4];
        s8v vw;
#pragma unroll
        for (int j = 0; j < 4; j++) { vw[j] = bfbits(w0[j]); vw[4 + j] = bfbits(w1[j]); }
        *(s8v*)&wb[wi] = vw;
    }
}

// ---------------------------------------------------------------------------
// Kernel 1: MFMA QKV projection from pre-converted bf16 inputs.
// nom=xn@wb^T, mid=xm@wb^T, rad=xr@|wb|^T (|wb| derived in-reg).
// Outputs bf16: Q,K in [var][part][B,H,T,D]; V in [B,H,D,T].
// Q (p==0) pre-scaled by 0.125*log2e. Ping-pong LDS dbuf, ONE barrier/K-step.
// ---------------------------------------------------------------------------
__global__ __launch_bounds__(256) void qkv_proj_mfma(
    const short* __restrict__ xn, const short* __restrict__ xm,
    const short* __restrict__ xr, const short* __restrict__ wb,
    short* __restrict__ qkvb)
{
    // per-buffer layout (shorts): Ax=0, Am=2560, Ar=5120, Bw=7680 (each [64][40])
    __shared__ short sm[2][4 * 2560];   // 40 KB
    short* Eb = &sm[0][0];              // epilogue alias [64][72] (4608 shorts)

    const int j0 = blockIdx.x * 64;     // N in [0,2304)
    const int n0 = blockIdx.y * 64;     // M in [0,4096)
    const int t  = threadIdx.x;
    const int wv = t >> 6, lane = t & 63, quad = lane >> 4, l16 = lane & 15;
    const int rw = t >> 2, koff = (t & 3) * 8;

    f4 aN[4], aM[4], aR[4];
#pragma unroll
    for (int i = 0; i < 4; i++) { aN[i] = f4{0,0,0,0}; aM[i] = f4{0,0,0,0}; aR[i] = f4{0,0,0,0}; }

    const size_t abase = (size_t)(n0 + rw) * NC + koff;
    const size_t bbase = (size_t)(j0 + rw) * NC + koff;

    s8v rn, rm, rr, rb;
    rn = *(const s8v*)&xn[abase];
    rm = *(const s8v*)&xm[abase];
    rr = *(const s8v*)&xr[abase];
    rb = *(const s8v*)&wb[bbase];
    *(s8v*)&sm[0][rw * 40 + koff]        = rn;
    *(s8v*)&sm[0][2560 + rw * 40 + koff] = rm;
    *(s8v*)&sm[0][5120 + rw * 40 + koff] = rr;
    *(s8v*)&sm[0][7680 + rw * 40 + koff] = rb;

    for (int it = 0; it < NC / 32; ++it) {
        const int cb = it & 1, nb = cb ^ 1;
        __syncthreads();                       // buf[cb] complete
        const bool pf = (it + 1 < NC / 32);
        if (pf) {                              // issue next-tile loads early
            const size_t k1 = (size_t)(it + 1) * 32;
            rn = *(const s8v*)&xn[abase + k1];
            rm = *(const s8v*)&xm[abase + k1];
            rr = *(const s8v*)&xr[abase + k1];
            rb = *(const s8v*)&wb[bbase + k1];
        }
        const s8v fx = *(const s8v*)&sm[cb][(wv * 16 + l16) * 40 + quad * 8];
        const s8v fm = *(const s8v*)&sm[cb][2560 + (wv * 16 + l16) * 40 + quad * 8];
        const s8v fr = *(const s8v*)&sm[cb][5120 + (wv * 16 + l16) * 40 + quad * 8];
#pragma unroll
        for (int nt = 0; nt < 4; ++nt) {
            const s8v fb = *(const s8v*)&sm[cb][7680 + (nt * 16 + l16) * 40 + quad * 8];
            i4v bi = __builtin_bit_cast(i4v, fb);
#pragma unroll
            for (int i = 0; i < 4; i++) bi[i] &= 0x7fff7fff;
            const s8v fa = __builtin_bit_cast(s8v, bi);
            aN[nt] = __builtin_amdgcn_mfma_f32_16x16x32_bf16(fx, fb, aN[nt], 0, 0, 0);
            aM[nt] = __builtin_amdgcn_mfma_f32_16x16x32_bf16(fm, fb, aM[nt], 0, 0, 0);
            aR[nt] = __builtin_amdgcn_mfma_f32_16x16x32_bf16(fr, fa, aR[nt], 0, 0, 0);
        }
        if (pf) {                              // stage into buf[nb]
            *(s8v*)&sm[nb][rw * 40 + koff]        = rn;
            *(s8v*)&sm[nb][2560 + rw * 40 + koff] = rm;
            *(s8v*)&sm[nb][5120 + rw * 40 + koff] = rr;
            *(s8v*)&sm[nb][7680 + rw * 40 + koff] = rb;
        }
    }

    const int p = j0 / NC, hh = (j0 % NC) >> 6;
    const float osc = (p == 0) ? QSCALE : 1.0f;   // pre-scale Q for exp2-domain flash
    const int cc16 = (t & 3) * 16;
    for (int var = 0; var < 3; ++var) {
        __syncthreads();
#pragma unroll
        for (int nt = 0; nt < 4; ++nt)
#pragma unroll
            for (int r = 0; r < 4; ++r) {
                const float v = (var == 0) ? aN[nt][r]
                              : (var == 1) ? aM[nt][r] - aR[nt][r]
                                           : aM[nt][r] + aR[nt][r];
                Eb[(wv * 16 + quad * 4 + r) * 72 + nt * 16 + l16] = bfbits(v * osc);
            }
        __syncthreads();
        short* dst = qkvb + (size_t)(var * 3 + p) * BHTD;
        if (p < 2) {       // Q,K row-major [B,H,T,D]
            const int token = n0 + rw, b = token >> 11, tt = token & 2047;
            const size_t o = ((size_t)(b * 12 + hh) * NT + tt) * 64 + cc16;
            *(s8v*)&dst[o]     = *(const s8v*)&Eb[rw * 72 + cc16];
            *(s8v*)&dst[o + 8] = *(const s8v*)&Eb[rw * 72 + cc16 + 8];
        } else {           // V transposed [B,H,D,T]
            const int d = rw;
            s8v e0, e1;
#pragma unroll
            for (int i = 0; i < 8; i++) e0[i] = Eb[(cc16 + i) * 72 + d];
#pragma unroll
            for (int i = 0; i < 8; i++) e1[i] = Eb[(cc16 + 8 + i) * 72 + d];
            const int token0 = n0 + cc16, b = token0 >> 11, tt = token0 & 2047;
            const size_t o = ((size_t)(b * 12 + hh) * 64 + d) * NT + tt;
            *(s8v*)&dst[o]     = e0;
            *(s8v*)&dst[o + 8] = e1;
        }
    }
}

// ---------------------------------------------------------------------------
// Kernel 2: MFMA flash, merged nominal + 4 bound branches in one launch.
//   blockIdx.x encodes (qt heavy-first, z): x = (15-qt)*5 + z
// Block = 128 q-rows, 4 waves x 32 rows (2 m-tiles), K-tile 32.
// SWAPPED QK^T: S = mfma(K_frag, Q_frag) with row-permuted K fragment
// (sigma(m) = (m>>2)*8 + (m&3), +4 for the 2nd MFMA) so each lane holds
// P[kpos = quad*8 + 0..7] for ONE q-row (q = rowb + l16) — exactly the PV
// A-fragment layout. P stays in registers: NO Ps LDS round-trip.
// mi/li are per-lane row state; li is a per-quad partial, reduced once via
// shfl_xor(16/32) in the epilogue; 1/li redistributed to acc rows by shfl.
// Ping-pong LDS dbuf (Ks pad 68, Vs pad 40), ONE barrier per k-tile; T14
// reg prefetch; defer-max (T13) in exp2 domain; setprio around MFMA.
// ---------------------------------------------------------------------------
__global__ __launch_bounds__(256) void flash_mfma(
    const short* __restrict__ qkvb, float* __restrict__ ybuf,
    short* __restrict__ cand)
{
    const int bx = blockIdx.x;             // 0..79: heavy qt first across all z
    const int qt = 15 - bx / 5;
    const int z  = bx % 5;
    const int bh = blockIdx.y;
    const int q0 = qt * 128;
    const int t  = threadIdx.x;
    const int wv = t >> 6, lane = t & 63, quad = lane >> 4, l16 = lane & 15;
    const bool TWO = (z != 0);

    __shared__ short Ks[2][32 * 68];       // [buf][kpos][d] pad 68 (8.7 KB)
    __shared__ short Vs[2][2][64 * 40];    // [buf][sv][d][kpos] (20.5 KB)

    int sv, qvi, kvi, v0i, v1i;
    if (TWO) { sv = z; qvi = (sv + 1) >> 1; kvi = 2 - (sv & 1); v0i = 1; v1i = 2; }
    else     { sv = 0; qvi = 0; kvi = 0; v0i = 0; v1i = 0; }

    const size_t hb = (size_t)bh * (NT * 64);
    const short* Qp  = qkvb + (size_t)(qvi * 3 + 0) * BHTD + hb;  // [t][d] (pre-scaled)
    const short* Kp  = qkvb + (size_t)(kvi * 3 + 1) * BHTD + hb;  // [t][d]
    const short* V0p = qkvb + (size_t)(v0i * 3 + 2) * BHTD + hb;  // [d][t] !
    const short* V1p = qkvb + (size_t)(v1i * 3 + 2) * BHTD + hb;

    // Q fragments (serve as the MFMA B operand in the swapped product)
    s8v qf[2][2];
#pragma unroll
    for (int mt = 0; mt < 2; ++mt)
#pragma unroll
        for (int ch = 0; ch < 2; ++ch)
            qf[mt][ch] = *(const s8v*)&Qp[(size_t)(q0 + 32 * wv + 16 * mt + l16) * 64 + ch * 32 + quad * 8];

    float mi[2], li[2];                    // per-lane: row q = rowb + l16; li = quad-partial
    mi[0] = mi[1] = NEG; li[0] = li[1] = 0.f;
    f4 acc0[2][4], acc1[2][4];
#pragma unroll
    for (int mt = 0; mt < 2; ++mt)
#pragma unroll
        for (int i = 0; i < 4; ++i) { acc0[mt][i] = f4{0,0,0,0}; acc1[mt][i] = f4{0,0,0,0}; }

    const int ktn  = 4 * qt + 4;
    const int mykt = 4 * qt + wv + 1;      // last tile this wave's rows need
    const int skr = t >> 3, skc = (t & 7) * 8;   // K stage: 32 x 64
    const int svd = t >> 2, svc = (t & 3) * 8;   // V stage: 64 x 32
    const int sig = (l16 >> 2) * 8 + (l16 & 3);  // K A-frag row permutation

    // prologue: tile 0 -> regs -> buf 0
    s8v rK, rV0, rV1;
    rK  = *(const s8v*)&Kp[(size_t)skr * 64 + skc];
    rV0 = *(const s8v*)&V0p[(size_t)svd * NT + svc];
    if (TWO) rV1 = *(const s8v*)&V1p[(size_t)svd * NT + svc];
    *(s8v*)&Ks[0][skr * 68 + skc]    = rK;
    *(s8v*)&Vs[0][0][svd * 40 + svc] = rV0;
    if (TWO) *(s8v*)&Vs[0][1][svd * 40 + svc] = rV1;

    for (int kt = 0; kt < ktn; ++kt) {
        const int k0 = kt * 32;
        const int cb = kt & 1, nb = cb ^ 1;
        __syncthreads();                   // buf[cb] complete for all waves
        const bool pf = (kt + 1 < ktn);
        if (pf) {                          // issue next-tile loads early
            const int k1 = k0 + 32;
            rK  = *(const s8v*)&Kp[(size_t)(k1 + skr) * 64 + skc];
            rV0 = *(const s8v*)&V0p[(size_t)svd * NT + k1 + svc];
            if (TWO) rV1 = *(const s8v*)&V1p[(size_t)svd * NT + k1 + svc];
        }
        if (kt < mykt) {
            // ---- S^T = K Q^T (log2 domain): s[mt][nt][r] =
            //      P[kpos = k0 + quad*8 + nt*4 + r][q = rowb + l16] ----
            f4 s[2][2];
#pragma unroll
            for (int mt = 0; mt < 2; ++mt) { s[mt][0] = f4{0,0,0,0}; s[mt][1] = f4{0,0,0,0}; }
            __builtin_amdgcn_s_setprio(1);
#pragma unroll
            for (int nt = 0; nt < 2; ++nt)
#pragma unroll
                for (int ch = 0; ch < 2; ++ch) {
                    const s8v kf = *(const s8v*)&Ks[cb][(sig + nt * 4) * 68 + ch * 32 + quad * 8];
                    s[0][nt] = __builtin_amdgcn_mfma_f32_16x16x32_bf16(kf, qf[0][ch], s[0][nt], 0, 0, 0);
                    s[1][nt] = __builtin_amdgcn_mfma_f32_16x16x32_bf16(kf, qf[1][ch], s[1][nt], 0, 0, 0);
                }
            __builtin_amdgcn_s_setprio(0);

            // ---- softmax + in-register P pack, per m-tile ----
            s8v pa[2];
#pragma unroll
            for (int mt = 0; mt < 2; ++mt) {
                const int rowb = q0 + 32 * wv + 16 * mt;
                const int qrow = rowb + l16;
                float a[8];
#pragma unroll
                for (int nt = 0; nt < 2; ++nt)
#pragma unroll
                    for (int r = 0; r < 4; ++r) a[nt * 4 + r] = s[mt][nt][r];
                if (k0 + 31 > rowb) {
#pragma unroll
                    for (int nt = 0; nt < 2; ++nt)
#pragma unroll
                        for (int r = 0; r < 4; ++r)
                            if (k0 + quad * 8 + nt * 4 + r > qrow) a[nt * 4 + r] = NEG;
                }
                const float c = fmaxf(fmaxf(fmaxf(a[0], a[1]), fmaxf(a[2], a[3])),
                                      fmaxf(fmaxf(a[4], a[5]), fmaxf(a[6], a[7])));
                if (__any(c - mi[mt] > 8.0f)) {     // rare: row max grew
                    const float mx = rowred_max(c); // full-row max, quad-consistent
                    const float nm = fmaxf(mi[mt], mx);
                    const float al = exp2fast(mi[mt] - nm);
                    mi[mt] = nm;
                    li[mt] *= al;
#pragma unroll
                    for (int r = 0; r < 4; ++r) {
                        // al lives at lane l16 = acc row; uniform across quads
                        const float alr = __shfl(al, (lane & 48) | (quad * 4 + r), 64);
#pragma unroll
                        for (int dt = 0; dt < 4; ++dt) acc0[mt][dt][r] *= alr;
                        if (TWO) {
#pragma unroll
                            for (int dt = 0; dt < 4; ++dt) acc1[mt][dt][r] *= alr;
                        }
                    }
                }
                float p[8];
#pragma unroll
                for (int j = 0; j < 8; ++j) p[j] = exp2fast(a[j] - mi[mt]);  // <= 2^8
                li[mt] += ((p[0] + p[1]) + (p[2] + p[3])) + ((p[4] + p[5]) + (p[6] + p[7]));
                i4v pi;
#pragma unroll
                for (int jj = 0; jj < 4; ++jj)
                    pi[jj] = ((int)(unsigned short)bfbits(p[2 * jj + 1]) << 16)
                           | (int)(unsigned short)bfbits(p[2 * jj]);
                pa[mt] = __builtin_bit_cast(s8v, pi);
            }
            // ---- O += P V (pa is the A fragment directly) ----
            __builtin_amdgcn_s_setprio(1);
#pragma unroll
            for (int dt = 0; dt < 4; ++dt) {
                const s8v vf0 = *(const s8v*)&Vs[cb][0][(dt * 16 + l16) * 40 + quad * 8];
                acc0[0][dt] = __builtin_amdgcn_mfma_f32_16x16x32_bf16(pa[0], vf0, acc0[0][dt], 0, 0, 0);
                acc0[1][dt] = __builtin_amdgcn_mfma_f32_16x16x32_bf16(pa[1], vf0, acc0[1][dt], 0, 0, 0);
                if (TWO) {
                    const s8v vf1 = *(const s8v*)&Vs[cb][1][(dt * 16 + l16) * 40 + quad * 8];
                    acc1[0][dt] = __builtin_amdgcn_mfma_f32_16x16x32_bf16(pa[0], vf1, acc1[0][dt], 0, 0, 0);
                    acc1[1][dt] = __builtin_amdgcn_mfma_f32_16x16x32_bf16(pa[1], vf1, acc1[1][dt], 0, 0, 0);
                }
            }
            __builtin_amdgcn_s_setprio(0);
        }
        if (pf) {                          // stage next tile into buf[nb]
            *(s8v*)&Ks[nb][skr * 68 + skc]    = rK;
            *(s8v*)&Vs[nb][0][svd * 40 + svc] = rV0;
            if (TWO) *(s8v*)&Vs[nb][1][svd * 40 + svc] = rV1;
        }
    }

#pragma unroll
    for (int mt = 0; mt < 2; ++mt) {
        // total row sum (uniform across quads after reduce), then redistribute
        const float invq = 1.f / rowred_sum(li[mt]);
        float inv[4];
#pragma unroll
        for (int r = 0; r < 4; ++r)
            inv[r] = __shfl(invq, (lane & 48) | (quad * 4 + r), 64);
#pragma unroll
        for (int dt = 0; dt < 4; ++dt)
#pragma unroll
            for (int r = 0; r < 4; ++r) {
                const size_t o = hb + (size_t)(q0 + 32 * wv + 16 * mt + quad * 4 + r) * 64 + dt * 16 + l16;
                if (!TWO) {
                    ybuf[o] = acc0[mt][dt][r] * inv[r];
                } else {
                    const float xa = acc0[mt][dt][r] * inv[r];
                    const float xb = acc1[mt][dt][r] * inv[r];
                    cand[(size_t)(sv - 1) * BHTD + o] = bfbits(fminf(xa, xb));
                    cand[(size_t)(3 + sv) * BHTD + o] = bfbits(fmaxf(xa, xb));
                }
            }
    }
}

// ---------------------------------------------------------------------------
// Kernel 3: MFMA output projection. z=0: A=y fp32; z=1: A=min of 4 candLo;
// z=2: A=max of 4 candHi. B=Wp (bf16). out fp32 via LDS re-layout.
// Ping-pong LDS double buffer: ONE barrier per K-step.
// ---------------------------------------------------------------------------
__global__ __launch_bounds__(256) void out_proj_mfma(
    const float* __restrict__ ybuf, const short* __restrict__ cand,
    const float* __restrict__ Wp, float* __restrict__ out)
{
    // per-buffer layout (shorts): As=0, Bs=2560 (each [64][40])
    __shared__ short sm3[2][2 * 2560];      // 20.5 KB
    float* Eb = (float*)sm3;                // epilogue alias [64][68] (17.4 KB)

    const int o  = blockIdx.z;
    const int j0 = blockIdx.x * 64, n0 = blockIdx.y * 64;
    const int t  = threadIdx.x;
    const int wv = t >> 6, lane = t & 63, quad = lane >> 4, l16 = lane & 15;
    const int rw = t >> 2, koff = (t & 3) * 8;

    f4 acc[4];
#pragma unroll
    for (int i = 0; i < 4; i++) acc[i] = f4{0,0,0,0};

    const int token = n0 + rw, b = token >> 11, tt = token & 2047;
    const size_t wbase = (size_t)(j0 + rw) * NC + koff;
    const short* cb = cand + (size_t)(o == 1 ? 0 : 4) * BHTD;

    f4 ry0, ry1, rw0, rw1;
    s8v rc0, rc1, rc2, rc3;

    auto convert = [&](s8v& av, s8v& bv) {
        if (o == 0) {
#pragma unroll
            for (int i = 0; i < 4; i++) { av[i] = bfbits(ry0[i]); av[4 + i] = bfbits(ry1[i]); }
        } else {
            float v[8];
#pragma unroll
            for (int i = 0; i < 8; i++) v[i] = bf2f(rc0[i]);
            if (o == 1) {
#pragma unroll
                for (int i = 0; i < 8; i++) v[i] = fminf(v[i], bf2f(rc1[i]));
#pragma unroll
                for (int i = 0; i < 8; i++) v[i] = fminf(v[i], bf2f(rc2[i]));
#pragma unroll
                for (int i = 0; i < 8; i++) v[i] = fminf(v[i], bf2f(rc3[i]));
            } else {
#pragma unroll
                for (int i = 0; i < 8; i++) v[i] = fmaxf(v[i], bf2f(rc1[i]));
#pragma unroll
                for (int i = 0; i < 8; i++) v[i] = fmaxf(v[i], bf2f(rc2[i]));
#pragma unroll
                for (int i = 0; i < 8; i++) v[i] = fmaxf(v[i], bf2f(rc3[i]));
            }
#pragma unroll
            for (int i = 0; i < 8; i++) av[i] = bfbits(v[i]);
        }
#pragma unroll
        for (int i = 0; i < 4; i++) { bv[i] = bfbits(rw0[i]); bv[4 + i] = bfbits(rw1[i]); }
    };
    auto loadTile = [&](int k1) {
        const int hh = k1 >> 6, d0 = (k1 & 63) + koff;
        const size_t aoff = ((size_t)(b * 12 + hh) * NT + tt) * 64 + d0;
        if (o == 0) {
            ry0 = *(const f4*)&ybuf[aoff];
            ry1 = *(const f4*)&ybuf[aoff + 4];
        } else {
            rc0 = *(const s8v*)&cb[aoff];
            rc1 = *(const s8v*)&cb[(size_t)1 * BHTD + aoff];
            rc2 = *(const s8v*)&cb[(size_t)2 * BHTD + aoff];
            rc3 = *(const s8v*)&cb[(size_t)3 * BHTD + aoff];
        }
        rw0 = *(const f4*)&Wp[wbase + k1];
        rw1 = *(const f4*)&Wp[wbase + k1 + 4];
    };

    // prologue: tile 0 -> regs -> convert -> buf 0
    loadTile(0);
    {
        s8v av, bv;
        convert(av, bv);
        *(s8v*)&sm3[0][rw * 40 + koff]        = av;
        *(s8v*)&sm3[0][2560 + rw * 40 + koff] = bv;
    }

    for (int it = 0; it < NC / 32; ++it) {
        const int cbuf = it & 1, nbuf = cbuf ^ 1;
        __syncthreads();
        const bool pf = (it + 1 < NC / 32);
        if (pf) loadTile((it + 1) * 32);
        const s8v af = *(const s8v*)&sm3[cbuf][(wv * 16 + l16) * 40 + quad * 8];
#pragma unroll
        for (int nt = 0; nt < 4; ++nt) {
            const s8v bf = *(const s8v*)&sm3[cbuf][2560 + (nt * 16 + l16) * 40 + quad * 8];
            acc[nt] = __builtin_amdgcn_mfma_f32_16x16x32_bf16(af, bf, acc[nt], 0, 0, 0);
        }
        if (pf) {
            s8v av, bv;
            convert(av, bv);
            *(s8v*)&sm3[nbuf][rw * 40 + koff]        = av;
            *(s8v*)&sm3[nbuf][2560 + rw * 40 + koff] = bv;
        }
    }
    __syncthreads();
#pragma unroll
    for (int nt = 0; nt < 4; ++nt)
#pragma unroll
        for (int r = 0; r < 4; ++r)
            Eb[(wv * 16 + quad * 4 + r) * 68 + nt * 16 + l16] = acc[nt][r];
    __syncthreads();
    const int cc = (t & 3) * 16;
#pragma unroll
    for (int i = 0; i < 4; ++i) {
        const f4 vo = *(const f4*)&Eb[rw * 68 + cc + 4 * i];
        *(f4*)&out[(size_t)o * BTC + (size_t)(n0 + rw) * NC + j0 + cc + 4 * i] = vo;
    }
}

extern "C" void kernel_launch(void* const* d_in, const int* in_sizes, int n_in,
                              void* d_out, int out_size, void* d_ws, size_t ws_size,
                              hipStream_t stream)
{
    const float* x  = (const float*)d_in[0];
    const float* xl = (const float*)d_in[1];
    const float* xu = (const float*)d_in[2];
    const float* Wa = (const float*)d_in[3];
    const float* Wp = (const float*)d_in[4];
    float* out = (float*)d_out;

    short* qkvb = (short*)d_ws;                       // 9*BHTD bf16  = 56.6 MB
    float* ybuf = (float*)(qkvb + (size_t)9 * BHTD);  // 1*BHTD f32   = 12.6 MB
    short* cand = (short*)(ybuf + (size_t)BHTD);      // 8*BHTD bf16  = 50.3 MB

    // prep arrays alias cand (dead until flash writes it; consumed by qkv_proj)
    short* xn = cand;                      // BTC shorts
    short* xm = cand + (size_t)1 * BHTD;   // BTC shorts
    short* xr = cand + (size_t)2 * BHTD;   // BTC shorts
    short* wb = cand + (size_t)3 * BHTD;   // NWA shorts (fits in BHTD)

    prep_cvt     <<<dim3(1536),      256, 0, stream>>>(x, xl, xu, Wa, xn, xm, xr, wb);
    qkv_proj_mfma<<<dim3(36, 64),    256, 0, stream>>>(xn, xm, xr, wb, qkvb);
    flash_mfma   <<<dim3(80, 24),    256, 0, stream>>>(qkvb, ybuf, cand);
    out_proj_mfma<<<dim3(12, 64, 3), 256, 0, stream>>>(ybuf, cand, Wp, out);
}

// Round 7
// 480.400 us; speedup vs baseline: 1.7932x; 1.0355x over previous
//
#include <hip/hip_runtime.h>
#include <hip/hip_bf16.h>
#include <cstdint>

typedef float f4  __attribute__((ext_vector_type(4)));
typedef short s8v __attribute__((ext_vector_type(8)));   // 8 bf16 (4 VGPRs)
typedef int   i4v __attribute__((ext_vector_type(4)));

#define BHTD 3145728    // B*H*T*D = 2*12*2048*64
#define BTC  3145728
#define NT   2048
#define NC   768
#define NWA  1769472    // 3C*C = 2304*768
#define NEG  -1e30f
// 0.125 (1/sqrt(64)) * log2(e): folded into Q at the producer so the flash
// kernel's scores are already in log2 domain (exp2 instead of expf, no scale mul)
#define QSCALE 0.18033688f

static __device__ __forceinline__ short bfbits(float f) {
    return __builtin_bit_cast(short, __float2bfloat16(f));
}
static __device__ __forceinline__ float bf2f(short s) {
    return __builtin_bit_cast(float, (int)(((unsigned int)(unsigned short)s) << 16));
}
static __device__ __forceinline__ float exp2fast(float x) {
    return __builtin_amdgcn_exp2f(x);
}
// row reductions across the 4 quads (lanes l16, l16+16, l16+32, l16+48)
static __device__ __forceinline__ float rowred_max(float x) {
    x = fmaxf(x, __shfl_xor(x, 16, 64));
    x = fmaxf(x, __shfl_xor(x, 32, 64));
    return x;
}
static __device__ __forceinline__ float rowred_sum(float x) {
    x += __shfl_xor(x, 16, 64);
    x += __shfl_xor(x, 32, 64);
    return x;
}

// ---------------------------------------------------------------------------
// Kernel 0: one-shot fp32->bf16 conversion. xn=x, xm=(xl+xu)/2, xr=(xu-xl)/2,
// wb=W. Removes the 36x-redundant per-block conversion from qkv_proj.
// ---------------------------------------------------------------------------
__global__ __launch_bounds__(256) void prep_cvt(
    const float* __restrict__ x, const float* __restrict__ xl,
    const float* __restrict__ xu, const float* __restrict__ W,
    short* __restrict__ xn, short* __restrict__ xm, short* __restrict__ xr,
    short* __restrict__ wb)
{
    const size_t flat = (size_t)blockIdx.x * 256 + threadIdx.x;
    const size_t i = flat * 8;        // 1536*256*8 == BTC exactly
    {
        const f4 a0 = *(const f4*)&x[i],  a1 = *(const f4*)&x[i + 4];
        const f4 l0 = *(const f4*)&xl[i], l1 = *(const f4*)&xl[i + 4];
        const f4 u0 = *(const f4*)&xu[i], u1 = *(const f4*)&xu[i + 4];
        s8v vn, vm, vr;
#pragma unroll
        for (int j = 0; j < 4; j++) {
            vn[j]     = bfbits(a0[j]);                   vn[4 + j] = bfbits(a1[j]);
            vm[j]     = bfbits(0.5f * (l0[j] + u0[j]));  vm[4 + j] = bfbits(0.5f * (l1[j] + u1[j]));
            vr[j]     = bfbits(0.5f * (u0[j] - l0[j]));  vr[4 + j] = bfbits(0.5f * (u1[j] - l1[j]));
        }
        *(s8v*)&xn[i] = vn;
        *(s8v*)&xm[i] = vm;
        *(s8v*)&xr[i] = vr;
    }
    if (flat < NWA / 8) {
        const size_t wi = flat * 8;
        const f4 w0 = *(const f4*)&W[wi], w1 = *(const f4*)&W[wi + 4];
        s8v vw;
#pragma unroll
        for (int j = 0; j < 4; j++) { vw[j] = bfbits(w0[j]); vw[4 + j] = bfbits(w1[j]); }
        *(s8v*)&wb[wi] = vw;
    }
}

// ---------------------------------------------------------------------------
// Kernel 1: MFMA QKV projection from pre-converted bf16 inputs.
// nom=xn@wb^T, mid=xm@wb^T, rad=xr@|wb|^T (|wb| derived in-reg).
// Outputs bf16: Q,K in [var][part][B,H,T,D]; V in [B,H,D,T].
// Q (p==0) pre-scaled by 0.125*log2e. Ping-pong LDS dbuf, ONE barrier/K-step.
// ---------------------------------------------------------------------------
__global__ __launch_bounds__(256) void qkv_proj_mfma(
    const short* __restrict__ xn, const short* __restrict__ xm,
    const short* __restrict__ xr, const short* __restrict__ wb,
    short* __restrict__ qkvb)
{
    // per-buffer layout (shorts): Ax=0, Am=2560, Ar=5120, Bw=7680 (each [64][40])
    __shared__ short sm[2][4 * 2560];   // 40 KB
    short* Eb = &sm[0][0];              // epilogue alias [64][72] (4608 shorts)

    const int j0 = blockIdx.x * 64;     // N in [0,2304)
    const int n0 = blockIdx.y * 64;     // M in [0,4096)
    const int t  = threadIdx.x;
    const int wv = t >> 6, lane = t & 63, quad = lane >> 4, l16 = lane & 15;
    const int rw = t >> 2, koff = (t & 3) * 8;

    f4 aN[4], aM[4], aR[4];
#pragma unroll
    for (int i = 0; i < 4; i++) { aN[i] = f4{0,0,0,0}; aM[i] = f4{0,0,0,0}; aR[i] = f4{0,0,0,0}; }

    const size_t abase = (size_t)(n0 + rw) * NC + koff;
    const size_t bbase = (size_t)(j0 + rw) * NC + koff;

    s8v rn, rm, rr, rb;
    rn = *(const s8v*)&xn[abase];
    rm = *(const s8v*)&xm[abase];
    rr = *(const s8v*)&xr[abase];
    rb = *(const s8v*)&wb[bbase];
    *(s8v*)&sm[0][rw * 40 + koff]        = rn;
    *(s8v*)&sm[0][2560 + rw * 40 + koff] = rm;
    *(s8v*)&sm[0][5120 + rw * 40 + koff] = rr;
    *(s8v*)&sm[0][7680 + rw * 40 + koff] = rb;

    for (int it = 0; it < NC / 32; ++it) {
        const int cb = it & 1, nb = cb ^ 1;
        __syncthreads();                       // buf[cb] complete
        const bool pf = (it + 1 < NC / 32);
        if (pf) {                              // issue next-tile loads early
            const size_t k1 = (size_t)(it + 1) * 32;
            rn = *(const s8v*)&xn[abase + k1];
            rm = *(const s8v*)&xm[abase + k1];
            rr = *(const s8v*)&xr[abase + k1];
            rb = *(const s8v*)&wb[bbase + k1];
        }
        const s8v fx = *(const s8v*)&sm[cb][(wv * 16 + l16) * 40 + quad * 8];
        const s8v fm = *(const s8v*)&sm[cb][2560 + (wv * 16 + l16) * 40 + quad * 8];
        const s8v fr = *(const s8v*)&sm[cb][5120 + (wv * 16 + l16) * 40 + quad * 8];
#pragma unroll
        for (int nt = 0; nt < 4; ++nt) {
            const s8v fb = *(const s8v*)&sm[cb][7680 + (nt * 16 + l16) * 40 + quad * 8];
            i4v bi = __builtin_bit_cast(i4v, fb);
#pragma unroll
            for (int i = 0; i < 4; i++) bi[i] &= 0x7fff7fff;
            const s8v fa = __builtin_bit_cast(s8v, bi);
            aN[nt] = __builtin_amdgcn_mfma_f32_16x16x32_bf16(fx, fb, aN[nt], 0, 0, 0);
            aM[nt] = __builtin_amdgcn_mfma_f32_16x16x32_bf16(fm, fb, aM[nt], 0, 0, 0);
            aR[nt] = __builtin_amdgcn_mfma_f32_16x16x32_bf16(fr, fa, aR[nt], 0, 0, 0);
        }
        if (pf) {                              // stage into buf[nb]
            *(s8v*)&sm[nb][rw * 40 + koff]        = rn;
            *(s8v*)&sm[nb][2560 + rw * 40 + koff] = rm;
            *(s8v*)&sm[nb][5120 + rw * 40 + koff] = rr;
            *(s8v*)&sm[nb][7680 + rw * 40 + koff] = rb;
        }
    }

    const int p = j0 / NC, hh = (j0 % NC) >> 6;
    const float osc = (p == 0) ? QSCALE : 1.0f;   // pre-scale Q for exp2-domain flash
    const int cc16 = (t & 3) * 16;
    for (int var = 0; var < 3; ++var) {
        __syncthreads();
#pragma unroll
        for (int nt = 0; nt < 4; ++nt)
#pragma unroll
            for (int r = 0; r < 4; ++r) {
                const float v = (var == 0) ? aN[nt][r]
                              : (var == 1) ? aM[nt][r] - aR[nt][r]
                                           : aM[nt][r] + aR[nt][r];
                Eb[(wv * 16 + quad * 4 + r) * 72 + nt * 16 + l16] = bfbits(v * osc);
            }
        __syncthreads();
        short* dst = qkvb + (size_t)(var * 3 + p) * BHTD;
        if (p < 2) {       // Q,K row-major [B,H,T,D]
            const int token = n0 + rw, b = token >> 11, tt = token & 2047;
            const size_t o = ((size_t)(b * 12 + hh) * NT + tt) * 64 + cc16;
            *(s8v*)&dst[o]     = *(const s8v*)&Eb[rw * 72 + cc16];
            *(s8v*)&dst[o + 8] = *(const s8v*)&Eb[rw * 72 + cc16 + 8];
        } else {           // V transposed [B,H,D,T]
            const int d = rw;
            s8v e0, e1;
#pragma unroll
            for (int i = 0; i < 8; i++) e0[i] = Eb[(cc16 + i) * 72 + d];
#pragma unroll
            for (int i = 0; i < 8; i++) e1[i] = Eb[(cc16 + 8 + i) * 72 + d];
            const int token0 = n0 + cc16, b = token0 >> 11, tt = token0 & 2047;
            const size_t o = ((size_t)(b * 12 + hh) * 64 + d) * NT + tt;
            *(s8v*)&dst[o]     = e0;
            *(s8v*)&dst[o + 8] = e1;
        }
    }
}

// ---------------------------------------------------------------------------
// Kernel 2: MFMA flash, merged nominal + 4 bound branches in one launch.
// LOAD-BALANCED: blockIdx.x encodes (pair p in 0..7, z in 0..4); each block
// processes q-tiles p AND 15-p sequentially -> uniform 68 kt-iters/block.
// Grid = 40 x 24 = 960 blocks <= 1024 residency capacity (4 blocks/CU at
// 116 VGPR): whole kernel runs as one fully-resident round (~15 waves/CU).
// Block = 128 q-rows, 4 waves x 32 rows (2 m-tiles), K-tile 32.
// SWAPPED QK^T: S = mfma(K_frag, Q_frag) with row-permuted K fragment
// (sigma(m) = (m>>2)*8 + (m&3), +4 for the 2nd MFMA) so each lane holds
// P[kpos = quad*8 + 0..7] for ONE q-row (q = rowb + l16) — exactly the PV
// A-fragment layout. P stays in registers: NO Ps LDS round-trip.
// mi/li per-lane row state; li quad-partial, reduced in epilogue.
// Ping-pong LDS dbuf, ONE barrier/k-tile; T14 reg prefetch; T13 defer-max;
// setprio around MFMA clusters.
// ---------------------------------------------------------------------------
__global__ __launch_bounds__(256) void flash_mfma(
    const short* __restrict__ qkvb, float* __restrict__ ybuf,
    short* __restrict__ cand)
{
    const int bx = blockIdx.x;             // 0..39: pair x z
    const int pr = bx / 5;                 // 0..7
    const int z  = bx % 5;
    const int bh = blockIdx.y;
    const int t  = threadIdx.x;
    const int wv = t >> 6, lane = t & 63, quad = lane >> 4, l16 = lane & 15;
    const bool TWO = (z != 0);

    __shared__ short Ks[2][32 * 68];       // [buf][kpos][d] pad 68 (8.7 KB)
    __shared__ short Vs[2][2][64 * 40];    // [buf][sv][d][kpos] (20.5 KB)

    int sv, qvi, kvi, v0i, v1i;
    if (TWO) { sv = z; qvi = (sv + 1) >> 1; kvi = 2 - (sv & 1); v0i = 1; v1i = 2; }
    else     { sv = 0; qvi = 0; kvi = 0; v0i = 0; v1i = 0; }

    const size_t hb = (size_t)bh * (NT * 64);
    const short* Qp  = qkvb + (size_t)(qvi * 3 + 0) * BHTD + hb;  // [t][d] (pre-scaled)
    const short* Kp  = qkvb + (size_t)(kvi * 3 + 1) * BHTD + hb;  // [t][d]
    const short* V0p = qkvb + (size_t)(v0i * 3 + 2) * BHTD + hb;  // [d][t] !
    const short* V1p = qkvb + (size_t)(v1i * 3 + 2) * BHTD + hb;

    const int skr = t >> 3, skc = (t & 7) * 8;   // K stage: 32 x 64
    const int svd = t >> 2, svc = (t & 3) * 8;   // V stage: 64 x 32
    const int sig = (l16 >> 2) * 8 + (l16 & 3);  // K A-frag row permutation

    for (int half = 0; half < 2; ++half) {
        const int qt = half ? (15 - pr) : pr;
        const int q0 = qt * 128;

        // Q fragments (serve as the MFMA B operand in the swapped product)
        s8v qf[2][2];
#pragma unroll
        for (int mt = 0; mt < 2; ++mt)
#pragma unroll
            for (int ch = 0; ch < 2; ++ch)
                qf[mt][ch] = *(const s8v*)&Qp[(size_t)(q0 + 32 * wv + 16 * mt + l16) * 64 + ch * 32 + quad * 8];

        float mi[2], li[2];                // per-lane: row q = rowb + l16; li = quad-partial
        mi[0] = mi[1] = NEG; li[0] = li[1] = 0.f;
        f4 acc0[2][4], acc1[2][4];
#pragma unroll
        for (int mt = 0; mt < 2; ++mt)
#pragma unroll
            for (int i = 0; i < 4; ++i) { acc0[mt][i] = f4{0,0,0,0}; acc1[mt][i] = f4{0,0,0,0}; }

        const int ktn  = 4 * qt + 4;
        const int mykt = 4 * qt + wv + 1;  // last tile this wave's rows need

        // prologue: barrier (protect prior half's live buffers), tile 0 -> buf 0
        __syncthreads();
        s8v rK, rV0, rV1;
        rK  = *(const s8v*)&Kp[(size_t)skr * 64 + skc];
        rV0 = *(const s8v*)&V0p[(size_t)svd * NT + svc];
        if (TWO) rV1 = *(const s8v*)&V1p[(size_t)svd * NT + svc];
        *(s8v*)&Ks[0][skr * 68 + skc]    = rK;
        *(s8v*)&Vs[0][0][svd * 40 + svc] = rV0;
        if (TWO) *(s8v*)&Vs[0][1][svd * 40 + svc] = rV1;

        for (int kt = 0; kt < ktn; ++kt) {
            const int k0 = kt * 32;
            const int cb = kt & 1, nb = cb ^ 1;
            __syncthreads();               // buf[cb] complete for all waves
            const bool pf = (kt + 1 < ktn);
            if (pf) {                      // issue next-tile loads early
                const int k1 = k0 + 32;
                rK  = *(const s8v*)&Kp[(size_t)(k1 + skr) * 64 + skc];
                rV0 = *(const s8v*)&V0p[(size_t)svd * NT + k1 + svc];
                if (TWO) rV1 = *(const s8v*)&V1p[(size_t)svd * NT + k1 + svc];
            }
            if (kt < mykt) {
                // ---- S^T = K Q^T (log2 domain): s[mt][nt][r] =
                //      P[kpos = k0 + quad*8 + nt*4 + r][q = rowb + l16] ----
                f4 s[2][2];
#pragma unroll
                for (int mt = 0; mt < 2; ++mt) { s[mt][0] = f4{0,0,0,0}; s[mt][1] = f4{0,0,0,0}; }
                __builtin_amdgcn_s_setprio(1);
#pragma unroll
                for (int nt = 0; nt < 2; ++nt)
#pragma unroll
                    for (int ch = 0; ch < 2; ++ch) {
                        const s8v kf = *(const s8v*)&Ks[cb][(sig + nt * 4) * 68 + ch * 32 + quad * 8];
                        s[0][nt] = __builtin_amdgcn_mfma_f32_16x16x32_bf16(kf, qf[0][ch], s[0][nt], 0, 0, 0);
                        s[1][nt] = __builtin_amdgcn_mfma_f32_16x16x32_bf16(kf, qf[1][ch], s[1][nt], 0, 0, 0);
                    }
                __builtin_amdgcn_s_setprio(0);

                // ---- softmax + in-register P pack, per m-tile ----
                s8v pa[2];
#pragma unroll
                for (int mt = 0; mt < 2; ++mt) {
                    const int rowb = q0 + 32 * wv + 16 * mt;
                    const int qrow = rowb + l16;
                    float a[8];
#pragma unroll
                    for (int nt = 0; nt < 2; ++nt)
#pragma unroll
                        for (int r = 0; r < 4; ++r) a[nt * 4 + r] = s[mt][nt][r];
                    if (k0 + 31 > rowb) {
#pragma unroll
                        for (int nt = 0; nt < 2; ++nt)
#pragma unroll
                            for (int r = 0; r < 4; ++r)
                                if (k0 + quad * 8 + nt * 4 + r > qrow) a[nt * 4 + r] = NEG;
                    }
                    const float c = fmaxf(fmaxf(fmaxf(a[0], a[1]), fmaxf(a[2], a[3])),
                                          fmaxf(fmaxf(a[4], a[5]), fmaxf(a[6], a[7])));
                    if (__any(c - mi[mt] > 8.0f)) {     // rare: row max grew
                        const float mx = rowred_max(c); // full-row max, quad-consistent
                        const float nm = fmaxf(mi[mt], mx);
                        const float al = exp2fast(mi[mt] - nm);
                        mi[mt] = nm;
                        li[mt] *= al;
#pragma unroll
                        for (int r = 0; r < 4; ++r) {
                            // al lives at lane l16 = acc row; uniform across quads
                            const float alr = __shfl(al, (lane & 48) | (quad * 4 + r), 64);
#pragma unroll
                            for (int dt = 0; dt < 4; ++dt) acc0[mt][dt][r] *= alr;
                            if (TWO) {
#pragma unroll
                                for (int dt = 0; dt < 4; ++dt) acc1[mt][dt][r] *= alr;
                            }
                        }
                    }
                    float p[8];
#pragma unroll
                    for (int j = 0; j < 8; ++j) p[j] = exp2fast(a[j] - mi[mt]);  // <= 2^8
                    li[mt] += ((p[0] + p[1]) + (p[2] + p[3])) + ((p[4] + p[5]) + (p[6] + p[7]));
                    i4v pi;
#pragma unroll
                    for (int jj = 0; jj < 4; ++jj)
                        pi[jj] = ((int)(unsigned short)bfbits(p[2 * jj + 1]) << 16)
                               | (int)(unsigned short)bfbits(p[2 * jj]);
                    pa[mt] = __builtin_bit_cast(s8v, pi);
                }
                // ---- O += P V (pa is the A fragment directly) ----
                __builtin_amdgcn_s_setprio(1);
#pragma unroll
                for (int dt = 0; dt < 4; ++dt) {
                    const s8v vf0 = *(const s8v*)&Vs[cb][0][(dt * 16 + l16) * 40 + quad * 8];
                    acc0[0][dt] = __builtin_amdgcn_mfma_f32_16x16x32_bf16(pa[0], vf0, acc0[0][dt], 0, 0, 0);
                    acc0[1][dt] = __builtin_amdgcn_mfma_f32_16x16x32_bf16(pa[1], vf0, acc0[1][dt], 0, 0, 0);
                    if (TWO) {
                        const s8v vf1 = *(const s8v*)&Vs[cb][1][(dt * 16 + l16) * 40 + quad * 8];
                        acc1[0][dt] = __builtin_amdgcn_mfma_f32_16x16x32_bf16(pa[0], vf1, acc1[0][dt], 0, 0, 0);
                        acc1[1][dt] = __builtin_amdgcn_mfma_f32_16x16x32_bf16(pa[1], vf1, acc1[1][dt], 0, 0, 0);
                    }
                }
                __builtin_amdgcn_s_setprio(0);
            }
            if (pf) {                      // stage next tile into buf[nb]
                *(s8v*)&Ks[nb][skr * 68 + skc]    = rK;
                *(s8v*)&Vs[nb][0][svd * 40 + svc] = rV0;
                if (TWO) *(s8v*)&Vs[nb][1][svd * 40 + svc] = rV1;
            }
        }

#pragma unroll
        for (int mt = 0; mt < 2; ++mt) {
            // total row sum (uniform across quads after reduce), then redistribute
            const float invq = 1.f / rowred_sum(li[mt]);
            float inv[4];
#pragma unroll
            for (int r = 0; r < 4; ++r)
                inv[r] = __shfl(invq, (lane & 48) | (quad * 4 + r), 64);
#pragma unroll
            for (int dt = 0; dt < 4; ++dt)
#pragma unroll
                for (int r = 0; r < 4; ++r) {
                    const size_t o = hb + (size_t)(q0 + 32 * wv + 16 * mt + quad * 4 + r) * 64 + dt * 16 + l16;
                    if (!TWO) {
                        ybuf[o] = acc0[mt][dt][r] * inv[r];
                    } else {
                        const float xa = acc0[mt][dt][r] * inv[r];
                        const float xb = acc1[mt][dt][r] * inv[r];
                        cand[(size_t)(sv - 1) * BHTD + o] = bfbits(fminf(xa, xb));
                        cand[(size_t)(3 + sv) * BHTD + o] = bfbits(fmaxf(xa, xb));
                    }
                }
        }
    }
}

// ---------------------------------------------------------------------------
// Kernel 3: MFMA output projection. z=0: A=y fp32; z=1: A=min of 4 candLo;
// z=2: A=max of 4 candHi. B=Wp (bf16). out fp32 via LDS re-layout.
// Ping-pong LDS double buffer: ONE barrier per K-step.
// ---------------------------------------------------------------------------
__global__ __launch_bounds__(256) void out_proj_mfma(
    const float* __restrict__ ybuf, const short* __restrict__ cand,
    const float* __restrict__ Wp, float* __restrict__ out)
{
    // per-buffer layout (shorts): As=0, Bs=2560 (each [64][40])
    __shared__ short sm3[2][2 * 2560];      // 20.5 KB
    float* Eb = (float*)sm3;                // epilogue alias [64][68] (17.4 KB)

    const int o  = blockIdx.z;
    const int j0 = blockIdx.x * 64, n0 = blockIdx.y * 64;
    const int t  = threadIdx.x;
    const int wv = t >> 6, lane = t & 63, quad = lane >> 4, l16 = lane & 15;
    const int rw = t >> 2, koff = (t & 3) * 8;

    f4 acc[4];
#pragma unroll
    for (int i = 0; i < 4; i++) acc[i] = f4{0,0,0,0};

    const int token = n0 + rw, b = token >> 11, tt = token & 2047;
    const size_t wbase = (size_t)(j0 + rw) * NC + koff;
    const short* cb = cand + (size_t)(o == 1 ? 0 : 4) * BHTD;

    f4 ry0, ry1, rw0, rw1;
    s8v rc0, rc1, rc2, rc3;

    auto convert = [&](s8v& av, s8v& bv) {
        if (o == 0) {
#pragma unroll
            for (int i = 0; i < 4; i++) { av[i] = bfbits(ry0[i]); av[4 + i] = bfbits(ry1[i]); }
        } else {
            float v[8];
#pragma unroll
            for (int i = 0; i < 8; i++) v[i] = bf2f(rc0[i]);
            if (o == 1) {
#pragma unroll
                for (int i = 0; i < 8; i++) v[i] = fminf(v[i], bf2f(rc1[i]));
#pragma unroll
                for (int i = 0; i < 8; i++) v[i] = fminf(v[i], bf2f(rc2[i]));
#pragma unroll
                for (int i = 0; i < 8; i++) v[i] = fminf(v[i], bf2f(rc3[i]));
            } else {
#pragma unroll
                for (int i = 0; i < 8; i++) v[i] = fmaxf(v[i], bf2f(rc1[i]));
#pragma unroll
                for (int i = 0; i < 8; i++) v[i] = fmaxf(v[i], bf2f(rc2[i]));
#pragma unroll
                for (int i = 0; i < 8; i++) v[i] = fmaxf(v[i], bf2f(rc3[i]));
            }
#pragma unroll
            for (int i = 0; i < 8; i++) av[i] = bfbits(v[i]);
        }
#pragma unroll
        for (int i = 0; i < 4; i++) { bv[i] = bfbits(rw0[i]); bv[4 + i] = bfbits(rw1[i]); }
    };
    auto loadTile = [&](int k1) {
        const int hh = k1 >> 6, d0 = (k1 & 63) + koff;
        const size_t aoff = ((size_t)(b * 12 + hh) * NT + tt) * 64 + d0;
        if (o == 0) {
            ry0 = *(const f4*)&ybuf[aoff];
            ry1 = *(const f4*)&ybuf[aoff + 4];
        } else {
            rc0 = *(const s8v*)&cb[aoff];
            rc1 = *(const s8v*)&cb[(size_t)1 * BHTD + aoff];
            rc2 = *(const s8v*)&cb[(size_t)2 * BHTD + aoff];
            rc3 = *(const s8v*)&cb[(size_t)3 * BHTD + aoff];
        }
        rw0 = *(const f4*)&Wp[wbase + k1];
        rw1 = *(const f4*)&Wp[wbase + k1 + 4];
    };

    // prologue: tile 0 -> regs -> convert -> buf 0
    loadTile(0);
    {
        s8v av, bv;
        convert(av, bv);
        *(s8v*)&sm3[0][rw * 40 + koff]        = av;
        *(s8v*)&sm3[0][2560 + rw * 40 + koff] = bv;
    }

    for (int it = 0; it < NC / 32; ++it) {
        const int cbuf = it & 1, nbuf = cbuf ^ 1;
        __syncthreads();
        const bool pf = (it + 1 < NC / 32);
        if (pf) loadTile((it + 1) * 32);
        const s8v af = *(const s8v*)&sm3[cbuf][(wv * 16 + l16) * 40 + quad * 8];
#pragma unroll
        for (int nt = 0; nt < 4; ++nt) {
            const s8v bf = *(const s8v*)&sm3[cbuf][2560 + (nt * 16 + l16) * 40 + quad * 8];
            acc[nt] = __builtin_amdgcn_mfma_f32_16x16x32_bf16(af, bf, acc[nt], 0, 0, 0);
        }
        if (pf) {
            s8v av, bv;
            convert(av, bv);
            *(s8v*)&sm3[nbuf][rw * 40 + koff]        = av;
            *(s8v*)&sm3[nbuf][2560 + rw * 40 + koff] = bv;
        }
    }
    __syncthreads();
#pragma unroll
    for (int nt = 0; nt < 4; ++nt)
#pragma unroll
        for (int r = 0; r < 4; ++r)
            Eb[(wv * 16 + quad * 4 + r) * 68 + nt * 16 + l16] = acc[nt][r];
    __syncthreads();
    const int cc = (t & 3) * 16;
#pragma unroll
    for (int i = 0; i < 4; ++i) {
        const f4 vo = *(const f4*)&Eb[rw * 68 + cc + 4 * i];
        *(f4*)&out[(size_t)o * BTC + (size_t)(n0 + rw) * NC + j0 + cc + 4 * i] = vo;
    }
}

extern "C" void kernel_launch(void* const* d_in, const int* in_sizes, int n_in,
                              void* d_out, int out_size, void* d_ws, size_t ws_size,
                              hipStream_t stream)
{
    const float* x  = (const float*)d_in[0];
    const float* xl = (const float*)d_in[1];
    const float* xu = (const float*)d_in[2];
    const float* Wa = (const float*)d_in[3];
    const float* Wp = (const float*)d_in[4];
    float* out = (float*)d_out;

    short* qkvb = (short*)d_ws;                       // 9*BHTD bf16  = 56.6 MB
    float* ybuf = (float*)(qkvb + (size_t)9 * BHTD);  // 1*BHTD f32   = 12.6 MB
    short* cand = (short*)(ybuf + (size_t)BHTD);      // 8*BHTD bf16  = 50.3 MB

    // prep arrays alias cand (dead until flash writes it; consumed by qkv_proj)
    short* xn = cand;                      // BTC shorts
    short* xm = cand + (size_t)1 * BHTD;   // BTC shorts
    short* xr = cand + (size_t)2 * BHTD;   // BTC shorts
    short* wb = cand + (size_t)3 * BHTD;   // NWA shorts (fits in BHTD)

    prep_cvt     <<<dim3(1536),      256, 0, stream>>>(x, xl, xu, Wa, xn, xm, xr, wb);
    qkv_proj_mfma<<<dim3(36, 64),    256, 0, stream>>>(xn, xm, xr, wb, qkvb);
    flash_mfma   <<<dim3(40, 24),    256, 0, stream>>>(qkvb, ybuf, cand);
    out_proj_mfma<<<dim3(12, 64, 3), 256, 0, stream>>>(ybuf, cand, Wp, out);
}

// Round 8
// 448.850 us; speedup vs baseline: 1.9192x; 1.0703x over previous
//
#include <hip/hip_runtime.h>
#include <hip/hip_bf16.h>
#include <cstdint>

typedef float f4  __attribute__((ext_vector_type(4)));
typedef short s8v __attribute__((ext_vector_type(8)));   // 8 bf16 (4 VGPRs)
typedef int   i4v __attribute__((ext_vector_type(4)));

#define BHTD 3145728    // B*H*T*D = 2*12*2048*64
#define BTC  3145728
#define NT   2048
#define NC   768
#define NWA  1769472    // 3C*C = 2304*768
#define NEG  -1e30f
// 0.125 (1/sqrt(64)) * log2(e): folded into Q at the producer so the flash
// kernel's scores are already in log2 domain (exp2 instead of expf, no scale mul)
#define QSCALE 0.18033688f

static __device__ __forceinline__ short bfbits(float f) {
    return __builtin_bit_cast(short, __float2bfloat16(f));
}
static __device__ __forceinline__ float bf2f(short s) {
    return __builtin_bit_cast(float, (int)(((unsigned int)(unsigned short)s) << 16));
}
static __device__ __forceinline__ float exp2fast(float x) {
    return __builtin_amdgcn_exp2f(x);
}
// hardware packed f32->bf16 (RNE), lo -> [15:0], hi -> [31:16]
static __device__ __forceinline__ int cvtpk_bf16(float lo, float hi) {
    int r;
    asm("v_cvt_pk_bf16_f32 %0, %1, %2" : "=v"(r) : "v"(lo), "v"(hi));
    return r;
}
// row reductions across the 4 quads (lanes l16, l16+16, l16+32, l16+48)
static __device__ __forceinline__ float rowred_max(float x) {
    x = fmaxf(x, __shfl_xor(x, 16, 64));
    x = fmaxf(x, __shfl_xor(x, 32, 64));
    return x;
}
static __device__ __forceinline__ float rowred_sum(float x) {
    x += __shfl_xor(x, 16, 64);
    x += __shfl_xor(x, 32, 64);
    return x;
}

// ---------------------------------------------------------------------------
// Kernel 0: one-shot fp32->bf16 conversion. xn=x, xm=(xl+xu)/2, xr=(xu-xl)/2,
// wb=W. Removes the 36x-redundant per-block conversion from qkv_proj.
// ---------------------------------------------------------------------------
__global__ __launch_bounds__(256) void prep_cvt(
    const float* __restrict__ x, const float* __restrict__ xl,
    const float* __restrict__ xu, const float* __restrict__ W,
    short* __restrict__ xn, short* __restrict__ xm, short* __restrict__ xr,
    short* __restrict__ wb)
{
    const size_t flat = (size_t)blockIdx.x * 256 + threadIdx.x;
    const size_t i = flat * 8;        // 1536*256*8 == BTC exactly
    {
        const f4 a0 = *(const f4*)&x[i],  a1 = *(const f4*)&x[i + 4];
        const f4 l0 = *(const f4*)&xl[i], l1 = *(const f4*)&xl[i + 4];
        const f4 u0 = *(const f4*)&xu[i], u1 = *(const f4*)&xu[i + 4];
        s8v vn, vm, vr;
#pragma unroll
        for (int j = 0; j < 4; j++) {
            vn[j]     = bfbits(a0[j]);                   vn[4 + j] = bfbits(a1[j]);
            vm[j]     = bfbits(0.5f * (l0[j] + u0[j]));  vm[4 + j] = bfbits(0.5f * (l1[j] + u1[j]));
            vr[j]     = bfbits(0.5f * (u0[j] - l0[j]));  vr[4 + j] = bfbits(0.5f * (u1[j] - l1[j]));
        }
        *(s8v*)&xn[i] = vn;
        *(s8v*)&xm[i] = vm;
        *(s8v*)&xr[i] = vr;
    }
    if (flat < NWA / 8) {
        const size_t wi = flat * 8;
        const f4 w0 = *(const f4*)&W[wi], w1 = *(const f4*)&W[wi + 4];
        s8v vw;
#pragma unroll
        for (int j = 0; j < 4; j++) { vw[j] = bfbits(w0[j]); vw[4 + j] = bfbits(w1[j]); }
        *(s8v*)&wb[wi] = vw;
    }
}

// ---------------------------------------------------------------------------
// Kernel 1: MFMA QKV projection from pre-converted bf16 inputs.
// nom=xn@wb^T, mid=xm@wb^T, rad=xr@|wb|^T (|wb| derived in-reg).
// Outputs bf16: Q,K in [var][part][B,H,T,D]; V in [B,H,D,T].
// Q (p==0) pre-scaled by 0.125*log2e. Ping-pong LDS dbuf, ONE barrier/K-step.
// ---------------------------------------------------------------------------
__global__ __launch_bounds__(256) void qkv_proj_mfma(
    const short* __restrict__ xn, const short* __restrict__ xm,
    const short* __restrict__ xr, const short* __restrict__ wb,
    short* __restrict__ qkvb)
{
    // per-buffer layout (shorts): Ax=0, Am=2560, Ar=5120, Bw=7680 (each [64][40])
    __shared__ short sm[2][4 * 2560];   // 40 KB
    short* Eb = &sm[0][0];              // epilogue alias [64][72] (4608 shorts)

    const int j0 = blockIdx.x * 64;     // N in [0,2304)
    const int n0 = blockIdx.y * 64;     // M in [0,4096)
    const int t  = threadIdx.x;
    const int wv = t >> 6, lane = t & 63, quad = lane >> 4, l16 = lane & 15;
    const int rw = t >> 2, koff = (t & 3) * 8;

    f4 aN[4], aM[4], aR[4];
#pragma unroll
    for (int i = 0; i < 4; i++) { aN[i] = f4{0,0,0,0}; aM[i] = f4{0,0,0,0}; aR[i] = f4{0,0,0,0}; }

    const size_t abase = (size_t)(n0 + rw) * NC + koff;
    const size_t bbase = (size_t)(j0 + rw) * NC + koff;

    s8v rn, rm, rr, rb;
    rn = *(const s8v*)&xn[abase];
    rm = *(const s8v*)&xm[abase];
    rr = *(const s8v*)&xr[abase];
    rb = *(const s8v*)&wb[bbase];
    *(s8v*)&sm[0][rw * 40 + koff]        = rn;
    *(s8v*)&sm[0][2560 + rw * 40 + koff] = rm;
    *(s8v*)&sm[0][5120 + rw * 40 + koff] = rr;
    *(s8v*)&sm[0][7680 + rw * 40 + koff] = rb;

    for (int it = 0; it < NC / 32; ++it) {
        const int cb = it & 1, nb = cb ^ 1;
        __syncthreads();                       // buf[cb] complete
        const bool pf = (it + 1 < NC / 32);
        if (pf) {                              // issue next-tile loads early
            const size_t k1 = (size_t)(it + 1) * 32;
            rn = *(const s8v*)&xn[abase + k1];
            rm = *(const s8v*)&xm[abase + k1];
            rr = *(const s8v*)&xr[abase + k1];
            rb = *(const s8v*)&wb[bbase + k1];
        }
        const s8v fx = *(const s8v*)&sm[cb][(wv * 16 + l16) * 40 + quad * 8];
        const s8v fm = *(const s8v*)&sm[cb][2560 + (wv * 16 + l16) * 40 + quad * 8];
        const s8v fr = *(const s8v*)&sm[cb][5120 + (wv * 16 + l16) * 40 + quad * 8];
#pragma unroll
        for (int nt = 0; nt < 4; ++nt) {
            const s8v fb = *(const s8v*)&sm[cb][7680 + (nt * 16 + l16) * 40 + quad * 8];
            i4v bi = __builtin_bit_cast(i4v, fb);
#pragma unroll
            for (int i = 0; i < 4; i++) bi[i] &= 0x7fff7fff;
            const s8v fa = __builtin_bit_cast(s8v, bi);
            aN[nt] = __builtin_amdgcn_mfma_f32_16x16x32_bf16(fx, fb, aN[nt], 0, 0, 0);
            aM[nt] = __builtin_amdgcn_mfma_f32_16x16x32_bf16(fm, fb, aM[nt], 0, 0, 0);
            aR[nt] = __builtin_amdgcn_mfma_f32_16x16x32_bf16(fr, fa, aR[nt], 0, 0, 0);
        }
        if (pf) {                              // stage into buf[nb]
            *(s8v*)&sm[nb][rw * 40 + koff]        = rn;
            *(s8v*)&sm[nb][2560 + rw * 40 + koff] = rm;
            *(s8v*)&sm[nb][5120 + rw * 40 + koff] = rr;
            *(s8v*)&sm[nb][7680 + rw * 40 + koff] = rb;
        }
    }

    const int p = j0 / NC, hh = (j0 % NC) >> 6;
    const float osc = (p == 0) ? QSCALE : 1.0f;   // pre-scale Q for exp2-domain flash
    const int cc16 = (t & 3) * 16;
    for (int var = 0; var < 3; ++var) {
        __syncthreads();
#pragma unroll
        for (int nt = 0; nt < 4; ++nt)
#pragma unroll
            for (int r = 0; r < 4; ++r) {
                const float v = (var == 0) ? aN[nt][r]
                              : (var == 1) ? aM[nt][r] - aR[nt][r]
                                           : aM[nt][r] + aR[nt][r];
                Eb[(wv * 16 + quad * 4 + r) * 72 + nt * 16 + l16] = bfbits(v * osc);
            }
        __syncthreads();
        short* dst = qkvb + (size_t)(var * 3 + p) * BHTD;
        if (p < 2) {       // Q,K row-major [B,H,T,D]
            const int token = n0 + rw, b = token >> 11, tt = token & 2047;
            const size_t o = ((size_t)(b * 12 + hh) * NT + tt) * 64 + cc16;
            *(s8v*)&dst[o]     = *(const s8v*)&Eb[rw * 72 + cc16];
            *(s8v*)&dst[o + 8] = *(const s8v*)&Eb[rw * 72 + cc16 + 8];
        } else {           // V transposed [B,H,D,T]
            const int d = rw;
            s8v e0, e1;
#pragma unroll
            for (int i = 0; i < 8; i++) e0[i] = Eb[(cc16 + i) * 72 + d];
#pragma unroll
            for (int i = 0; i < 8; i++) e1[i] = Eb[(cc16 + 8 + i) * 72 + d];
            const int token0 = n0 + cc16, b = token0 >> 11, tt = token0 & 2047;
            const size_t o = ((size_t)(b * 12 + hh) * 64 + d) * NT + tt;
            *(s8v*)&dst[o]     = e0;
            *(s8v*)&dst[o + 8] = e1;
        }
    }
}

// ---------------------------------------------------------------------------
// Kernel 2: MFMA flash, merged nominal + 4 bound branches in one launch.
// 1D grid 960, XCD-aware encoding: linear id b -> xcd = b%8 == bh%8, so all
// 40 blocks sharing 3 bh values land on ONE XCD; their K/V working set
// (6 x 256KB x 3 bh ~ 4.5MB) ~ the XCD's private 4MB L2 -> prefetches become
// L2 hits instead of ~900cy HBM misses.
//   decode: xcd=b%8; r=b/8; pr=r%8; r2=r/8; z=r2%5; bh = xcd + 8*(r2/5)
// LOAD-BALANCED: each block does q-tiles pr AND 15-pr -> uniform 68 kt-iters.
// Block = 128 q-rows, 4 waves x 32 rows (2 m-tiles), K-tile 32.
// SWAPPED QK^T (P in registers, no LDS round-trip); P packed to bf16 via
// hardware v_cvt_pk_bf16_f32 (4 instr per m-tile). Ping-pong LDS dbuf, ONE
// barrier/k-tile; T14 reg prefetch; T13 defer-max; setprio around MFMA.
// ---------------------------------------------------------------------------
__global__ __launch_bounds__(256) void flash_mfma(
    const short* __restrict__ qkvb, float* __restrict__ ybuf,
    short* __restrict__ cand)
{
    const int b_  = blockIdx.x;            // 0..959
    const int xcd = b_ & 7;
    const int r_  = b_ >> 3;               // 0..119
    const int pr  = r_ & 7;                // 0..7
    const int r2  = r_ >> 3;               // 0..14
    const int z   = r2 % 5;
    const int bh  = xcd + 8 * (r2 / 5);    // 0..23
    const int t   = threadIdx.x;
    const int wv = t >> 6, lane = t & 63, quad = lane >> 4, l16 = lane & 15;
    const bool TWO = (z != 0);

    __shared__ short Ks[2][32 * 68];       // [buf][kpos][d] pad 68 (8.7 KB)
    __shared__ short Vs[2][2][64 * 40];    // [buf][sv][d][kpos] (20.5 KB)

    int sv, qvi, kvi, v0i, v1i;
    if (TWO) { sv = z; qvi = (sv + 1) >> 1; kvi = 2 - (sv & 1); v0i = 1; v1i = 2; }
    else     { sv = 0; qvi = 0; kvi = 0; v0i = 0; v1i = 0; }

    const size_t hb = (size_t)bh * (NT * 64);
    const short* Qp  = qkvb + (size_t)(qvi * 3 + 0) * BHTD + hb;  // [t][d] (pre-scaled)
    const short* Kp  = qkvb + (size_t)(kvi * 3 + 1) * BHTD + hb;  // [t][d]
    const short* V0p = qkvb + (size_t)(v0i * 3 + 2) * BHTD + hb;  // [d][t] !
    const short* V1p = qkvb + (size_t)(v1i * 3 + 2) * BHTD + hb;

    const int skr = t >> 3, skc = (t & 7) * 8;   // K stage: 32 x 64
    const int svd = t >> 2, svc = (t & 3) * 8;   // V stage: 64 x 32
    const int sig = (l16 >> 2) * 8 + (l16 & 3);  // K A-frag row permutation

    for (int half = 0; half < 2; ++half) {
        const int qt = half ? (15 - pr) : pr;
        const int q0 = qt * 128;

        // Q fragments (serve as the MFMA B operand in the swapped product)
        s8v qf[2][2];
#pragma unroll
        for (int mt = 0; mt < 2; ++mt)
#pragma unroll
            for (int ch = 0; ch < 2; ++ch)
                qf[mt][ch] = *(const s8v*)&Qp[(size_t)(q0 + 32 * wv + 16 * mt + l16) * 64 + ch * 32 + quad * 8];

        float mi[2], li[2];                // per-lane: row q = rowb + l16; li = quad-partial
        mi[0] = mi[1] = NEG; li[0] = li[1] = 0.f;
        f4 acc0[2][4], acc1[2][4];
#pragma unroll
        for (int mt = 0; mt < 2; ++mt)
#pragma unroll
            for (int i = 0; i < 4; ++i) { acc0[mt][i] = f4{0,0,0,0}; acc1[mt][i] = f4{0,0,0,0}; }

        const int ktn  = 4 * qt + 4;
        const int mykt = 4 * qt + wv + 1;  // last tile this wave's rows need

        // prologue: barrier (protect prior half's live buffers), tile 0 -> buf 0
        __syncthreads();
        s8v rK, rV0, rV1;
        rK  = *(const s8v*)&Kp[(size_t)skr * 64 + skc];
        rV0 = *(const s8v*)&V0p[(size_t)svd * NT + svc];
        if (TWO) rV1 = *(const s8v*)&V1p[(size_t)svd * NT + svc];
        *(s8v*)&Ks[0][skr * 68 + skc]    = rK;
        *(s8v*)&Vs[0][0][svd * 40 + svc] = rV0;
        if (TWO) *(s8v*)&Vs[0][1][svd * 40 + svc] = rV1;

        for (int kt = 0; kt < ktn; ++kt) {
            const int k0 = kt * 32;
            const int cb = kt & 1, nb = cb ^ 1;
            __syncthreads();               // buf[cb] complete for all waves
            const bool pf = (kt + 1 < ktn);
            if (pf) {                      // issue next-tile loads early
                const int k1 = k0 + 32;
                rK  = *(const s8v*)&Kp[(size_t)(k1 + skr) * 64 + skc];
                rV0 = *(const s8v*)&V0p[(size_t)svd * NT + k1 + svc];
                if (TWO) rV1 = *(const s8v*)&V1p[(size_t)svd * NT + k1 + svc];
            }
            if (kt < mykt) {
                // ---- S^T = K Q^T (log2 domain): s[mt][nt][r] =
                //      P[kpos = k0 + quad*8 + nt*4 + r][q = rowb + l16] ----
                f4 s[2][2];
#pragma unroll
                for (int mt = 0; mt < 2; ++mt) { s[mt][0] = f4{0,0,0,0}; s[mt][1] = f4{0,0,0,0}; }
                __builtin_amdgcn_s_setprio(1);
#pragma unroll
                for (int nt = 0; nt < 2; ++nt)
#pragma unroll
                    for (int ch = 0; ch < 2; ++ch) {
                        const s8v kf = *(const s8v*)&Ks[cb][(sig + nt * 4) * 68 + ch * 32 + quad * 8];
                        s[0][nt] = __builtin_amdgcn_mfma_f32_16x16x32_bf16(kf, qf[0][ch], s[0][nt], 0, 0, 0);
                        s[1][nt] = __builtin_amdgcn_mfma_f32_16x16x32_bf16(kf, qf[1][ch], s[1][nt], 0, 0, 0);
                    }
                __builtin_amdgcn_s_setprio(0);

                // ---- softmax + in-register P pack, per m-tile ----
                s8v pa[2];
#pragma unroll
                for (int mt = 0; mt < 2; ++mt) {
                    const int rowb = q0 + 32 * wv + 16 * mt;
                    const int qrow = rowb + l16;
                    float a[8];
#pragma unroll
                    for (int nt = 0; nt < 2; ++nt)
#pragma unroll
                        for (int r = 0; r < 4; ++r) a[nt * 4 + r] = s[mt][nt][r];
                    if (k0 + 31 > rowb) {
#pragma unroll
                        for (int nt = 0; nt < 2; ++nt)
#pragma unroll
                            for (int r = 0; r < 4; ++r)
                                if (k0 + quad * 8 + nt * 4 + r > qrow) a[nt * 4 + r] = NEG;
                    }
                    const float c = fmaxf(fmaxf(fmaxf(a[0], a[1]), fmaxf(a[2], a[3])),
                                          fmaxf(fmaxf(a[4], a[5]), fmaxf(a[6], a[7])));
                    if (__any(c - mi[mt] > 8.0f)) {     // rare: row max grew
                        const float mx = rowred_max(c); // full-row max, quad-consistent
                        const float nm = fmaxf(mi[mt], mx);
                        const float al = exp2fast(mi[mt] - nm);
                        mi[mt] = nm;
                        li[mt] *= al;
#pragma unroll
                        for (int r = 0; r < 4; ++r) {
                            // al lives at lane l16 = acc row; uniform across quads
                            const float alr = __shfl(al, (lane & 48) | (quad * 4 + r), 64);
#pragma unroll
                            for (int dt = 0; dt < 4; ++dt) acc0[mt][dt][r] *= alr;
                            if (TWO) {
#pragma unroll
                                for (int dt = 0; dt < 4; ++dt) acc1[mt][dt][r] *= alr;
                            }
                        }
                    }
                    float p[8];
#pragma unroll
                    for (int j = 0; j < 8; ++j) p[j] = exp2fast(a[j] - mi[mt]);  // <= 2^8
                    li[mt] += ((p[0] + p[1]) + (p[2] + p[3])) + ((p[4] + p[5]) + (p[6] + p[7]));
                    i4v pi;
#pragma unroll
                    for (int jj = 0; jj < 4; ++jj)
                        pi[jj] = cvtpk_bf16(p[2 * jj], p[2 * jj + 1]);
                    pa[mt] = __builtin_bit_cast(s8v, pi);
                }
                // ---- O += P V (pa is the A fragment directly) ----
                __builtin_amdgcn_s_setprio(1);
#pragma unroll
                for (int dt = 0; dt < 4; ++dt) {
                    const s8v vf0 = *(const s8v*)&Vs[cb][0][(dt * 16 + l16) * 40 + quad * 8];
                    acc0[0][dt] = __builtin_amdgcn_mfma_f32_16x16x32_bf16(pa[0], vf0, acc0[0][dt], 0, 0, 0);
                    acc0[1][dt] = __builtin_amdgcn_mfma_f32_16x16x32_bf16(pa[1], vf0, acc0[1][dt], 0, 0, 0);
                    if (TWO) {
                        const s8v vf1 = *(const s8v*)&Vs[cb][1][(dt * 16 + l16) * 40 + quad * 8];
                        acc1[0][dt] = __builtin_amdgcn_mfma_f32_16x16x32_bf16(pa[0], vf1, acc1[0][dt], 0, 0, 0);
                        acc1[1][dt] = __builtin_amdgcn_mfma_f32_16x16x32_bf16(pa[1], vf1, acc1[1][dt], 0, 0, 0);
                    }
                }
                __builtin_amdgcn_s_setprio(0);
            }
            if (pf) {                      // stage next tile into buf[nb]
                *(s8v*)&Ks[nb][skr * 68 + skc]    = rK;
                *(s8v*)&Vs[nb][0][svd * 40 + svc] = rV0;
                if (TWO) *(s8v*)&Vs[nb][1][svd * 40 + svc] = rV1;
            }
        }

#pragma unroll
        for (int mt = 0; mt < 2; ++mt) {
            // total row sum (uniform across quads after reduce), then redistribute
            const float invq = 1.f / rowred_sum(li[mt]);
            float inv[4];
#pragma unroll
            for (int r = 0; r < 4; ++r)
                inv[r] = __shfl(invq, (lane & 48) | (quad * 4 + r), 64);
#pragma unroll
            for (int dt = 0; dt < 4; ++dt)
#pragma unroll
                for (int r = 0; r < 4; ++r) {
                    const size_t o = hb + (size_t)(q0 + 32 * wv + 16 * mt + quad * 4 + r) * 64 + dt * 16 + l16;
                    if (!TWO) {
                        ybuf[o] = acc0[mt][dt][r] * inv[r];
                    } else {
                        const float xa = acc0[mt][dt][r] * inv[r];
                        const float xb = acc1[mt][dt][r] * inv[r];
                        cand[(size_t)(sv - 1) * BHTD + o] = bfbits(fminf(xa, xb));
                        cand[(size_t)(3 + sv) * BHTD + o] = bfbits(fmaxf(xa, xb));
                    }
                }
        }
    }
}

// ---------------------------------------------------------------------------
// Kernel 3: MFMA output projection. z=0: A=y fp32; z=1: A=min of 4 candLo;
// z=2: A=max of 4 candHi. B=Wp (bf16). out fp32 via LDS re-layout.
// Ping-pong LDS double buffer: ONE barrier per K-step.
// ---------------------------------------------------------------------------
__global__ __launch_bounds__(256) void out_proj_mfma(
    const float* __restrict__ ybuf, const short* __restrict__ cand,
    const float* __restrict__ Wp, float* __restrict__ out)
{
    // per-buffer layout (shorts): As=0, Bs=2560 (each [64][40])
    __shared__ short sm3[2][2 * 2560];      // 20.5 KB
    float* Eb = (float*)sm3;                // epilogue alias [64][68] (17.4 KB)

    const int o  = blockIdx.z;
    const int j0 = blockIdx.x * 64, n0 = blockIdx.y * 64;
    const int t  = threadIdx.x;
    const int wv = t >> 6, lane = t & 63, quad = lane >> 4, l16 = lane & 15;
    const int rw = t >> 2, koff = (t & 3) * 8;

    f4 acc[4];
#pragma unroll
    for (int i = 0; i < 4; i++) acc[i] = f4{0,0,0,0};

    const int token = n0 + rw, b = token >> 11, tt = token & 2047;
    const size_t wbase = (size_t)(j0 + rw) * NC + koff;
    const short* cb = cand + (size_t)(o == 1 ? 0 : 4) * BHTD;

    f4 ry0, ry1, rw0, rw1;
    s8v rc0, rc1, rc2, rc3;

    auto convert = [&](s8v& av, s8v& bv) {
        if (o == 0) {
#pragma unroll
            for (int i = 0; i < 4; i++) { av[i] = bfbits(ry0[i]); av[4 + i] = bfbits(ry1[i]); }
        } else {
            float v[8];
#pragma unroll
            for (int i = 0; i < 8; i++) v[i] = bf2f(rc0[i]);
            if (o == 1) {
#pragma unroll
                for (int i = 0; i < 8; i++) v[i] = fminf(v[i], bf2f(rc1[i]));
#pragma unroll
                for (int i = 0; i < 8; i++) v[i] = fminf(v[i], bf2f(rc2[i]));
#pragma unroll
                for (int i = 0; i < 8; i++) v[i] = fminf(v[i], bf2f(rc3[i]));
            } else {
#pragma unroll
                for (int i = 0; i < 8; i++) v[i] = fmaxf(v[i], bf2f(rc1[i]));
#pragma unroll
                for (int i = 0; i < 8; i++) v[i] = fmaxf(v[i], bf2f(rc2[i]));
#pragma unroll
                for (int i = 0; i < 8; i++) v[i] = fmaxf(v[i], bf2f(rc3[i]));
            }
#pragma unroll
            for (int i = 0; i < 8; i++) av[i] = bfbits(v[i]);
        }
#pragma unroll
        for (int i = 0; i < 4; i++) { bv[i] = bfbits(rw0[i]); bv[4 + i] = bfbits(rw1[i]); }
    };
    auto loadTile = [&](int k1) {
        const int hh = k1 >> 6, d0 = (k1 & 63) + koff;
        const size_t aoff = ((size_t)(b * 12 + hh) * NT + tt) * 64 + d0;
        if (o == 0) {
            ry0 = *(const f4*)&ybuf[aoff];
            ry1 = *(const f4*)&ybuf[aoff + 4];
        } else {
            rc0 = *(const s8v*)&cb[aoff];
            rc1 = *(const s8v*)&cb[(size_t)1 * BHTD + aoff];
            rc2 = *(const s8v*)&cb[(size_t)2 * BHTD + aoff];
            rc3 = *(const s8v*)&cb[(size_t)3 * BHTD + aoff];
        }
        rw0 = *(const f4*)&Wp[wbase + k1];
        rw1 = *(const f4*)&Wp[wbase + k1 + 4];
    };

    // prologue: tile 0 -> regs -> convert -> buf 0
    loadTile(0);
    {
        s8v av, bv;
        convert(av, bv);
        *(s8v*)&sm3[0][rw * 40 + koff]        = av;
        *(s8v*)&sm3[0][2560 + rw * 40 + koff] = bv;
    }

    for (int it = 0; it < NC / 32; ++it) {
        const int cbuf = it & 1, nbuf = cbuf ^ 1;
        __syncthreads();
        const bool pf = (it + 1 < NC / 32);
        if (pf) loadTile((it + 1) * 32);
        const s8v af = *(const s8v*)&sm3[cbuf][(wv * 16 + l16) * 40 + quad * 8];
#pragma unroll
        for (int nt = 0; nt < 4; ++nt) {
            const s8v bf = *(const s8v*)&sm3[cbuf][2560 + (nt * 16 + l16) * 40 + quad * 8];
            acc[nt] = __builtin_amdgcn_mfma_f32_16x16x32_bf16(af, bf, acc[nt], 0, 0, 0);
        }
        if (pf) {
            s8v av, bv;
            convert(av, bv);
            *(s8v*)&sm3[nbuf][rw * 40 + koff]        = av;
            *(s8v*)&sm3[nbuf][2560 + rw * 40 + koff] = bv;
        }
    }
    __syncthreads();
#pragma unroll
    for (int nt = 0; nt < 4; ++nt)
#pragma unroll
        for (int r = 0; r < 4; ++r)
            Eb[(wv * 16 + quad * 4 + r) * 68 + nt * 16 + l16] = acc[nt][r];
    __syncthreads();
    const int cc = (t & 3) * 16;
#pragma unroll
    for (int i = 0; i < 4; ++i) {
        const f4 vo = *(const f4*)&Eb[rw * 68 + cc + 4 * i];
        *(f4*)&out[(size_t)o * BTC + (size_t)(n0 + rw) * NC + j0 + cc + 4 * i] = vo;
    }
}

extern "C" void kernel_launch(void* const* d_in, const int* in_sizes, int n_in,
                              void* d_out, int out_size, void* d_ws, size_t ws_size,
                              hipStream_t stream)
{
    const float* x  = (const float*)d_in[0];
    const float* xl = (const float*)d_in[1];
    const float* xu = (const float*)d_in[2];
    const float* Wa = (const float*)d_in[3];
    const float* Wp = (const float*)d_in[4];
    float* out = (float*)d_out;

    short* qkvb = (short*)d_ws;                       // 9*BHTD bf16  = 56.6 MB
    float* ybuf = (float*)(qkvb + (size_t)9 * BHTD);  // 1*BHTD f32   = 12.6 MB
    short* cand = (short*)(ybuf + (size_t)BHTD);      // 8*BHTD bf16  = 50.3 MB

    // prep arrays alias cand (dead until flash writes it; consumed by qkv_proj)
    short* xn = cand;                      // BTC shorts
    short* xm = cand + (size_t)1 * BHTD;   // BTC shorts
    short* xr = cand + (size_t)2 * BHTD;   // BTC shorts
    short* wb = cand + (size_t)3 * BHTD;   // NWA shorts (fits in BHTD)

    prep_cvt     <<<dim3(1536),      256, 0, stream>>>(x, xl, xu, Wa, xn, xm, xr, wb);
    qkv_proj_mfma<<<dim3(36, 64),    256, 0, stream>>>(xn, xm, xr, wb, qkvb);
    flash_mfma   <<<dim3(960),       256, 0, stream>>>(qkvb, ybuf, cand);
    out_proj_mfma<<<dim3(12, 64, 3), 256, 0, stream>>>(ybuf, cand, Wp, out);
}

// Round 9
// 417.764 us; speedup vs baseline: 2.0620x; 1.0744x over previous
//
#include <hip/hip_runtime.h>
#include <hip/hip_bf16.h>
#include <cstdint>

typedef float f4  __attribute__((ext_vector_type(4)));
typedef short s8v __attribute__((ext_vector_type(8)));   // 8 bf16 (4 VGPRs)
typedef int   i4v __attribute__((ext_vector_type(4)));

#define BHTD 3145728    // B*H*T*D = 2*12*2048*64
#define BTC  3145728
#define NT   2048
#define NC   768
#define NWA  1769472    // 3C*C = 2304*768
#define NEG  -1e30f
// 0.125 (1/sqrt(64)) * log2(e): folded into Q at the producer so the flash
// kernel's scores are already in log2 domain (exp2 instead of expf, no scale mul)
#define QSCALE 0.18033688f

static __device__ __forceinline__ short bfbits(float f) {
    return __builtin_bit_cast(short, __float2bfloat16(f));
}
static __device__ __forceinline__ float bf2f(short s) {
    return __builtin_bit_cast(float, (int)(((unsigned int)(unsigned short)s) << 16));
}
static __device__ __forceinline__ float exp2fast(float x) {
    return __builtin_amdgcn_exp2f(x);
}
// hardware packed f32->bf16 (RNE), lo -> [15:0], hi -> [31:16]
static __device__ __forceinline__ int cvtpk_bf16(float lo, float hi) {
    int r;
    asm("v_cvt_pk_bf16_f32 %0, %1, %2" : "=v"(r) : "v"(lo), "v"(hi));
    return r;
}
// row reductions across the 4 quads (lanes l16, l16+16, l16+32, l16+48)
static __device__ __forceinline__ float rowred_max(float x) {
    x = fmaxf(x, __shfl_xor(x, 16, 64));
    x = fmaxf(x, __shfl_xor(x, 32, 64));
    return x;
}
static __device__ __forceinline__ float rowred_sum(float x) {
    x += __shfl_xor(x, 16, 64);
    x += __shfl_xor(x, 32, 64);
    return x;
}

// ---------------------------------------------------------------------------
// Kernel 0: one-shot fp32->bf16 conversion. xn=x, xm=(xl+xu)/2, xr=(xu-xl)/2,
// wb=W. Removes the 36x-redundant per-block conversion from qkv_proj.
// ---------------------------------------------------------------------------
__global__ __launch_bounds__(256) void prep_cvt(
    const float* __restrict__ x, const float* __restrict__ xl,
    const float* __restrict__ xu, const float* __restrict__ W,
    short* __restrict__ xn, short* __restrict__ xm, short* __restrict__ xr,
    short* __restrict__ wb)
{
    const size_t flat = (size_t)blockIdx.x * 256 + threadIdx.x;
    const size_t i = flat * 8;        // 1536*256*8 == BTC exactly
    {
        const f4 a0 = *(const f4*)&x[i],  a1 = *(const f4*)&x[i + 4];
        const f4 l0 = *(const f4*)&xl[i], l1 = *(const f4*)&xl[i + 4];
        const f4 u0 = *(const f4*)&xu[i], u1 = *(const f4*)&xu[i + 4];
        s8v vn, vm, vr;
#pragma unroll
        for (int j = 0; j < 4; j++) {
            vn[j]     = bfbits(a0[j]);                   vn[4 + j] = bfbits(a1[j]);
            vm[j]     = bfbits(0.5f * (l0[j] + u0[j]));  vm[4 + j] = bfbits(0.5f * (l1[j] + u1[j]));
            vr[j]     = bfbits(0.5f * (u0[j] - l0[j]));  vr[4 + j] = bfbits(0.5f * (u1[j] - l1[j]));
        }
        *(s8v*)&xn[i] = vn;
        *(s8v*)&xm[i] = vm;
        *(s8v*)&xr[i] = vr;
    }
    if (flat < NWA / 8) {
        const size_t wi = flat * 8;
        const f4 w0 = *(const f4*)&W[wi], w1 = *(const f4*)&W[wi + 4];
        s8v vw;
#pragma unroll
        for (int j = 0; j < 4; j++) { vw[j] = bfbits(w0[j]); vw[4 + j] = bfbits(w1[j]); }
        *(s8v*)&wb[wi] = vw;
    }
}

// ---------------------------------------------------------------------------
// Kernel 1: MFMA QKV projection from pre-converted bf16 inputs.
// nom=xn@wb^T, mid=xm@wb^T, rad=xr@|wb|^T (|wb| derived in-reg).
// XCD-COLOCATED 1D grid (2304): xcd=b%8; s=b/8; jx=s%36 (FASTEST: all 36
// j0-blocks of one n0 run back-to-back on one XCD so the A-tile (295KB x3)
// is L2-hot across its 36 consumers; wb (3.5MB) stays L2-resident).
// ny = xcd + 8*(s/36).
// Outputs bf16: Q,K in [var][part][B,H,T,D]; V in [B,H,D,T].
// Q (p==0) pre-scaled by 0.125*log2e. Ping-pong LDS dbuf, ONE barrier/K-step.
// ---------------------------------------------------------------------------
__global__ __launch_bounds__(256) void qkv_proj_mfma(
    const short* __restrict__ xn, const short* __restrict__ xm,
    const short* __restrict__ xr, const short* __restrict__ wb,
    short* __restrict__ qkvb)
{
    // per-buffer layout (shorts): Ax=0, Am=2560, Ar=5120, Bw=7680 (each [64][40])
    __shared__ short sm[2][4 * 2560];   // 40 KB
    short* Eb = &sm[0][0];              // epilogue alias [64][72] (4608 shorts)

    const int b_  = blockIdx.x;         // 0..2303
    const int xcd = b_ & 7;
    const int s_  = b_ >> 3;            // 0..287
    const int jx  = s_ % 36;
    const int ny  = xcd + 8 * (s_ / 36);   // 0..63
    const int j0 = jx * 64;             // N in [0,2304)
    const int n0 = ny * 64;             // M in [0,4096)
    const int t  = threadIdx.x;
    const int wv = t >> 6, lane = t & 63, quad = lane >> 4, l16 = lane & 15;
    const int rw = t >> 2, koff = (t & 3) * 8;

    f4 aN[4], aM[4], aR[4];
#pragma unroll
    for (int i = 0; i < 4; i++) { aN[i] = f4{0,0,0,0}; aM[i] = f4{0,0,0,0}; aR[i] = f4{0,0,0,0}; }

    const size_t abase = (size_t)(n0 + rw) * NC + koff;
    const size_t bbase = (size_t)(j0 + rw) * NC + koff;

    s8v rn, rm, rr, rb;
    rn = *(const s8v*)&xn[abase];
    rm = *(const s8v*)&xm[abase];
    rr = *(const s8v*)&xr[abase];
    rb = *(const s8v*)&wb[bbase];
    *(s8v*)&sm[0][rw * 40 + koff]        = rn;
    *(s8v*)&sm[0][2560 + rw * 40 + koff] = rm;
    *(s8v*)&sm[0][5120 + rw * 40 + koff] = rr;
    *(s8v*)&sm[0][7680 + rw * 40 + koff] = rb;

    for (int it = 0; it < NC / 32; ++it) {
        const int cb = it & 1, nb = cb ^ 1;
        __syncthreads();                       // buf[cb] complete
        const bool pf = (it + 1 < NC / 32);
        if (pf) {                              // issue next-tile loads early
            const size_t k1 = (size_t)(it + 1) * 32;
            rn = *(const s8v*)&xn[abase + k1];
            rm = *(const s8v*)&xm[abase + k1];
            rr = *(const s8v*)&xr[abase + k1];
            rb = *(const s8v*)&wb[bbase + k1];
        }
        const s8v fx = *(const s8v*)&sm[cb][(wv * 16 + l16) * 40 + quad * 8];
        const s8v fm = *(const s8v*)&sm[cb][2560 + (wv * 16 + l16) * 40 + quad * 8];
        const s8v fr = *(const s8v*)&sm[cb][5120 + (wv * 16 + l16) * 40 + quad * 8];
#pragma unroll
        for (int nt = 0; nt < 4; ++nt) {
            const s8v fb = *(const s8v*)&sm[cb][7680 + (nt * 16 + l16) * 40 + quad * 8];
            i4v bi = __builtin_bit_cast(i4v, fb);
#pragma unroll
            for (int i = 0; i < 4; i++) bi[i] &= 0x7fff7fff;
            const s8v fa = __builtin_bit_cast(s8v, bi);
            aN[nt] = __builtin_amdgcn_mfma_f32_16x16x32_bf16(fx, fb, aN[nt], 0, 0, 0);
            aM[nt] = __builtin_amdgcn_mfma_f32_16x16x32_bf16(fm, fb, aM[nt], 0, 0, 0);
            aR[nt] = __builtin_amdgcn_mfma_f32_16x16x32_bf16(fr, fa, aR[nt], 0, 0, 0);
        }
        if (pf) {                              // stage into buf[nb]
            *(s8v*)&sm[nb][rw * 40 + koff]        = rn;
            *(s8v*)&sm[nb][2560 + rw * 40 + koff] = rm;
            *(s8v*)&sm[nb][5120 + rw * 40 + koff] = rr;
            *(s8v*)&sm[nb][7680 + rw * 40 + koff] = rb;
        }
    }

    const int p = j0 / NC, hh = (j0 % NC) >> 6;
    const float osc = (p == 0) ? QSCALE : 1.0f;   // pre-scale Q for exp2-domain flash
    const int cc16 = (t & 3) * 16;
    for (int var = 0; var < 3; ++var) {
        __syncthreads();
#pragma unroll
        for (int nt = 0; nt < 4; ++nt)
#pragma unroll
            for (int r = 0; r < 4; ++r) {
                const float v = (var == 0) ? aN[nt][r]
                              : (var == 1) ? aM[nt][r] - aR[nt][r]
                                           : aM[nt][r] + aR[nt][r];
                Eb[(wv * 16 + quad * 4 + r) * 72 + nt * 16 + l16] = bfbits(v * osc);
            }
        __syncthreads();
        short* dst = qkvb + (size_t)(var * 3 + p) * BHTD;
        if (p < 2) {       // Q,K row-major [B,H,T,D]
            const int token = n0 + rw, b = token >> 11, tt = token & 2047;
            const size_t o = ((size_t)(b * 12 + hh) * NT + tt) * 64 + cc16;
            *(s8v*)&dst[o]     = *(const s8v*)&Eb[rw * 72 + cc16];
            *(s8v*)&dst[o + 8] = *(const s8v*)&Eb[rw * 72 + cc16 + 8];
        } else {           // V transposed [B,H,D,T]
            const int d = rw;
            s8v e0, e1;
#pragma unroll
            for (int i = 0; i < 8; i++) e0[i] = Eb[(cc16 + i) * 72 + d];
#pragma unroll
            for (int i = 0; i < 8; i++) e1[i] = Eb[(cc16 + 8 + i) * 72 + d];
            const int token0 = n0 + cc16, b = token0 >> 11, tt = token0 & 2047;
            const size_t o = ((size_t)(b * 12 + hh) * 64 + d) * NT + tt;
            *(s8v*)&dst[o]     = e0;
            *(s8v*)&dst[o + 8] = e1;
        }
    }
}

// ---------------------------------------------------------------------------
// Kernel 2: MFMA flash, merged nominal + 4 bound branches in one launch.
// 1D grid 960, XCD-aware encoding: xcd=b%8 == bh%8 -> per-XCD K/V working set
// ~4.5MB ~ private 4MB L2 (R8: FETCH 279->31MB).
//   decode: xcd=b%8; r=b/8; pr=r%8; r2=r/8; z=r2%5; bh = xcd + 8*(r2/5)
// LOAD-BALANCED: each block does q-tiles pr AND 15-pr -> uniform 68 kt-iters.
// Block = 128 q-rows, 4 waves x 32 rows (2 m-tiles), K-tile 32.
// SWAPPED QK^T (P in registers, no LDS round-trip); P packed via
// v_cvt_pk_bf16_f32. Ks pad 70 shorts (35 dw = odd bank stride: the 16
// sigma-permuted rows map to 16 distinct banks -> read conflicts cut).
// Ping-pong LDS dbuf, ONE barrier/k-tile; T14 reg prefetch; T13 defer-max;
// setprio around MFMA.
// ---------------------------------------------------------------------------
__global__ __launch_bounds__(256) void flash_mfma(
    const short* __restrict__ qkvb, float* __restrict__ ybuf,
    short* __restrict__ cand)
{
    const int b_  = blockIdx.x;            // 0..959
    const int xcd = b_ & 7;
    const int r_  = b_ >> 3;               // 0..119
    const int pr  = r_ & 7;                // 0..7
    const int r2  = r_ >> 3;               // 0..14
    const int z   = r2 % 5;
    const int bh  = xcd + 8 * (r2 / 5);    // 0..23
    const int t   = threadIdx.x;
    const int wv = t >> 6, lane = t & 63, quad = lane >> 4, l16 = lane & 15;
    const bool TWO = (z != 0);

    __shared__ short Ks[2][32 * 70];       // [buf][kpos][d] pad 70 (9.0 KB)
    __shared__ short Vs[2][2][64 * 40];    // [buf][sv][d][kpos] (20.5 KB)

    int sv, qvi, kvi, v0i, v1i;
    if (TWO) { sv = z; qvi = (sv + 1) >> 1; kvi = 2 - (sv & 1); v0i = 1; v1i = 2; }
    else     { sv = 0; qvi = 0; kvi = 0; v0i = 0; v1i = 0; }

    const size_t hb = (size_t)bh * (NT * 64);
    const short* Qp  = qkvb + (size_t)(qvi * 3 + 0) * BHTD + hb;  // [t][d] (pre-scaled)
    const short* Kp  = qkvb + (size_t)(kvi * 3 + 1) * BHTD + hb;  // [t][d]
    const short* V0p = qkvb + (size_t)(v0i * 3 + 2) * BHTD + hb;  // [d][t] !
    const short* V1p = qkvb + (size_t)(v1i * 3 + 2) * BHTD + hb;

    const int skr = t >> 3, skc = (t & 7) * 8;   // K stage: 32 x 64
    const int svd = t >> 2, svc = (t & 3) * 8;   // V stage: 64 x 32
    const int sig = (l16 >> 2) * 8 + (l16 & 3);  // K A-frag row permutation

    for (int half = 0; half < 2; ++half) {
        const int qt = half ? (15 - pr) : pr;
        const int q0 = qt * 128;

        // Q fragments (serve as the MFMA B operand in the swapped product)
        s8v qf[2][2];
#pragma unroll
        for (int mt = 0; mt < 2; ++mt)
#pragma unroll
            for (int ch = 0; ch < 2; ++ch)
                qf[mt][ch] = *(const s8v*)&Qp[(size_t)(q0 + 32 * wv + 16 * mt + l16) * 64 + ch * 32 + quad * 8];

        float mi[2], li[2];                // per-lane: row q = rowb + l16; li = quad-partial
        mi[0] = mi[1] = NEG; li[0] = li[1] = 0.f;
        f4 acc0[2][4], acc1[2][4];
#pragma unroll
        for (int mt = 0; mt < 2; ++mt)
#pragma unroll
            for (int i = 0; i < 4; ++i) { acc0[mt][i] = f4{0,0,0,0}; acc1[mt][i] = f4{0,0,0,0}; }

        const int ktn  = 4 * qt + 4;
        const int mykt = 4 * qt + wv + 1;  // last tile this wave's rows need

        // prologue: barrier (protect prior half's live buffers), tile 0 -> buf 0
        __syncthreads();
        s8v rK, rV0, rV1;
        rK  = *(const s8v*)&Kp[(size_t)skr * 64 + skc];
        rV0 = *(const s8v*)&V0p[(size_t)svd * NT + svc];
        if (TWO) rV1 = *(const s8v*)&V1p[(size_t)svd * NT + svc];
        *(s8v*)&Ks[0][skr * 70 + skc]    = rK;
        *(s8v*)&Vs[0][0][svd * 40 + svc] = rV0;
        if (TWO) *(s8v*)&Vs[0][1][svd * 40 + svc] = rV1;

        for (int kt = 0; kt < ktn; ++kt) {
            const int k0 = kt * 32;
            const int cb = kt & 1, nb = cb ^ 1;
            __syncthreads();               // buf[cb] complete for all waves
            const bool pf = (kt + 1 < ktn);
            if (pf) {                      // issue next-tile loads early
                const int k1 = k0 + 32;
                rK  = *(const s8v*)&Kp[(size_t)(k1 + skr) * 64 + skc];
                rV0 = *(const s8v*)&V0p[(size_t)svd * NT + k1 + svc];
                if (TWO) rV1 = *(const s8v*)&V1p[(size_t)svd * NT + k1 + svc];
            }
            if (kt < mykt) {
                // ---- S^T = K Q^T (log2 domain): s[mt][nt][r] =
                //      P[kpos = k0 + quad*8 + nt*4 + r][q = rowb + l16] ----
                f4 s[2][2];
#pragma unroll
                for (int mt = 0; mt < 2; ++mt) { s[mt][0] = f4{0,0,0,0}; s[mt][1] = f4{0,0,0,0}; }
                __builtin_amdgcn_s_setprio(1);
#pragma unroll
                for (int nt = 0; nt < 2; ++nt)
#pragma unroll
                    for (int ch = 0; ch < 2; ++ch) {
                        const s8v kf = *(const s8v*)&Ks[cb][(sig + nt * 4) * 70 + ch * 32 + quad * 8];
                        s[0][nt] = __builtin_amdgcn_mfma_f32_16x16x32_bf16(kf, qf[0][ch], s[0][nt], 0, 0, 0);
                        s[1][nt] = __builtin_amdgcn_mfma_f32_16x16x32_bf16(kf, qf[1][ch], s[1][nt], 0, 0, 0);
                    }
                __builtin_amdgcn_s_setprio(0);

                // ---- softmax + in-register P pack, per m-tile ----
                s8v pa[2];
#pragma unroll
                for (int mt = 0; mt < 2; ++mt) {
                    const int rowb = q0 + 32 * wv + 16 * mt;
                    const int qrow = rowb + l16;
                    float a[8];
#pragma unroll
                    for (int nt = 0; nt < 2; ++nt)
#pragma unroll
                        for (int r = 0; r < 4; ++r) a[nt * 4 + r] = s[mt][nt][r];
                    if (k0 + 31 > rowb) {
#pragma unroll
                        for (int nt = 0; nt < 2; ++nt)
#pragma unroll
                            for (int r = 0; r < 4; ++r)
                                if (k0 + quad * 8 + nt * 4 + r > qrow) a[nt * 4 + r] = NEG;
                    }
                    const float c = fmaxf(fmaxf(fmaxf(a[0], a[1]), fmaxf(a[2], a[3])),
                                          fmaxf(fmaxf(a[4], a[5]), fmaxf(a[6], a[7])));
                    if (__any(c - mi[mt] > 8.0f)) {     // rare: row max grew
                        const float mx = rowred_max(c); // full-row max, quad-consistent
                        const float nm = fmaxf(mi[mt], mx);
                        const float al = exp2fast(mi[mt] - nm);
                        mi[mt] = nm;
                        li[mt] *= al;
#pragma unroll
                        for (int r = 0; r < 4; ++r) {
                            // al lives at lane l16 = acc row; uniform across quads
                            const float alr = __shfl(al, (lane & 48) | (quad * 4 + r), 64);
#pragma unroll
                            for (int dt = 0; dt < 4; ++dt) acc0[mt][dt][r] *= alr;
                            if (TWO) {
#pragma unroll
                                for (int dt = 0; dt < 4; ++dt) acc1[mt][dt][r] *= alr;
                            }
                        }
                    }
                    float p[8];
#pragma unroll
                    for (int j = 0; j < 8; ++j) p[j] = exp2fast(a[j] - mi[mt]);  // <= 2^8
                    li[mt] += ((p[0] + p[1]) + (p[2] + p[3])) + ((p[4] + p[5]) + (p[6] + p[7]));
                    i4v pi;
#pragma unroll
                    for (int jj = 0; jj < 4; ++jj)
                        pi[jj] = cvtpk_bf16(p[2 * jj], p[2 * jj + 1]);
                    pa[mt] = __builtin_bit_cast(s8v, pi);
                }
                // ---- O += P V (pa is the A fragment directly) ----
                __builtin_amdgcn_s_setprio(1);
#pragma unroll
                for (int dt = 0; dt < 4; ++dt) {
                    const s8v vf0 = *(const s8v*)&Vs[cb][0][(dt * 16 + l16) * 40 + quad * 8];
                    acc0[0][dt] = __builtin_amdgcn_mfma_f32_16x16x32_bf16(pa[0], vf0, acc0[0][dt], 0, 0, 0);
                    acc0[1][dt] = __builtin_amdgcn_mfma_f32_16x16x32_bf16(pa[1], vf0, acc0[1][dt], 0, 0, 0);
                    if (TWO) {
                        const s8v vf1 = *(const s8v*)&Vs[cb][1][(dt * 16 + l16) * 40 + quad * 8];
                        acc1[0][dt] = __builtin_amdgcn_mfma_f32_16x16x32_bf16(pa[0], vf1, acc1[0][dt], 0, 0, 0);
                        acc1[1][dt] = __builtin_amdgcn_mfma_f32_16x16x32_bf16(pa[1], vf1, acc1[1][dt], 0, 0, 0);
                    }
                }
                __builtin_amdgcn_s_setprio(0);
            }
            if (pf) {                      // stage next tile into buf[nb]
                *(s8v*)&Ks[nb][skr * 70 + skc]    = rK;
                *(s8v*)&Vs[nb][0][svd * 40 + svc] = rV0;
                if (TWO) *(s8v*)&Vs[nb][1][svd * 40 + svc] = rV1;
            }
        }

#pragma unroll
        for (int mt = 0; mt < 2; ++mt) {
            // total row sum (uniform across quads after reduce), then redistribute
            const float invq = 1.f / rowred_sum(li[mt]);
            float inv[4];
#pragma unroll
            for (int r = 0; r < 4; ++r)
                inv[r] = __shfl(invq, (lane & 48) | (quad * 4 + r), 64);
#pragma unroll
            for (int dt = 0; dt < 4; ++dt)
#pragma unroll
                for (int r = 0; r < 4; ++r) {
                    const size_t o = hb + (size_t)(q0 + 32 * wv + 16 * mt + quad * 4 + r) * 64 + dt * 16 + l16;
                    if (!TWO) {
                        ybuf[o] = acc0[mt][dt][r] * inv[r];
                    } else {
                        const float xa = acc0[mt][dt][r] * inv[r];
                        const float xb = acc1[mt][dt][r] * inv[r];
                        cand[(size_t)(sv - 1) * BHTD + o] = bfbits(fminf(xa, xb));
                        cand[(size_t)(3 + sv) * BHTD + o] = bfbits(fmaxf(xa, xb));
                    }
                }
        }
    }
}

// ---------------------------------------------------------------------------
// Kernel 3: MFMA output projection. o=0: A=y fp32; o=1: A=min of 4 candLo;
// o=2: A=max of 4 candHi. B=Wp (bf16-converted in-reg). out fp32.
// XCD-COLOCATED 1D grid (2304): xcd=b%8; s=b/8; o=s%3, jx=(s/3)%12 fastest,
// ny=xcd+8*(s/36): all 36 (o,jx) blocks of one n0 run on one XCD -> cand/y
// tile read once from HBM (rest L2); Wp (2.25MB) stays L2-resident.
// Ping-pong LDS double buffer: ONE barrier per K-step.
// ---------------------------------------------------------------------------
__global__ __launch_bounds__(256) void out_proj_mfma(
    const float* __restrict__ ybuf, const short* __restrict__ cand,
    const float* __restrict__ Wp, float* __restrict__ out)
{
    // per-buffer layout (shorts): As=0, Bs=2560 (each [64][40])
    __shared__ short sm3[2][2 * 2560];      // 20.5 KB
    float* Eb = (float*)sm3;                // epilogue alias [64][68] (17.4 KB)

    const int b_  = blockIdx.x;             // 0..2303
    const int xcd = b_ & 7;
    const int s_  = b_ >> 3;                // 0..287
    const int o   = s_ % 3;
    const int jx  = (s_ / 3) % 12;
    const int ny  = xcd + 8 * (s_ / 36);    // 0..63
    const int j0 = jx * 64, n0 = ny * 64;
    const int t  = threadIdx.x;
    const int wv = t >> 6, lane = t & 63, quad = lane >> 4, l16 = lane & 15;
    const int rw = t >> 2, koff = (t & 3) * 8;

    f4 acc[4];
#pragma unroll
    for (int i = 0; i < 4; i++) acc[i] = f4{0,0,0,0};

    const int token = n0 + rw, b = token >> 11, tt = token & 2047;
    const size_t wbase = (size_t)(j0 + rw) * NC + koff;
    const short* cb = cand + (size_t)(o == 1 ? 0 : 4) * BHTD;

    f4 ry0, ry1, rw0, rw1;
    s8v rc0, rc1, rc2, rc3;

    auto convert = [&](s8v& av, s8v& bv) {
        if (o == 0) {
#pragma unroll
            for (int i = 0; i < 4; i++) { av[i] = bfbits(ry0[i]); av[4 + i] = bfbits(ry1[i]); }
        } else {
            float v[8];
#pragma unroll
            for (int i = 0; i < 8; i++) v[i] = bf2f(rc0[i]);
            if (o == 1) {
#pragma unroll
                for (int i = 0; i < 8; i++) v[i] = fminf(v[i], bf2f(rc1[i]));
#pragma unroll
                for (int i = 0; i < 8; i++) v[i] = fminf(v[i], bf2f(rc2[i]));
#pragma unroll
                for (int i = 0; i < 8; i++) v[i] = fminf(v[i], bf2f(rc3[i]));
            } else {
#pragma unroll
                for (int i = 0; i < 8; i++) v[i] = fmaxf(v[i], bf2f(rc1[i]));
#pragma unroll
                for (int i = 0; i < 8; i++) v[i] = fmaxf(v[i], bf2f(rc2[i]));
#pragma unroll
                for (int i = 0; i < 8; i++) v[i] = fmaxf(v[i], bf2f(rc3[i]));
            }
#pragma unroll
            for (int i = 0; i < 8; i++) av[i] = bfbits(v[i]);
        }
#pragma unroll
        for (int i = 0; i < 4; i++) { bv[i] = bfbits(rw0[i]); bv[4 + i] = bfbits(rw1[i]); }
    };
    auto loadTile = [&](int k1) {
        const int hh = k1 >> 6, d0 = (k1 & 63) + koff;
        const size_t aoff = ((size_t)(b * 12 + hh) * NT + tt) * 64 + d0;
        if (o == 0) {
            ry0 = *(const f4*)&ybuf[aoff];
            ry1 = *(const f4*)&ybuf[aoff + 4];
        } else {
            rc0 = *(const s8v*)&cb[aoff];
            rc1 = *(const s8v*)&cb[(size_t)1 * BHTD + aoff];
            rc2 = *(const s8v*)&cb[(size_t)2 * BHTD + aoff];
            rc3 = *(const s8v*)&cb[(size_t)3 * BHTD + aoff];
        }
        rw0 = *(const f4*)&Wp[wbase + k1];
        rw1 = *(const f4*)&Wp[wbase + k1 + 4];
    };

    // prologue: tile 0 -> regs -> convert -> buf 0
    loadTile(0);
    {
        s8v av, bv;
        convert(av, bv);
        *(s8v*)&sm3[0][rw * 40 + koff]        = av;
        *(s8v*)&sm3[0][2560 + rw * 40 + koff] = bv;
    }

    for (int it = 0; it < NC / 32; ++it) {
        const int cbuf = it & 1, nbuf = cbuf ^ 1;
        __syncthreads();
        const bool pf = (it + 1 < NC / 32);
        if (pf) loadTile((it + 1) * 32);
        const s8v af = *(const s8v*)&sm3[cbuf][(wv * 16 + l16) * 40 + quad * 8];
#pragma unroll
        for (int nt = 0; nt < 4; ++nt) {
            const s8v bf = *(const s8v*)&sm3[cbuf][2560 + (nt * 16 + l16) * 40 + quad * 8];
            acc[nt] = __builtin_amdgcn_mfma_f32_16x16x32_bf16(af, bf, acc[nt], 0, 0, 0);
        }
        if (pf) {
            s8v av, bv;
            convert(av, bv);
            *(s8v*)&sm3[nbuf][rw * 40 + koff]        = av;
            *(s8v*)&sm3[nbuf][2560 + rw * 40 + koff] = bv;
        }
    }
    __syncthreads();
#pragma unroll
    for (int nt = 0; nt < 4; ++nt)
#pragma unroll
        for (int r = 0; r < 4; ++r)
            Eb[(wv * 16 + quad * 4 + r) * 68 + nt * 16 + l16] = acc[nt][r];
    __syncthreads();
    const int cc = (t & 3) * 16;
#pragma unroll
    for (int i = 0; i < 4; ++i) {
        const f4 vo = *(const f4*)&Eb[rw * 68 + cc + 4 * i];
        *(f4*)&out[(size_t)o * BTC + (size_t)(n0 + rw) * NC + j0 + cc + 4 * i] = vo;
    }
}

extern "C" void kernel_launch(void* const* d_in, const int* in_sizes, int n_in,
                              void* d_out, int out_size, void* d_ws, size_t ws_size,
                              hipStream_t stream)
{
    const float* x  = (const float*)d_in[0];
    const float* xl = (const float*)d_in[1];
    const float* xu = (const float*)d_in[2];
    const float* Wa = (const float*)d_in[3];
    const float* Wp = (const float*)d_in[4];
    float* out = (float*)d_out;

    short* qkvb = (short*)d_ws;                       // 9*BHTD bf16  = 56.6 MB
    float* ybuf = (float*)(qkvb + (size_t)9 * BHTD);  // 1*BHTD f32   = 12.6 MB
    short* cand = (short*)(ybuf + (size_t)BHTD);      // 8*BHTD bf16  = 50.3 MB

    // prep arrays alias cand (dead until flash writes it; consumed by qkv_proj)
    short* xn = cand;                      // BTC shorts
    short* xm = cand + (size_t)1 * BHTD;   // BTC shorts
    short* xr = cand + (size_t)2 * BHTD;   // BTC shorts
    short* wb = cand + (size_t)3 * BHTD;   // NWA shorts (fits in BHTD)

    prep_cvt     <<<dim3(1536), 256, 0, stream>>>(x, xl, xu, Wa, xn, xm, xr, wb);
    qkv_proj_mfma<<<dim3(2304), 256, 0, stream>>>(xn, xm, xr, wb, qkvb);
    flash_mfma   <<<dim3(960),  256, 0, stream>>>(qkvb, ybuf, cand);
    out_proj_mfma<<<dim3(2304), 256, 0, stream>>>(ybuf, cand, Wp, out);
}

// Round 10
// 396.581 us; speedup vs baseline: 2.1721x; 1.0534x over previous
//
#include <hip/hip_runtime.h>
#include <hip/hip_bf16.h>
#include <cstdint>

typedef float f4  __attribute__((ext_vector_type(4)));
typedef short s8v __attribute__((ext_vector_type(8)));   // 8 bf16 (4 VGPRs)
typedef int   i4v __attribute__((ext_vector_type(4)));

#define BHTD 3145728    // B*H*T*D = 2*12*2048*64
#define BTC  3145728
#define NT   2048
#define NC   768
#define NWA  1769472    // 3C*C = 2304*768
#define NWP  589824     // C*C = 768*768
#define NEG  -1e30f
// 0.125 (1/sqrt(64)) * log2(e): folded into Q at the producer so the flash
// kernel's scores are already in log2 domain (exp2 instead of expf, no scale mul)
#define QSCALE 0.18033688f

static __device__ __forceinline__ short bfbits(float f) {
    return __builtin_bit_cast(short, __float2bfloat16(f));
}
static __device__ __forceinline__ float bf2f(short s) {
    return __builtin_bit_cast(float, (int)(((unsigned int)(unsigned short)s) << 16));
}
static __device__ __forceinline__ float exp2fast(float x) {
    return __builtin_amdgcn_exp2f(x);
}
// hardware packed f32->bf16 (RNE), lo -> [15:0], hi -> [31:16]
static __device__ __forceinline__ int cvtpk_bf16(float lo, float hi) {
    int r;
    asm("v_cvt_pk_bf16_f32 %0, %1, %2" : "=v"(r) : "v"(lo), "v"(hi));
    return r;
}
// row reductions across the 4 quads (lanes l16, l16+16, l16+32, l16+48)
static __device__ __forceinline__ float rowred_max(float x) {
    x = fmaxf(x, __shfl_xor(x, 16, 64));
    x = fmaxf(x, __shfl_xor(x, 32, 64));
    return x;
}
static __device__ __forceinline__ float rowred_sum(float x) {
    x += __shfl_xor(x, 16, 64);
    x += __shfl_xor(x, 32, 64);
    return x;
}

// ---------------------------------------------------------------------------
// Kernel 0: one-shot fp32->bf16 conversion. xn=x, xm=(xl+xu)/2, xr=(xu-xl)/2,
// wb=W_attn, wpb=W_proj. Removes per-block re-conversion from the GEMMs.
// ---------------------------------------------------------------------------
__global__ __launch_bounds__(256) void prep_cvt(
    const float* __restrict__ x, const float* __restrict__ xl,
    const float* __restrict__ xu, const float* __restrict__ W,
    const float* __restrict__ Wp,
    short* __restrict__ xn, short* __restrict__ xm, short* __restrict__ xr,
    short* __restrict__ wb, short* __restrict__ wpb)
{
    const size_t flat = (size_t)blockIdx.x * 256 + threadIdx.x;
    const size_t i = flat * 8;        // 1536*256*8 == BTC exactly
    {
        const f4 a0 = *(const f4*)&x[i],  a1 = *(const f4*)&x[i + 4];
        const f4 l0 = *(const f4*)&xl[i], l1 = *(const f4*)&xl[i + 4];
        const f4 u0 = *(const f4*)&xu[i], u1 = *(const f4*)&xu[i + 4];
        s8v vn, vm, vr;
#pragma unroll
        for (int j = 0; j < 4; j++) {
            vn[j]     = bfbits(a0[j]);                   vn[4 + j] = bfbits(a1[j]);
            vm[j]     = bfbits(0.5f * (l0[j] + u0[j]));  vm[4 + j] = bfbits(0.5f * (l1[j] + u1[j]));
            vr[j]     = bfbits(0.5f * (u0[j] - l0[j]));  vr[4 + j] = bfbits(0.5f * (u1[j] - l1[j]));
        }
        *(s8v*)&xn[i] = vn;
        *(s8v*)&xm[i] = vm;
        *(s8v*)&xr[i] = vr;
    }
    if (flat < NWA / 8) {
        const size_t wi = flat * 8;
        const f4 w0 = *(const f4*)&W[wi], w1 = *(const f4*)&W[wi + 4];
        s8v vw;
#pragma unroll
        for (int j = 0; j < 4; j++) { vw[j] = bfbits(w0[j]); vw[4 + j] = bfbits(w1[j]); }
        *(s8v*)&wb[wi] = vw;
    }
    if (flat < NWP / 8) {
        const size_t wi = flat * 8;
        const f4 w0 = *(const f4*)&Wp[wi], w1 = *(const f4*)&Wp[wi + 4];
        s8v vw;
#pragma unroll
        for (int j = 0; j < 4; j++) { vw[j] = bfbits(w0[j]); vw[4 + j] = bfbits(w1[j]); }
        *(s8v*)&wpb[wi] = vw;
    }
}

// ---------------------------------------------------------------------------
// Kernel 1: MFMA QKV projection from pre-converted bf16 inputs.
// nom=xn@wb^T, mid=xm@wb^T, rad=xr@|wb|^T (|wb| derived in-reg).
// XCD-COLOCATED 1D grid (2304): xcd=b%8; s=b/8; jx=s%36 fastest;
// ny = xcd + 8*(s/36). Outputs bf16: Q,K [var][part][B,H,T,D]; V [B,H,D,T].
// Q (p==0) pre-scaled by 0.125*log2e. Ping-pong LDS dbuf, ONE barrier/K-step.
// ---------------------------------------------------------------------------
__global__ __launch_bounds__(256) void qkv_proj_mfma(
    const short* __restrict__ xn, const short* __restrict__ xm,
    const short* __restrict__ xr, const short* __restrict__ wb,
    short* __restrict__ qkvb)
{
    // per-buffer layout (shorts): Ax=0, Am=2560, Ar=5120, Bw=7680 (each [64][40])
    __shared__ short sm[2][4 * 2560];   // 40 KB
    short* Eb = &sm[0][0];              // epilogue alias [64][72] (4608 shorts)

    const int b_  = blockIdx.x;         // 0..2303
    const int xcd = b_ & 7;
    const int s_  = b_ >> 3;            // 0..287
    const int jx  = s_ % 36;
    const int ny  = xcd + 8 * (s_ / 36);   // 0..63
    const int j0 = jx * 64;             // N in [0,2304)
    const int n0 = ny * 64;             // M in [0,4096)
    const int t  = threadIdx.x;
    const int wv = t >> 6, lane = t & 63, quad = lane >> 4, l16 = lane & 15;
    const int rw = t >> 2, koff = (t & 3) * 8;

    f4 aN[4], aM[4], aR[4];
#pragma unroll
    for (int i = 0; i < 4; i++) { aN[i] = f4{0,0,0,0}; aM[i] = f4{0,0,0,0}; aR[i] = f4{0,0,0,0}; }

    const size_t abase = (size_t)(n0 + rw) * NC + koff;
    const size_t bbase = (size_t)(j0 + rw) * NC + koff;

    s8v rn, rm, rr, rb;
    rn = *(const s8v*)&xn[abase];
    rm = *(const s8v*)&xm[abase];
    rr = *(const s8v*)&xr[abase];
    rb = *(const s8v*)&wb[bbase];
    *(s8v*)&sm[0][rw * 40 + koff]        = rn;
    *(s8v*)&sm[0][2560 + rw * 40 + koff] = rm;
    *(s8v*)&sm[0][5120 + rw * 40 + koff] = rr;
    *(s8v*)&sm[0][7680 + rw * 40 + koff] = rb;

    for (int it = 0; it < NC / 32; ++it) {
        const int cb = it & 1, nb = cb ^ 1;
        __syncthreads();                       // buf[cb] complete
        const bool pf = (it + 1 < NC / 32);
        if (pf) {                              // issue next-tile loads early
            const size_t k1 = (size_t)(it + 1) * 32;
            rn = *(const s8v*)&xn[abase + k1];
            rm = *(const s8v*)&xm[abase + k1];
            rr = *(const s8v*)&xr[abase + k1];
            rb = *(const s8v*)&wb[bbase + k1];
        }
        const s8v fx = *(const s8v*)&sm[cb][(wv * 16 + l16) * 40 + quad * 8];
        const s8v fm = *(const s8v*)&sm[cb][2560 + (wv * 16 + l16) * 40 + quad * 8];
        const s8v fr = *(const s8v*)&sm[cb][5120 + (wv * 16 + l16) * 40 + quad * 8];
#pragma unroll
        for (int nt = 0; nt < 4; ++nt) {
            const s8v fb = *(const s8v*)&sm[cb][7680 + (nt * 16 + l16) * 40 + quad * 8];
            i4v bi = __builtin_bit_cast(i4v, fb);
#pragma unroll
            for (int i = 0; i < 4; i++) bi[i] &= 0x7fff7fff;
            const s8v fa = __builtin_bit_cast(s8v, bi);
            aN[nt] = __builtin_amdgcn_mfma_f32_16x16x32_bf16(fx, fb, aN[nt], 0, 0, 0);
            aM[nt] = __builtin_amdgcn_mfma_f32_16x16x32_bf16(fm, fb, aM[nt], 0, 0, 0);
            aR[nt] = __builtin_amdgcn_mfma_f32_16x16x32_bf16(fr, fa, aR[nt], 0, 0, 0);
        }
        if (pf) {                              // stage into buf[nb]
            *(s8v*)&sm[nb][rw * 40 + koff]        = rn;
            *(s8v*)&sm[nb][2560 + rw * 40 + koff] = rm;
            *(s8v*)&sm[nb][5120 + rw * 40 + koff] = rr;
            *(s8v*)&sm[nb][7680 + rw * 40 + koff] = rb;
        }
    }

    const int p = j0 / NC, hh = (j0 % NC) >> 6;
    const float osc = (p == 0) ? QSCALE : 1.0f;   // pre-scale Q for exp2-domain flash
    const int cc16 = (t & 3) * 16;
    for (int var = 0; var < 3; ++var) {
        __syncthreads();
#pragma unroll
        for (int nt = 0; nt < 4; ++nt)
#pragma unroll
            for (int r = 0; r < 4; ++r) {
                const float v = (var == 0) ? aN[nt][r]
                              : (var == 1) ? aM[nt][r] - aR[nt][r]
                                           : aM[nt][r] + aR[nt][r];
                Eb[(wv * 16 + quad * 4 + r) * 72 + nt * 16 + l16] = bfbits(v * osc);
            }
        __syncthreads();
        short* dst = qkvb + (size_t)(var * 3 + p) * BHTD;
        if (p < 2) {       // Q,K row-major [B,H,T,D]
            const int token = n0 + rw, b = token >> 11, tt = token & 2047;
            const size_t o = ((size_t)(b * 12 + hh) * NT + tt) * 64 + cc16;
            *(s8v*)&dst[o]     = *(const s8v*)&Eb[rw * 72 + cc16];
            *(s8v*)&dst[o + 8] = *(const s8v*)&Eb[rw * 72 + cc16 + 8];
        } else {           // V transposed [B,H,D,T]
            const int d = rw;
            s8v e0, e1;
#pragma unroll
            for (int i = 0; i < 8; i++) e0[i] = Eb[(cc16 + i) * 72 + d];
#pragma unroll
            for (int i = 0; i < 8; i++) e1[i] = Eb[(cc16 + 8 + i) * 72 + d];
            const int token0 = n0 + cc16, b = token0 >> 11, tt = token0 & 2047;
            const size_t o = ((size_t)(b * 12 + hh) * 64 + d) * NT + tt;
            *(s8v*)&dst[o]     = e0;
            *(s8v*)&dst[o + 8] = e1;
        }
    }
}

// ---------------------------------------------------------------------------
// Kernel 2: MFMA flash, merged nominal + 4 bound branches in one launch.
// 1D grid 960, XCD-aware: xcd=b%8 == bh%8 (R8: FETCH 279->31MB).
// LOAD-BALANCED pairs (pr, 15-pr) -> uniform 68 kt-iters.
// SWAPPED QK^T (P in registers); cvt_pk P pack; Ks pad 70 (odd bank stride).
// y output now written as BF16 (out_proj consumed it as bf16 anyway).
// Ping-pong LDS dbuf, ONE barrier/k-tile; T14 prefetch; T13 defer-max;
// setprio around MFMA.
// ---------------------------------------------------------------------------
__global__ __launch_bounds__(256) void flash_mfma(
    const short* __restrict__ qkvb, short* __restrict__ ybf,
    short* __restrict__ cand)
{
    const int b_  = blockIdx.x;            // 0..959
    const int xcd = b_ & 7;
    const int r_  = b_ >> 3;               // 0..119
    const int pr  = r_ & 7;                // 0..7
    const int r2  = r_ >> 3;               // 0..14
    const int z   = r2 % 5;
    const int bh  = xcd + 8 * (r2 / 5);    // 0..23
    const int t   = threadIdx.x;
    const int wv = t >> 6, lane = t & 63, quad = lane >> 4, l16 = lane & 15;
    const bool TWO = (z != 0);

    __shared__ short Ks[2][32 * 70];       // [buf][kpos][d] pad 70 (9.0 KB)
    __shared__ short Vs[2][2][64 * 40];    // [buf][sv][d][kpos] (20.5 KB)

    int sv, qvi, kvi, v0i, v1i;
    if (TWO) { sv = z; qvi = (sv + 1) >> 1; kvi = 2 - (sv & 1); v0i = 1; v1i = 2; }
    else     { sv = 0; qvi = 0; kvi = 0; v0i = 0; v1i = 0; }

    const size_t hb = (size_t)bh * (NT * 64);
    const short* Qp  = qkvb + (size_t)(qvi * 3 + 0) * BHTD + hb;  // [t][d] (pre-scaled)
    const short* Kp  = qkvb + (size_t)(kvi * 3 + 1) * BHTD + hb;  // [t][d]
    const short* V0p = qkvb + (size_t)(v0i * 3 + 2) * BHTD + hb;  // [d][t] !
    const short* V1p = qkvb + (size_t)(v1i * 3 + 2) * BHTD + hb;

    const int skr = t >> 3, skc = (t & 7) * 8;   // K stage: 32 x 64
    const int svd = t >> 2, svc = (t & 3) * 8;   // V stage: 64 x 32
    const int sig = (l16 >> 2) * 8 + (l16 & 3);  // K A-frag row permutation

    for (int half = 0; half < 2; ++half) {
        const int qt = half ? (15 - pr) : pr;
        const int q0 = qt * 128;

        // Q fragments (serve as the MFMA B operand in the swapped product)
        s8v qf[2][2];
#pragma unroll
        for (int mt = 0; mt < 2; ++mt)
#pragma unroll
            for (int ch = 0; ch < 2; ++ch)
                qf[mt][ch] = *(const s8v*)&Qp[(size_t)(q0 + 32 * wv + 16 * mt + l16) * 64 + ch * 32 + quad * 8];

        float mi[2], li[2];                // per-lane: row q = rowb + l16; li = quad-partial
        mi[0] = mi[1] = NEG; li[0] = li[1] = 0.f;
        f4 acc0[2][4], acc1[2][4];
#pragma unroll
        for (int mt = 0; mt < 2; ++mt)
#pragma unroll
            for (int i = 0; i < 4; ++i) { acc0[mt][i] = f4{0,0,0,0}; acc1[mt][i] = f4{0,0,0,0}; }

        const int ktn  = 4 * qt + 4;
        const int mykt = 4 * qt + wv + 1;  // last tile this wave's rows need

        // prologue: barrier (protect prior half's live buffers), tile 0 -> buf 0
        __syncthreads();
        s8v rK, rV0, rV1;
        rK  = *(const s8v*)&Kp[(size_t)skr * 64 + skc];
        rV0 = *(const s8v*)&V0p[(size_t)svd * NT + svc];
        if (TWO) rV1 = *(const s8v*)&V1p[(size_t)svd * NT + svc];
        *(s8v*)&Ks[0][skr * 70 + skc]    = rK;
        *(s8v*)&Vs[0][0][svd * 40 + svc] = rV0;
        if (TWO) *(s8v*)&Vs[0][1][svd * 40 + svc] = rV1;

        for (int kt = 0; kt < ktn; ++kt) {
            const int k0 = kt * 32;
            const int cb = kt & 1, nb = cb ^ 1;
            __syncthreads();               // buf[cb] complete for all waves
            const bool pf = (kt + 1 < ktn);
            if (pf) {                      // issue next-tile loads early
                const int k1 = k0 + 32;
                rK  = *(const s8v*)&Kp[(size_t)(k1 + skr) * 64 + skc];
                rV0 = *(const s8v*)&V0p[(size_t)svd * NT + k1 + svc];
                if (TWO) rV1 = *(const s8v*)&V1p[(size_t)svd * NT + k1 + svc];
            }
            if (kt < mykt) {
                // ---- S^T = K Q^T (log2 domain): s[mt][nt][r] =
                //      P[kpos = k0 + quad*8 + nt*4 + r][q = rowb + l16] ----
                f4 s[2][2];
#pragma unroll
                for (int mt = 0; mt < 2; ++mt) { s[mt][0] = f4{0,0,0,0}; s[mt][1] = f4{0,0,0,0}; }
                __builtin_amdgcn_s_setprio(1);
#pragma unroll
                for (int nt = 0; nt < 2; ++nt)
#pragma unroll
                    for (int ch = 0; ch < 2; ++ch) {
                        const s8v kf = *(const s8v*)&Ks[cb][(sig + nt * 4) * 70 + ch * 32 + quad * 8];
                        s[0][nt] = __builtin_amdgcn_mfma_f32_16x16x32_bf16(kf, qf[0][ch], s[0][nt], 0, 0, 0);
                        s[1][nt] = __builtin_amdgcn_mfma_f32_16x16x32_bf16(kf, qf[1][ch], s[1][nt], 0, 0, 0);
                    }
                __builtin_amdgcn_s_setprio(0);

                // ---- softmax + in-register P pack, per m-tile ----
                s8v pa[2];
#pragma unroll
                for (int mt = 0; mt < 2; ++mt) {
                    const int rowb = q0 + 32 * wv + 16 * mt;
                    const int qrow = rowb + l16;
                    float a[8];
#pragma unroll
                    for (int nt = 0; nt < 2; ++nt)
#pragma unroll
                        for (int r = 0; r < 4; ++r) a[nt * 4 + r] = s[mt][nt][r];
                    if (k0 + 31 > rowb) {
#pragma unroll
                        for (int nt = 0; nt < 2; ++nt)
#pragma unroll
                            for (int r = 0; r < 4; ++r)
                                if (k0 + quad * 8 + nt * 4 + r > qrow) a[nt * 4 + r] = NEG;
                    }
                    const float c = fmaxf(fmaxf(fmaxf(a[0], a[1]), fmaxf(a[2], a[3])),
                                          fmaxf(fmaxf(a[4], a[5]), fmaxf(a[6], a[7])));
                    if (__any(c - mi[mt] > 8.0f)) {     // rare: row max grew
                        const float mx = rowred_max(c); // full-row max, quad-consistent
                        const float nm = fmaxf(mi[mt], mx);
                        const float al = exp2fast(mi[mt] - nm);
                        mi[mt] = nm;
                        li[mt] *= al;
#pragma unroll
                        for (int r = 0; r < 4; ++r) {
                            // al lives at lane l16 = acc row; uniform across quads
                            const float alr = __shfl(al, (lane & 48) | (quad * 4 + r), 64);
#pragma unroll
                            for (int dt = 0; dt < 4; ++dt) acc0[mt][dt][r] *= alr;
                            if (TWO) {
#pragma unroll
                                for (int dt = 0; dt < 4; ++dt) acc1[mt][dt][r] *= alr;
                            }
                        }
                    }
                    float p[8];
#pragma unroll
                    for (int j = 0; j < 8; ++j) p[j] = exp2fast(a[j] - mi[mt]);  // <= 2^8
                    li[mt] += ((p[0] + p[1]) + (p[2] + p[3])) + ((p[4] + p[5]) + (p[6] + p[7]));
                    i4v pi;
#pragma unroll
                    for (int jj = 0; jj < 4; ++jj)
                        pi[jj] = cvtpk_bf16(p[2 * jj], p[2 * jj + 1]);
                    pa[mt] = __builtin_bit_cast(s8v, pi);
                }
                // ---- O += P V (pa is the A fragment directly) ----
                __builtin_amdgcn_s_setprio(1);
#pragma unroll
                for (int dt = 0; dt < 4; ++dt) {
                    const s8v vf0 = *(const s8v*)&Vs[cb][0][(dt * 16 + l16) * 40 + quad * 8];
                    acc0[0][dt] = __builtin_amdgcn_mfma_f32_16x16x32_bf16(pa[0], vf0, acc0[0][dt], 0, 0, 0);
                    acc0[1][dt] = __builtin_amdgcn_mfma_f32_16x16x32_bf16(pa[1], vf0, acc0[1][dt], 0, 0, 0);
                    if (TWO) {
                        const s8v vf1 = *(const s8v*)&Vs[cb][1][(dt * 16 + l16) * 40 + quad * 8];
                        acc1[0][dt] = __builtin_amdgcn_mfma_f32_16x16x32_bf16(pa[0], vf1, acc1[0][dt], 0, 0, 0);
                        acc1[1][dt] = __builtin_amdgcn_mfma_f32_16x16x32_bf16(pa[1], vf1, acc1[1][dt], 0, 0, 0);
                    }
                }
                __builtin_amdgcn_s_setprio(0);
            }
            if (pf) {                      // stage next tile into buf[nb]
                *(s8v*)&Ks[nb][skr * 70 + skc]    = rK;
                *(s8v*)&Vs[nb][0][svd * 40 + svc] = rV0;
                if (TWO) *(s8v*)&Vs[nb][1][svd * 40 + svc] = rV1;
            }
        }

#pragma unroll
        for (int mt = 0; mt < 2; ++mt) {
            // total row sum (uniform across quads after reduce), then redistribute
            const float invq = 1.f / rowred_sum(li[mt]);
            float inv[4];
#pragma unroll
            for (int r = 0; r < 4; ++r)
                inv[r] = __shfl(invq, (lane & 48) | (quad * 4 + r), 64);
#pragma unroll
            for (int dt = 0; dt < 4; ++dt)
#pragma unroll
                for (int r = 0; r < 4; ++r) {
                    const size_t o = hb + (size_t)(q0 + 32 * wv + 16 * mt + quad * 4 + r) * 64 + dt * 16 + l16;
                    if (!TWO) {
                        ybf[o] = bfbits(acc0[mt][dt][r] * inv[r]);
                    } else {
                        const float xa = acc0[mt][dt][r] * inv[r];
                        const float xb = acc1[mt][dt][r] * inv[r];
                        cand[(size_t)(sv - 1) * BHTD + o] = bfbits(fminf(xa, xb));
                        cand[(size_t)(3 + sv) * BHTD + o] = bfbits(fmaxf(xa, xb));
                    }
                }
        }
    }
}

// ---------------------------------------------------------------------------
// Kernel 2.5: fold the 4-way candidate min/max ONCE (was re-done 12x per jx
// inside out_proj). In-place: lo4 -> cand stream 0, hi4 -> cand stream 4.
// min/max of exact-bf16 values is exact, so >>16 truncation is lossless.
// ---------------------------------------------------------------------------
__global__ __launch_bounds__(256) void prep_out(short* __restrict__ cand)
{
    const size_t i = ((size_t)blockIdx.x * 256 + threadIdx.x) * 8;
    {
        const s8v c0 = *(const s8v*)&cand[i];
        const s8v c1 = *(const s8v*)&cand[(size_t)1 * BHTD + i];
        const s8v c2 = *(const s8v*)&cand[(size_t)2 * BHTD + i];
        const s8v c3 = *(const s8v*)&cand[(size_t)3 * BHTD + i];
        s8v lo;
#pragma unroll
        for (int j = 0; j < 8; j++) {
            const float v = fminf(fminf(bf2f(c0[j]), bf2f(c1[j])),
                                  fminf(bf2f(c2[j]), bf2f(c3[j])));
            lo[j] = (short)(__builtin_bit_cast(unsigned int, v) >> 16);
        }
        *(s8v*)&cand[i] = lo;
    }
    {
        const s8v c0 = *(const s8v*)&cand[(size_t)4 * BHTD + i];
        const s8v c1 = *(const s8v*)&cand[(size_t)5 * BHTD + i];
        const s8v c2 = *(const s8v*)&cand[(size_t)6 * BHTD + i];
        const s8v c3 = *(const s8v*)&cand[(size_t)7 * BHTD + i];
        s8v hi;
#pragma unroll
        for (int j = 0; j < 8; j++) {
            const float v = fmaxf(fmaxf(bf2f(c0[j]), bf2f(c1[j])),
                                  fmaxf(bf2f(c2[j]), bf2f(c3[j])));
            hi[j] = (short)(__builtin_bit_cast(unsigned int, v) >> 16);
        }
        *(s8v*)&cand[(size_t)4 * BHTD + i] = hi;
    }
}

// ---------------------------------------------------------------------------
// Kernel 3: MFMA output projection — now a PURE bf16 GEMM (A pre-reduced by
// prep_out, W pre-converted by prep_cvt): 2 loads + 4 MFMA per K-step.
// o=0: A=ybf; o=1: A=cand stream 0 (lo); o=2: A=cand stream 4 (hi).
// XCD-COLOCATED 1D grid (2304): xcd=b%8; s=b/8; o=s%3, jx=(s/3)%12 fastest,
// ny=xcd+8*(s/36). Ping-pong LDS dbuf, ONE barrier per K-step.
// ---------------------------------------------------------------------------
__global__ __launch_bounds__(256) void out_proj_mfma(
    const short* __restrict__ ybf, const short* __restrict__ cand,
    const short* __restrict__ wpb, float* __restrict__ out)
{
    // per-buffer layout (shorts): As=0, Bs=2560 (each [64][40])
    __shared__ short sm3[2][2 * 2560];      // 20.5 KB
    float* Eb = (float*)sm3;                // epilogue alias [64][68] (17.4 KB)

    const int b_  = blockIdx.x;             // 0..2303
    const int xcd = b_ & 7;
    const int s_  = b_ >> 3;                // 0..287
    const int o   = s_ % 3;
    const int jx  = (s_ / 3) % 12;
    const int ny  = xcd + 8 * (s_ / 36);    // 0..63
    const int j0 = jx * 64, n0 = ny * 64;
    const int t  = threadIdx.x;
    const int wv = t >> 6, lane = t & 63, quad = lane >> 4, l16 = lane & 15;
    const int rw = t >> 2, koff = (t & 3) * 8;

    f4 acc[4];
#pragma unroll
    for (int i = 0; i < 4; i++) acc[i] = f4{0,0,0,0};

    const int token = n0 + rw, b = token >> 11, tt = token & 2047;
    const size_t wbase = (size_t)(j0 + rw) * NC + koff;
    const short* Ap = (o == 0) ? ybf : (o == 1) ? cand : cand + (size_t)4 * BHTD;

    s8v ra, rb;
    auto loadTile = [&](int k1) {
        const int hh = k1 >> 6, d0 = (k1 & 63) + koff;
        const size_t aoff = ((size_t)(b * 12 + hh) * NT + tt) * 64 + d0;
        ra = *(const s8v*)&Ap[aoff];
        rb = *(const s8v*)&wpb[wbase + k1];
    };

    // prologue: tile 0 -> regs -> buf 0
    loadTile(0);
    *(s8v*)&sm3[0][rw * 40 + koff]        = ra;
    *(s8v*)&sm3[0][2560 + rw * 40 + koff] = rb;

    for (int it = 0; it < NC / 32; ++it) {
        const int cbuf = it & 1, nbuf = cbuf ^ 1;
        __syncthreads();
        const bool pf = (it + 1 < NC / 32);
        if (pf) loadTile((it + 1) * 32);
        const s8v af = *(const s8v*)&sm3[cbuf][(wv * 16 + l16) * 40 + quad * 8];
#pragma unroll
        for (int nt = 0; nt < 4; ++nt) {
            const s8v bf = *(const s8v*)&sm3[cbuf][2560 + (nt * 16 + l16) * 40 + quad * 8];
            acc[nt] = __builtin_amdgcn_mfma_f32_16x16x32_bf16(af, bf, acc[nt], 0, 0, 0);
        }
        if (pf) {
            *(s8v*)&sm3[nbuf][rw * 40 + koff]        = ra;
            *(s8v*)&sm3[nbuf][2560 + rw * 40 + koff] = rb;
        }
    }
    __syncthreads();
#pragma unroll
    for (int nt = 0; nt < 4; ++nt)
#pragma unroll
        for (int r = 0; r < 4; ++r)
            Eb[(wv * 16 + quad * 4 + r) * 68 + nt * 16 + l16] = acc[nt][r];
    __syncthreads();
    const int cc = (t & 3) * 16;
#pragma unroll
    for (int i = 0; i < 4; ++i) {
        const f4 vo = *(const f4*)&Eb[rw * 68 + cc + 4 * i];
        *(f4*)&out[(size_t)o * BTC + (size_t)(n0 + rw) * NC + j0 + cc + 4 * i] = vo;
    }
}

extern "C" void kernel_launch(void* const* d_in, const int* in_sizes, int n_in,
                              void* d_out, int out_size, void* d_ws, size_t ws_size,
                              hipStream_t stream)
{
    const float* x  = (const float*)d_in[0];
    const float* xl = (const float*)d_in[1];
    const float* xu = (const float*)d_in[2];
    const float* Wa = (const float*)d_in[3];
    const float* Wp = (const float*)d_in[4];
    float* out = (float*)d_out;

    short* qkvb = (short*)d_ws;                       // 9*BHTD bf16 = 56.6 MB
    short* ybf  = qkvb + (size_t)9 * BHTD;            // 1*BHTD bf16 =  6.3 MB
    short* cand = ybf + (size_t)BHTD;                 // 8*BHTD bf16 = 50.3 MB
    short* wpb  = cand + (size_t)8 * BHTD;            // NWP bf16   =  1.2 MB

    // prep aliases (inside cand; consumed by qkv before flash clobbers them)
    short* xn = cand;                      // BTC shorts
    short* xm = cand + (size_t)1 * BHTD;   // BTC shorts
    short* xr = cand + (size_t)2 * BHTD;   // BTC shorts
    short* wb = cand + (size_t)3 * BHTD;   // NWA shorts (fits in BHTD)

    prep_cvt     <<<dim3(1536), 256, 0, stream>>>(x, xl, xu, Wa, Wp, xn, xm, xr, wb, wpb);
    qkv_proj_mfma<<<dim3(2304), 256, 0, stream>>>(xn, xm, xr, wb, qkvb);
    flash_mfma   <<<dim3(960),  256, 0, stream>>>(qkvb, ybf, cand);
    prep_out     <<<dim3(1536), 256, 0, stream>>>(cand);
    out_proj_mfma<<<dim3(2304), 256, 0, stream>>>(ybf, cand, wpb, out);
}

// Round 11
// 377.618 us; speedup vs baseline: 2.2812x; 1.0502x over previous
//
#include <hip/hip_runtime.h>
#include <hip/hip_bf16.h>
#include <cstdint>

typedef float f4  __attribute__((ext_vector_type(4)));
typedef short s8v __attribute__((ext_vector_type(8)));   // 8 bf16 (4 VGPRs)
typedef int   i4v __attribute__((ext_vector_type(4)));

#define BHTD 3145728    // B*H*T*D = 2*12*2048*64
#define BTC  3145728
#define NT   2048
#define NC   768
#define NWA  1769472    // 3C*C = 2304*768
#define NWP  589824     // C*C = 768*768
#define NEG  -1e30f
// 0.125 (1/sqrt(64)) * log2(e): folded into Q at the producer so the flash
// kernel's scores are already in log2 domain (exp2 instead of expf, no scale mul)
#define QSCALE 0.18033688f

static __device__ __forceinline__ short bfbits(float f) {
    return __builtin_bit_cast(short, __float2bfloat16(f));
}
static __device__ __forceinline__ float bf2f(short s) {
    return __builtin_bit_cast(float, (int)(((unsigned int)(unsigned short)s) << 16));
}
static __device__ __forceinline__ float exp2fast(float x) {
    return __builtin_amdgcn_exp2f(x);
}
// hardware packed f32->bf16 (RNE), lo -> [15:0], hi -> [31:16]
static __device__ __forceinline__ int cvtpk_bf16(float lo, float hi) {
    int r;
    asm("v_cvt_pk_bf16_f32 %0, %1, %2" : "=v"(r) : "v"(lo), "v"(hi));
    return r;
}
// row reductions across the 4 quads (lanes l16, l16+16, l16+32, l16+48)
static __device__ __forceinline__ float rowred_max(float x) {
    x = fmaxf(x, __shfl_xor(x, 16, 64));
    x = fmaxf(x, __shfl_xor(x, 32, 64));
    return x;
}
static __device__ __forceinline__ float rowred_sum(float x) {
    x += __shfl_xor(x, 16, 64);
    x += __shfl_xor(x, 32, 64);
    return x;
}

// ---------------------------------------------------------------------------
// Kernel 0: one-shot fp32->bf16 conversion. xn=x, xm=(xl+xu)/2, xr=(xu-xl)/2,
// wb=W_attn, wpb=W_proj. Removes per-block re-conversion from the GEMMs.
// ---------------------------------------------------------------------------
__global__ __launch_bounds__(256) void prep_cvt(
    const float* __restrict__ x, const float* __restrict__ xl,
    const float* __restrict__ xu, const float* __restrict__ W,
    const float* __restrict__ Wp,
    short* __restrict__ xn, short* __restrict__ xm, short* __restrict__ xr,
    short* __restrict__ wb, short* __restrict__ wpb)
{
    const size_t flat = (size_t)blockIdx.x * 256 + threadIdx.x;
    const size_t i = flat * 8;        // 1536*256*8 == BTC exactly
    {
        const f4 a0 = *(const f4*)&x[i],  a1 = *(const f4*)&x[i + 4];
        const f4 l0 = *(const f4*)&xl[i], l1 = *(const f4*)&xl[i + 4];
        const f4 u0 = *(const f4*)&xu[i], u1 = *(const f4*)&xu[i + 4];
        s8v vn, vm, vr;
#pragma unroll
        for (int j = 0; j < 4; j++) {
            vn[j]     = bfbits(a0[j]);                   vn[4 + j] = bfbits(a1[j]);
            vm[j]     = bfbits(0.5f * (l0[j] + u0[j]));  vm[4 + j] = bfbits(0.5f * (l1[j] + u1[j]));
            vr[j]     = bfbits(0.5f * (u0[j] - l0[j]));  vr[4 + j] = bfbits(0.5f * (u1[j] - l1[j]));
        }
        *(s8v*)&xn[i] = vn;
        *(s8v*)&xm[i] = vm;
        *(s8v*)&xr[i] = vr;
    }
    if (flat < NWA / 8) {
        const size_t wi = flat * 8;
        const f4 w0 = *(const f4*)&W[wi], w1 = *(const f4*)&W[wi + 4];
        s8v vw;
#pragma unroll
        for (int j = 0; j < 4; j++) { vw[j] = bfbits(w0[j]); vw[4 + j] = bfbits(w1[j]); }
        *(s8v*)&wb[wi] = vw;
    }
    if (flat < NWP / 8) {
        const size_t wi = flat * 8;
        const f4 w0 = *(const f4*)&Wp[wi], w1 = *(const f4*)&Wp[wi + 4];
        s8v vw;
#pragma unroll
        for (int j = 0; j < 4; j++) { vw[j] = bfbits(w0[j]); vw[4 + j] = bfbits(w1[j]); }
        *(s8v*)&wpb[wi] = vw;
    }
}

// ---------------------------------------------------------------------------
// Kernel 1: MFMA QKV projection, M64 x N128 tile (24 MFMA per K-step: 2x the
// MFMA density of the old 64x64 tile at the same barrier/staging overhead).
// nom=xn@wb^T, mid=xm@wb^T, rad=xr@|wb|^T (|wb| derived in-reg).
// XCD-COLOCATED 1D grid (1152): xcd=b%8; s=b/8; jx=s%18 fastest;
// ny = xcd + 8*(s/18). The 128-wide tile spans 2 heads -> 2-pass epilogue.
// Outputs bf16: Q,K [var][part][B,H,T,D]; V [B,H,D,T].
// Q (p==0) pre-scaled by 0.125*log2e. Ping-pong LDS dbuf, ONE barrier/K-step.
// ---------------------------------------------------------------------------
__global__ __launch_bounds__(256, 3) void qkv_proj_mfma(
    const short* __restrict__ xn, const short* __restrict__ xm,
    const short* __restrict__ xr, const short* __restrict__ wb,
    short* __restrict__ qkvb)
{
    // per-buffer (shorts): Ax=0, Am=2560, Ar=5120 (each [64][40]);
    // Bw=7680 ([128][40] = 5120). Buffer stride 12800.
    __shared__ short sm[2][12800];      // 51.2 KB
    short* Eb = &sm[0][0];              // epilogue alias [64][72] (4608 shorts)

    const int b_  = blockIdx.x;         // 0..1151
    const int xcd = b_ & 7;
    const int s_  = b_ >> 3;            // 0..143
    const int jx  = s_ % 18;
    const int ny  = xcd + 8 * (s_ / 18);   // 0..63
    const int j0 = jx * 128;            // N in [0,2304)
    const int n0 = ny * 64;             // M in [0,4096)
    const int t  = threadIdx.x;
    const int wv = t >> 6, lane = t & 63, quad = lane >> 4, l16 = lane & 15;
    const int rw = t >> 2, koff = (t & 3) * 8;

    f4 aN[8], aM[8], aR[8];
#pragma unroll
    for (int i = 0; i < 8; i++) { aN[i] = f4{0,0,0,0}; aM[i] = f4{0,0,0,0}; aR[i] = f4{0,0,0,0}; }

    const size_t abase  = (size_t)(n0 + rw) * NC + koff;
    const size_t bbase0 = (size_t)(j0 + rw) * NC + koff;
    const size_t bbase1 = (size_t)(j0 + 64 + rw) * NC + koff;

    s8v rn, rm, rr, rb0, rb1;
    rn  = *(const s8v*)&xn[abase];
    rm  = *(const s8v*)&xm[abase];
    rr  = *(const s8v*)&xr[abase];
    rb0 = *(const s8v*)&wb[bbase0];
    rb1 = *(const s8v*)&wb[bbase1];
    *(s8v*)&sm[0][rw * 40 + koff]               = rn;
    *(s8v*)&sm[0][2560 + rw * 40 + koff]        = rm;
    *(s8v*)&sm[0][5120 + rw * 40 + koff]        = rr;
    *(s8v*)&sm[0][7680 + rw * 40 + koff]        = rb0;
    *(s8v*)&sm[0][7680 + (rw + 64) * 40 + koff] = rb1;

    for (int it = 0; it < NC / 32; ++it) {
        const int cb = it & 1, nb = cb ^ 1;
        __syncthreads();                       // buf[cb] complete
        const bool pf = (it + 1 < NC / 32);
        if (pf) {                              // issue next-tile loads early
            const size_t k1 = (size_t)(it + 1) * 32;
            rn  = *(const s8v*)&xn[abase + k1];
            rm  = *(const s8v*)&xm[abase + k1];
            rr  = *(const s8v*)&xr[abase + k1];
            rb0 = *(const s8v*)&wb[bbase0 + k1];
            rb1 = *(const s8v*)&wb[bbase1 + k1];
        }
        const s8v fx = *(const s8v*)&sm[cb][(wv * 16 + l16) * 40 + quad * 8];
        const s8v fm = *(const s8v*)&sm[cb][2560 + (wv * 16 + l16) * 40 + quad * 8];
        const s8v fr = *(const s8v*)&sm[cb][5120 + (wv * 16 + l16) * 40 + quad * 8];
#pragma unroll
        for (int nt = 0; nt < 8; ++nt) {
            const s8v fb = *(const s8v*)&sm[cb][7680 + (nt * 16 + l16) * 40 + quad * 8];
            i4v bi = __builtin_bit_cast(i4v, fb);
#pragma unroll
            for (int i = 0; i < 4; i++) bi[i] &= 0x7fff7fff;
            const s8v fa = __builtin_bit_cast(s8v, bi);
            aN[nt] = __builtin_amdgcn_mfma_f32_16x16x32_bf16(fx, fb, aN[nt], 0, 0, 0);
            aM[nt] = __builtin_amdgcn_mfma_f32_16x16x32_bf16(fm, fb, aM[nt], 0, 0, 0);
            aR[nt] = __builtin_amdgcn_mfma_f32_16x16x32_bf16(fr, fa, aR[nt], 0, 0, 0);
        }
        if (pf) {                              // stage into buf[nb]
            *(s8v*)&sm[nb][rw * 40 + koff]               = rn;
            *(s8v*)&sm[nb][2560 + rw * 40 + koff]        = rm;
            *(s8v*)&sm[nb][5120 + rw * 40 + koff]        = rr;
            *(s8v*)&sm[nb][7680 + rw * 40 + koff]        = rb0;
            *(s8v*)&sm[nb][7680 + (rw + 64) * 40 + koff] = rb1;
        }
    }

    const int p = j0 / NC, hh0 = (j0 % NC) >> 6;   // tile spans heads hh0, hh0+1
    const float osc = (p == 0) ? QSCALE : 1.0f;    // pre-scale Q for exp2-domain flash
    const int cc16 = (t & 3) * 16;
    for (int var = 0; var < 3; ++var)
        for (int h2 = 0; h2 < 2; ++h2) {
            __syncthreads();
#pragma unroll
            for (int nt4 = 0; nt4 < 4; ++nt4) {
                const int nt = h2 * 4 + nt4;
#pragma unroll
                for (int r = 0; r < 4; ++r) {
                    const float v = (var == 0) ? aN[nt][r]
                                  : (var == 1) ? aM[nt][r] - aR[nt][r]
                                               : aM[nt][r] + aR[nt][r];
                    Eb[(wv * 16 + quad * 4 + r) * 72 + nt4 * 16 + l16] = bfbits(v * osc);
                }
            }
            __syncthreads();
            const int hh = hh0 + h2;
            short* dst = qkvb + (size_t)(var * 3 + p) * BHTD;
            if (p < 2) {       // Q,K row-major [B,H,T,D]
                const int token = n0 + rw, b = token >> 11, tt = token & 2047;
                const size_t o = ((size_t)(b * 12 + hh) * NT + tt) * 64 + cc16;
                *(s8v*)&dst[o]     = *(const s8v*)&Eb[rw * 72 + cc16];
                *(s8v*)&dst[o + 8] = *(const s8v*)&Eb[rw * 72 + cc16 + 8];
            } else {           // V transposed [B,H,D,T]
                const int d = rw;
                s8v e0, e1;
#pragma unroll
                for (int i = 0; i < 8; i++) e0[i] = Eb[(cc16 + i) * 72 + d];
#pragma unroll
                for (int i = 0; i < 8; i++) e1[i] = Eb[(cc16 + 8 + i) * 72 + d];
                const int token0 = n0 + cc16, b = token0 >> 11, tt = token0 & 2047;
                const size_t o = ((size_t)(b * 12 + hh) * 64 + d) * NT + tt;
                *(s8v*)&dst[o]     = e0;
                *(s8v*)&dst[o + 8] = e1;
            }
        }
}

// ---------------------------------------------------------------------------
// Kernel 2: MFMA flash, merged nominal + 4 bound branches in one launch.
// 1D grid 960, XCD-aware: xcd=b%8 == bh%8 (R8: FETCH 279->31MB).
// LOAD-BALANCED pairs (pr, 15-pr) -> uniform 68 kt-iters.
// SWAPPED QK^T (P in registers); cvt_pk P pack; Ks pad 70 (odd bank stride).
// y written as BF16. Ping-pong LDS dbuf, ONE barrier/k-tile; T14 prefetch;
// T13 defer-max; setprio around MFMA.  (UNCHANGED from R10.)
// ---------------------------------------------------------------------------
__global__ __launch_bounds__(256) void flash_mfma(
    const short* __restrict__ qkvb, short* __restrict__ ybf,
    short* __restrict__ cand)
{
    const int b_  = blockIdx.x;            // 0..959
    const int xcd = b_ & 7;
    const int r_  = b_ >> 3;               // 0..119
    const int pr  = r_ & 7;                // 0..7
    const int r2  = r_ >> 3;               // 0..14
    const int z   = r2 % 5;
    const int bh  = xcd + 8 * (r2 / 5);    // 0..23
    const int t   = threadIdx.x;
    const int wv = t >> 6, lane = t & 63, quad = lane >> 4, l16 = lane & 15;
    const bool TWO = (z != 0);

    __shared__ short Ks[2][32 * 70];       // [buf][kpos][d] pad 70 (9.0 KB)
    __shared__ short Vs[2][2][64 * 40];    // [buf][sv][d][kpos] (20.5 KB)

    int sv, qvi, kvi, v0i, v1i;
    if (TWO) { sv = z; qvi = (sv + 1) >> 1; kvi = 2 - (sv & 1); v0i = 1; v1i = 2; }
    else     { sv = 0; qvi = 0; kvi = 0; v0i = 0; v1i = 0; }

    const size_t hb = (size_t)bh * (NT * 64);
    const short* Qp  = qkvb + (size_t)(qvi * 3 + 0) * BHTD + hb;  // [t][d] (pre-scaled)
    const short* Kp  = qkvb + (size_t)(kvi * 3 + 1) * BHTD + hb;  // [t][d]
    const short* V0p = qkvb + (size_t)(v0i * 3 + 2) * BHTD + hb;  // [d][t] !
    const short* V1p = qkvb + (size_t)(v1i * 3 + 2) * BHTD + hb;

    const int skr = t >> 3, skc = (t & 7) * 8;   // K stage: 32 x 64
    const int svd = t >> 2, svc = (t & 3) * 8;   // V stage: 64 x 32
    const int sig = (l16 >> 2) * 8 + (l16 & 3);  // K A-frag row permutation

    for (int half = 0; half < 2; ++half) {
        const int qt = half ? (15 - pr) : pr;
        const int q0 = qt * 128;

        // Q fragments (serve as the MFMA B operand in the swapped product)
        s8v qf[2][2];
#pragma unroll
        for (int mt = 0; mt < 2; ++mt)
#pragma unroll
            for (int ch = 0; ch < 2; ++ch)
                qf[mt][ch] = *(const s8v*)&Qp[(size_t)(q0 + 32 * wv + 16 * mt + l16) * 64 + ch * 32 + quad * 8];

        float mi[2], li[2];                // per-lane: row q = rowb + l16; li = quad-partial
        mi[0] = mi[1] = NEG; li[0] = li[1] = 0.f;
        f4 acc0[2][4], acc1[2][4];
#pragma unroll
        for (int mt = 0; mt < 2; ++mt)
#pragma unroll
            for (int i = 0; i < 4; ++i) { acc0[mt][i] = f4{0,0,0,0}; acc1[mt][i] = f4{0,0,0,0}; }

        const int ktn  = 4 * qt + 4;
        const int mykt = 4 * qt + wv + 1;  // last tile this wave's rows need

        // prologue: barrier (protect prior half's live buffers), tile 0 -> buf 0
        __syncthreads();
        s8v rK, rV0, rV1;
        rK  = *(const s8v*)&Kp[(size_t)skr * 64 + skc];
        rV0 = *(const s8v*)&V0p[(size_t)svd * NT + svc];
        if (TWO) rV1 = *(const s8v*)&V1p[(size_t)svd * NT + svc];
        *(s8v*)&Ks[0][skr * 70 + skc]    = rK;
        *(s8v*)&Vs[0][0][svd * 40 + svc] = rV0;
        if (TWO) *(s8v*)&Vs[0][1][svd * 40 + svc] = rV1;

        for (int kt = 0; kt < ktn; ++kt) {
            const int k0 = kt * 32;
            const int cb = kt & 1, nb = cb ^ 1;
            __syncthreads();               // buf[cb] complete for all waves
            const bool pf = (kt + 1 < ktn);
            if (pf) {                      // issue next-tile loads early
                const int k1 = k0 + 32;
                rK  = *(const s8v*)&Kp[(size_t)(k1 + skr) * 64 + skc];
                rV0 = *(const s8v*)&V0p[(size_t)svd * NT + k1 + svc];
                if (TWO) rV1 = *(const s8v*)&V1p[(size_t)svd * NT + k1 + svc];
            }
            if (kt < mykt) {
                // ---- S^T = K Q^T (log2 domain): s[mt][nt][r] =
                //      P[kpos = k0 + quad*8 + nt*4 + r][q = rowb + l16] ----
                f4 s[2][2];
#pragma unroll
                for (int mt = 0; mt < 2; ++mt) { s[mt][0] = f4{0,0,0,0}; s[mt][1] = f4{0,0,0,0}; }
                __builtin_amdgcn_s_setprio(1);
#pragma unroll
                for (int nt = 0; nt < 2; ++nt)
#pragma unroll
                    for (int ch = 0; ch < 2; ++ch) {
                        const s8v kf = *(const s8v*)&Ks[cb][(sig + nt * 4) * 70 + ch * 32 + quad * 8];
                        s[0][nt] = __builtin_amdgcn_mfma_f32_16x16x32_bf16(kf, qf[0][ch], s[0][nt], 0, 0, 0);
                        s[1][nt] = __builtin_amdgcn_mfma_f32_16x16x32_bf16(kf, qf[1][ch], s[1][nt], 0, 0, 0);
                    }
                __builtin_amdgcn_s_setprio(0);

                // ---- softmax + in-register P pack, per m-tile ----
                s8v pa[2];
#pragma unroll
                for (int mt = 0; mt < 2; ++mt) {
                    const int rowb = q0 + 32 * wv + 16 * mt;
                    const int qrow = rowb + l16;
                    float a[8];
#pragma unroll
                    for (int nt = 0; nt < 2; ++nt)
#pragma unroll
                        for (int r = 0; r < 4; ++r) a[nt * 4 + r] = s[mt][nt][r];
                    if (k0 + 31 > rowb) {
#pragma unroll
                        for (int nt = 0; nt < 2; ++nt)
#pragma unroll
                            for (int r = 0; r < 4; ++r)
                                if (k0 + quad * 8 + nt * 4 + r > qrow) a[nt * 4 + r] = NEG;
                    }
                    const float c = fmaxf(fmaxf(fmaxf(a[0], a[1]), fmaxf(a[2], a[3])),
                                          fmaxf(fmaxf(a[4], a[5]), fmaxf(a[6], a[7])));
                    if (__any(c - mi[mt] > 8.0f)) {     // rare: row max grew
                        const float mx = rowred_max(c); // full-row max, quad-consistent
                        const float nm = fmaxf(mi[mt], mx);
                        const float al = exp2fast(mi[mt] - nm);
                        mi[mt] = nm;
                        li[mt] *= al;
#pragma unroll
                        for (int r = 0; r < 4; ++r) {
                            // al lives at lane l16 = acc row; uniform across quads
                            const float alr = __shfl(al, (lane & 48) | (quad * 4 + r), 64);
#pragma unroll
                            for (int dt = 0; dt < 4; ++dt) acc0[mt][dt][r] *= alr;
                            if (TWO) {
#pragma unroll
                                for (int dt = 0; dt < 4; ++dt) acc1[mt][dt][r] *= alr;
                            }
                        }
                    }
                    float p[8];
#pragma unroll
                    for (int j = 0; j < 8; ++j) p[j] = exp2fast(a[j] - mi[mt]);  // <= 2^8
                    li[mt] += ((p[0] + p[1]) + (p[2] + p[3])) + ((p[4] + p[5]) + (p[6] + p[7]));
                    i4v pi;
#pragma unroll
                    for (int jj = 0; jj < 4; ++jj)
                        pi[jj] = cvtpk_bf16(p[2 * jj], p[2 * jj + 1]);
                    pa[mt] = __builtin_bit_cast(s8v, pi);
                }
                // ---- O += P V (pa is the A fragment directly) ----
                __builtin_amdgcn_s_setprio(1);
#pragma unroll
                for (int dt = 0; dt < 4; ++dt) {
                    const s8v vf0 = *(const s8v*)&Vs[cb][0][(dt * 16 + l16) * 40 + quad * 8];
                    acc0[0][dt] = __builtin_amdgcn_mfma_f32_16x16x32_bf16(pa[0], vf0, acc0[0][dt], 0, 0, 0);
                    acc0[1][dt] = __builtin_amdgcn_mfma_f32_16x16x32_bf16(pa[1], vf0, acc0[1][dt], 0, 0, 0);
                    if (TWO) {
                        const s8v vf1 = *(const s8v*)&Vs[cb][1][(dt * 16 + l16) * 40 + quad * 8];
                        acc1[0][dt] = __builtin_amdgcn_mfma_f32_16x16x32_bf16(pa[0], vf1, acc1[0][dt], 0, 0, 0);
                        acc1[1][dt] = __builtin_amdgcn_mfma_f32_16x16x32_bf16(pa[1], vf1, acc1[1][dt], 0, 0, 0);
                    }
                }
                __builtin_amdgcn_s_setprio(0);
            }
            if (pf) {                      // stage next tile into buf[nb]
                *(s8v*)&Ks[nb][skr * 70 + skc]    = rK;
                *(s8v*)&Vs[nb][0][svd * 40 + svc] = rV0;
                if (TWO) *(s8v*)&Vs[nb][1][svd * 40 + svc] = rV1;
            }
        }

#pragma unroll
        for (int mt = 0; mt < 2; ++mt) {
            // total row sum (uniform across quads after reduce), then redistribute
            const float invq = 1.f / rowred_sum(li[mt]);
            float inv[4];
#pragma unroll
            for (int r = 0; r < 4; ++r)
                inv[r] = __shfl(invq, (lane & 48) | (quad * 4 + r), 64);
#pragma unroll
            for (int dt = 0; dt < 4; ++dt)
#pragma unroll
                for (int r = 0; r < 4; ++r) {
                    const size_t o = hb + (size_t)(q0 + 32 * wv + 16 * mt + quad * 4 + r) * 64 + dt * 16 + l16;
                    if (!TWO) {
                        ybf[o] = bfbits(acc0[mt][dt][r] * inv[r]);
                    } else {
                        const float xa = acc0[mt][dt][r] * inv[r];
                        const float xb = acc1[mt][dt][r] * inv[r];
                        cand[(size_t)(sv - 1) * BHTD + o] = bfbits(fminf(xa, xb));
                        cand[(size_t)(3 + sv) * BHTD + o] = bfbits(fmaxf(xa, xb));
                    }
                }
        }
    }
}

// ---------------------------------------------------------------------------
// Kernel 2.5: fold the 4-way candidate min/max ONCE (was re-done 12x per jx
// inside out_proj). In-place: lo4 -> cand stream 0, hi4 -> cand stream 4.
// min/max of exact-bf16 values is exact, so >>16 truncation is lossless.
// ---------------------------------------------------------------------------
__global__ __launch_bounds__(256) void prep_out(short* __restrict__ cand)
{
    const size_t i = ((size_t)blockIdx.x * 256 + threadIdx.x) * 8;
    {
        const s8v c0 = *(const s8v*)&cand[i];
        const s8v c1 = *(const s8v*)&cand[(size_t)1 * BHTD + i];
        const s8v c2 = *(const s8v*)&cand[(size_t)2 * BHTD + i];
        const s8v c3 = *(const s8v*)&cand[(size_t)3 * BHTD + i];
        s8v lo;
#pragma unroll
        for (int j = 0; j < 8; j++) {
            const float v = fminf(fminf(bf2f(c0[j]), bf2f(c1[j])),
                                  fminf(bf2f(c2[j]), bf2f(c3[j])));
            lo[j] = (short)(__builtin_bit_cast(unsigned int, v) >> 16);
        }
        *(s8v*)&cand[i] = lo;
    }
    {
        const s8v c0 = *(const s8v*)&cand[(size_t)4 * BHTD + i];
        const s8v c1 = *(const s8v*)&cand[(size_t)5 * BHTD + i];
        const s8v c2 = *(const s8v*)&cand[(size_t)6 * BHTD + i];
        const s8v c3 = *(const s8v*)&cand[(size_t)7 * BHTD + i];
        s8v hi;
#pragma unroll
        for (int j = 0; j < 8; j++) {
            const float v = fmaxf(fmaxf(bf2f(c0[j]), bf2f(c1[j])),
                                  fmaxf(bf2f(c2[j]), bf2f(c3[j])));
            hi[j] = (short)(__builtin_bit_cast(unsigned int, v) >> 16);
        }
        *(s8v*)&cand[(size_t)4 * BHTD + i] = hi;
    }
}

// ---------------------------------------------------------------------------
// Kernel 3: MFMA output projection, M64 x N128 tile (8 MFMA per K-step), pure
// bf16 GEMM (A pre-reduced by prep_out, W pre-converted by prep_cvt).
// o=0: A=ybf; o=1: A=cand stream 0 (lo); o=2: A=cand stream 4 (hi).
// XCD-COLOCATED 1D grid (1152): xcd=b%8; s=b/8; o=s%3, jx=(s/3)%6 fastest,
// ny=xcd+8*(s/18). 2-pass epilogue (64 cols each). Ping-pong dbuf, 1 barrier.
// ---------------------------------------------------------------------------
__global__ __launch_bounds__(256) void out_proj_mfma(
    const short* __restrict__ ybf, const short* __restrict__ cand,
    const short* __restrict__ wpb, float* __restrict__ out)
{
    // per-buffer (shorts): As=0 ([64][40]=2560), Bs=2560 ([128][40]=5120)
    __shared__ short sm3[2][7680];          // 30.7 KB
    float* Eb = (float*)sm3;                // epilogue alias [64][68] floats (17.4 KB)

    const int b_  = blockIdx.x;             // 0..1151
    const int xcd = b_ & 7;
    const int s_  = b_ >> 3;                // 0..143
    const int o   = s_ % 3;
    const int jx  = (s_ / 3) % 6;
    const int ny  = xcd + 8 * (s_ / 18);    // 0..63
    const int j0 = jx * 128, n0 = ny * 64;
    const int t  = threadIdx.x;
    const int wv = t >> 6, lane = t & 63, quad = lane >> 4, l16 = lane & 15;
    const int rw = t >> 2, koff = (t & 3) * 8;

    f4 acc[8];
#pragma unroll
    for (int i = 0; i < 8; i++) acc[i] = f4{0,0,0,0};

    const int token = n0 + rw, b = token >> 11, tt = token & 2047;
    const size_t wbase0 = (size_t)(j0 + rw) * NC + koff;
    const size_t wbase1 = (size_t)(j0 + 64 + rw) * NC + koff;
    const short* Ap = (o == 0) ? ybf : (o == 1) ? cand : cand + (size_t)4 * BHTD;

    s8v ra, rb0, rb1;
    auto loadTile = [&](int k1) {
        const int hh = k1 >> 6, d0 = (k1 & 63) + koff;
        const size_t aoff = ((size_t)(b * 12 + hh) * NT + tt) * 64 + d0;
        ra  = *(const s8v*)&Ap[aoff];
        rb0 = *(const s8v*)&wpb[wbase0 + k1];
        rb1 = *(const s8v*)&wpb[wbase1 + k1];
    };

    // prologue: tile 0 -> regs -> buf 0
    loadTile(0);
    *(s8v*)&sm3[0][rw * 40 + koff]               = ra;
    *(s8v*)&sm3[0][2560 + rw * 40 + koff]        = rb0;
    *(s8v*)&sm3[0][2560 + (rw + 64) * 40 + koff] = rb1;

    for (int it = 0; it < NC / 32; ++it) {
        const int cbuf = it & 1, nbuf = cbuf ^ 1;
        __syncthreads();
        const bool pf = (it + 1 < NC / 32);
        if (pf) loadTile((it + 1) * 32);
        const s8v af = *(const s8v*)&sm3[cbuf][(wv * 16 + l16) * 40 + quad * 8];
#pragma unroll
        for (int nt = 0; nt < 8; ++nt) {
            const s8v bf = *(const s8v*)&sm3[cbuf][2560 + (nt * 16 + l16) * 40 + quad * 8];
            acc[nt] = __builtin_amdgcn_mfma_f32_16x16x32_bf16(af, bf, acc[nt], 0, 0, 0);
        }
        if (pf) {
            *(s8v*)&sm3[nbuf][rw * 40 + koff]               = ra;
            *(s8v*)&sm3[nbuf][2560 + rw * 40 + koff]        = rb0;
            *(s8v*)&sm3[nbuf][2560 + (rw + 64) * 40 + koff] = rb1;
        }
    }
    const int cc = (t & 3) * 16;
    for (int h2 = 0; h2 < 2; ++h2) {
        __syncthreads();
#pragma unroll
        for (int nt4 = 0; nt4 < 4; ++nt4)
#pragma unroll
            for (int r = 0; r < 4; ++r)
                Eb[(wv * 16 + quad * 4 + r) * 68 + nt4 * 16 + l16] = acc[h2 * 4 + nt4][r];
        __syncthreads();
#pragma unroll
        for (int i = 0; i < 4; ++i) {
            const f4 vo = *(const f4*)&Eb[rw * 68 + cc + 4 * i];
            *(f4*)&out[(size_t)o * BTC + (size_t)(n0 + rw) * NC + j0 + h2 * 64 + cc + 4 * i] = vo;
        }
    }
}

extern "C" void kernel_launch(void* const* d_in, const int* in_sizes, int n_in,
                              void* d_out, int out_size, void* d_ws, size_t ws_size,
                              hipStream_t stream)
{
    const float* x  = (const float*)d_in[0];
    const float* xl = (const float*)d_in[1];
    const float* xu = (const float*)d_in[2];
    const float* Wa = (const float*)d_in[3];
    const float* Wp = (const float*)d_in[4];
    float* out = (float*)d_out;

    short* qkvb = (short*)d_ws;                       // 9*BHTD bf16 = 56.6 MB
    short* ybf  = qkvb + (size_t)9 * BHTD;            // 1*BHTD bf16 =  6.3 MB
    short* cand = ybf + (size_t)BHTD;                 // 8*BHTD bf16 = 50.3 MB
    short* wpb  = cand + (size_t)8 * BHTD;            // NWP bf16   =  1.2 MB

    // prep aliases (inside cand; consumed by qkv before flash clobbers them)
    short* xn = cand;                      // BTC shorts
    short* xm = cand + (size_t)1 * BHTD;   // BTC shorts
    short* xr = cand + (size_t)2 * BHTD;   // BTC shorts
    short* wb = cand + (size_t)3 * BHTD;   // NWA shorts (fits in BHTD)

    prep_cvt     <<<dim3(1536), 256, 0, stream>>>(x, xl, xu, Wa, Wp, xn, xm, xr, wb, wpb);
    qkv_proj_mfma<<<dim3(1152), 256, 0, stream>>>(xn, xm, xr, wb, qkvb);
    flash_mfma   <<<dim3(960),  256, 0, stream>>>(qkvb, ybf, cand);
    prep_out     <<<dim3(1536), 256, 0, stream>>>(cand);
    out_proj_mfma<<<dim3(1152), 256, 0, stream>>>(ybf, cand, wpb, out);
}

// Round 12
// 373.684 us; speedup vs baseline: 2.3052x; 1.0105x over previous
//
#include <hip/hip_runtime.h>
#include <hip/hip_bf16.h>
#include <cstdint>

typedef float f4  __attribute__((ext_vector_type(4)));
typedef short s8v __attribute__((ext_vector_type(8)));   // 8 bf16 (4 VGPRs)
typedef int   i4v __attribute__((ext_vector_type(4)));

#define BHTD 3145728    // B*H*T*D = 2*12*2048*64
#define BTC  3145728
#define NT   2048
#define NC   768
#define NWA  1769472    // 3C*C = 2304*768
#define NWP  589824     // C*C = 768*768
#define NEG  -1e30f
// 0.125 (1/sqrt(64)) * log2(e): folded into Q at the producer so the flash
// kernel's scores are already in log2 domain (exp2 instead of expf, no scale mul)
#define QSCALE 0.18033688f

static __device__ __forceinline__ short bfbits(float f) {
    return __builtin_bit_cast(short, __float2bfloat16(f));
}
static __device__ __forceinline__ float bf2f(short s) {
    return __builtin_bit_cast(float, (int)(((unsigned int)(unsigned short)s) << 16));
}
static __device__ __forceinline__ float exp2fast(float x) {
    return __builtin_amdgcn_exp2f(x);
}
// hardware packed f32->bf16 (RNE), lo -> [15:0], hi -> [31:16]
static __device__ __forceinline__ int cvtpk_bf16(float lo, float hi) {
    int r;
    asm("v_cvt_pk_bf16_f32 %0, %1, %2" : "=v"(r) : "v"(lo), "v"(hi));
    return r;
}
// async global->LDS, 16B per lane; dest = base + lane*16 (wave-uniform base)
static __device__ __forceinline__ void gl_lds16(const short* g, short* l) {
    __builtin_amdgcn_global_load_lds(
        (const __attribute__((address_space(1))) void*)g,
        (__attribute__((address_space(3))) void*)l, 16, 0, 0);
}
// row reductions across the 4 quads (lanes l16, l16+16, l16+32, l16+48)
static __device__ __forceinline__ float rowred_max(float x) {
    x = fmaxf(x, __shfl_xor(x, 16, 64));
    x = fmaxf(x, __shfl_xor(x, 32, 64));
    return x;
}
static __device__ __forceinline__ float rowred_sum(float x) {
    x += __shfl_xor(x, 16, 64);
    x += __shfl_xor(x, 32, 64);
    return x;
}

// ---------------------------------------------------------------------------
// Kernel 0: one-shot fp32->bf16 conversion. xn=x, xm=(xl+xu)/2, xr=(xu-xl)/2,
// wb=W_attn, wpb=W_proj. Removes per-block re-conversion from the GEMMs.
// ---------------------------------------------------------------------------
__global__ __launch_bounds__(256) void prep_cvt(
    const float* __restrict__ x, const float* __restrict__ xl,
    const float* __restrict__ xu, const float* __restrict__ W,
    const float* __restrict__ Wp,
    short* __restrict__ xn, short* __restrict__ xm, short* __restrict__ xr,
    short* __restrict__ wb, short* __restrict__ wpb)
{
    const size_t flat = (size_t)blockIdx.x * 256 + threadIdx.x;
    const size_t i = flat * 8;        // 1536*256*8 == BTC exactly
    {
        const f4 a0 = *(const f4*)&x[i],  a1 = *(const f4*)&x[i + 4];
        const f4 l0 = *(const f4*)&xl[i], l1 = *(const f4*)&xl[i + 4];
        const f4 u0 = *(const f4*)&xu[i], u1 = *(const f4*)&xu[i + 4];
        s8v vn, vm, vr;
#pragma unroll
        for (int j = 0; j < 4; j++) {
            vn[j]     = bfbits(a0[j]);                   vn[4 + j] = bfbits(a1[j]);
            vm[j]     = bfbits(0.5f * (l0[j] + u0[j]));  vm[4 + j] = bfbits(0.5f * (l1[j] + u1[j]));
            vr[j]     = bfbits(0.5f * (u0[j] - l0[j]));  vr[4 + j] = bfbits(0.5f * (u1[j] - l1[j]));
        }
        *(s8v*)&xn[i] = vn;
        *(s8v*)&xm[i] = vm;
        *(s8v*)&xr[i] = vr;
    }
    if (flat < NWA / 8) {
        const size_t wi = flat * 8;
        const f4 w0 = *(const f4*)&W[wi], w1 = *(const f4*)&W[wi + 4];
        s8v vw;
#pragma unroll
        for (int j = 0; j < 4; j++) { vw[j] = bfbits(w0[j]); vw[4 + j] = bfbits(w1[j]); }
        *(s8v*)&wb[wi] = vw;
    }
    if (flat < NWP / 8) {
        const size_t wi = flat * 8;
        const f4 w0 = *(const f4*)&Wp[wi], w1 = *(const f4*)&Wp[wi + 4];
        s8v vw;
#pragma unroll
        for (int j = 0; j < 4; j++) { vw[j] = bfbits(w0[j]); vw[4 + j] = bfbits(w1[j]); }
        *(s8v*)&wpb[wi] = vw;
    }
}

// ---------------------------------------------------------------------------
// Kernel 1: MFMA QKV projection, M64 x N128 tile, global_load_lds staging.
// Staging is DMA'd direct to LDS (no VGPR round-trip, no ds_writes): linear
// unpadded [row][32] rows with XOR-chunk swizzle — lane stages global chunk
// (l&3)^((l>>2)&3) into slot l&3 (pre-swizzled SOURCE, m173); reads use
// slot = quad^(row&3). 20 segs/K-step, 5 gl_lds per wave. LDS 40 KB.
// XCD-COLOCATED 1D grid (1152): xcd=b%8; s=b/8; jx=s%18 fastest;
// ny = xcd + 8*(s/18). Outputs bf16: Q,K [var][part][B,H,T,D]; V [B,H,D,T].
// Q (p==0) pre-scaled by 0.125*log2e. Ping-pong dbuf, ONE barrier/K-step
// (the barrier's vmcnt(0) drain is the DMA arrival fence).
// ---------------------------------------------------------------------------
__global__ __launch_bounds__(256, 3) void qkv_proj_mfma(
    const short* __restrict__ xn, const short* __restrict__ xm,
    const short* __restrict__ xr, const short* __restrict__ wb,
    short* __restrict__ qkvb)
{
    // per-buffer (shorts): Ax@0, Am@2048, Ar@4096 (each [64][32]);
    // Bw@6144 ([128][32] = 4096). Buffer = 10240 shorts = 20.5 KB.
    __shared__ short sm[2][10240];      // 40 KB
    short* Eb = &sm[0][0];              // epilogue alias [64][72] (4608 shorts)

    const int b_  = blockIdx.x;         // 0..1151
    const int xcd = b_ & 7;
    const int s_  = b_ >> 3;            // 0..143
    const int jx  = s_ % 18;
    const int ny  = xcd + 8 * (s_ / 18);   // 0..63
    const int j0 = jx * 128;            // N in [0,2304)
    const int n0 = ny * 64;             // M in [0,4096)
    const int t  = threadIdx.x;
    const int wv = t >> 6, lane = t & 63, quad = lane >> 4, l16 = lane & 15;

    // staging lane geometry: seg = 16 rows; lane l -> row l>>2, slot l&3,
    // source chunk (l&3)^((l>>2)&3)
    const int srow = lane >> 2;
    const int cswz = (lane & 3) ^ (srow & 3);

    // per-lane global element offsets (k1 added per iter)
    const size_t aoff  = (size_t)(n0 + wv * 16 + srow) * NC + cswz * 8;
    const size_t boff0 = (size_t)(j0 + wv * 16 + srow) * NC + cswz * 8;
    const size_t boff1 = (size_t)(j0 + 64 + wv * 16 + srow) * NC + cswz * 8;
    const int lws = wv * 512;           // wave's 16-row LDS window (shorts)

    f4 aN[8], aM[8], aR[8];
#pragma unroll
    for (int i = 0; i < 8; i++) { aN[i] = f4{0,0,0,0}; aM[i] = f4{0,0,0,0}; aR[i] = f4{0,0,0,0}; }

    // prologue: DMA tile 0 into buf 0
    {
        gl_lds16(&xn[aoff],  &sm[0][0    + lws]);
        gl_lds16(&xm[aoff],  &sm[0][2048 + lws]);
        gl_lds16(&xr[aoff],  &sm[0][4096 + lws]);
        gl_lds16(&wb[boff0], &sm[0][6144 + lws]);
        gl_lds16(&wb[boff1], &sm[0][8192 + lws]);
    }

    const int rsw = (quad ^ (l16 & 3)) * 8;   // swizzled read slot (shorts)

    for (int it = 0; it < NC / 32; ++it) {
        const int cb = it & 1, nb = cb ^ 1;
        __syncthreads();                       // buf[cb] DMA complete (vmcnt drain)
        if (it + 1 < NC / 32) {                // DMA next tile (flies under MFMAs)
            const size_t k1 = (size_t)(it + 1) * 32;
            gl_lds16(&xn[aoff + k1],  &sm[nb][0    + lws]);
            gl_lds16(&xm[aoff + k1],  &sm[nb][2048 + lws]);
            gl_lds16(&xr[aoff + k1],  &sm[nb][4096 + lws]);
            gl_lds16(&wb[boff0 + k1], &sm[nb][6144 + lws]);
            gl_lds16(&wb[boff1 + k1], &sm[nb][8192 + lws]);
        }
        const s8v fx = *(const s8v*)&sm[cb][       (wv * 16 + l16) * 32 + rsw];
        const s8v fm = *(const s8v*)&sm[cb][2048 + (wv * 16 + l16) * 32 + rsw];
        const s8v fr = *(const s8v*)&sm[cb][4096 + (wv * 16 + l16) * 32 + rsw];
#pragma unroll
        for (int nt = 0; nt < 8; ++nt) {
            const s8v fb = *(const s8v*)&sm[cb][6144 + (nt * 16 + l16) * 32 + rsw];
            i4v bi = __builtin_bit_cast(i4v, fb);
#pragma unroll
            for (int i = 0; i < 4; i++) bi[i] &= 0x7fff7fff;
            const s8v fa = __builtin_bit_cast(s8v, bi);
            aN[nt] = __builtin_amdgcn_mfma_f32_16x16x32_bf16(fx, fb, aN[nt], 0, 0, 0);
            aM[nt] = __builtin_amdgcn_mfma_f32_16x16x32_bf16(fm, fb, aM[nt], 0, 0, 0);
            aR[nt] = __builtin_amdgcn_mfma_f32_16x16x32_bf16(fr, fa, aR[nt], 0, 0, 0);
        }
    }

    const int p = j0 / NC, hh0 = (j0 % NC) >> 6;   // tile spans heads hh0, hh0+1
    const float osc = (p == 0) ? QSCALE : 1.0f;    // pre-scale Q for exp2-domain flash
    const int rw = t >> 2, cc16 = (t & 3) * 16;
    for (int var = 0; var < 3; ++var)
        for (int h2 = 0; h2 < 2; ++h2) {
            __syncthreads();
#pragma unroll
            for (int nt4 = 0; nt4 < 4; ++nt4) {
                const int nt = h2 * 4 + nt4;
#pragma unroll
                for (int r = 0; r < 4; ++r) {
                    const float v = (var == 0) ? aN[nt][r]
                                  : (var == 1) ? aM[nt][r] - aR[nt][r]
                                               : aM[nt][r] + aR[nt][r];
                    Eb[(wv * 16 + quad * 4 + r) * 72 + nt4 * 16 + l16] = bfbits(v * osc);
                }
            }
            __syncthreads();
            const int hh = hh0 + h2;
            short* dst = qkvb + (size_t)(var * 3 + p) * BHTD;
            if (p < 2) {       // Q,K row-major [B,H,T,D]
                const int token = n0 + rw, b = token >> 11, tt = token & 2047;
                const size_t o = ((size_t)(b * 12 + hh) * NT + tt) * 64 + cc16;
                *(s8v*)&dst[o]     = *(const s8v*)&Eb[rw * 72 + cc16];
                *(s8v*)&dst[o + 8] = *(const s8v*)&Eb[rw * 72 + cc16 + 8];
            } else {           // V transposed [B,H,D,T]
                const int d = rw;
                s8v e0, e1;
#pragma unroll
                for (int i = 0; i < 8; i++) e0[i] = Eb[(cc16 + i) * 72 + d];
#pragma unroll
                for (int i = 0; i < 8; i++) e1[i] = Eb[(cc16 + 8 + i) * 72 + d];
                const int token0 = n0 + cc16, b = token0 >> 11, tt = token0 & 2047;
                const size_t o = ((size_t)(b * 12 + hh) * 64 + d) * NT + tt;
                *(s8v*)&dst[o]     = e0;
                *(s8v*)&dst[o + 8] = e1;
            }
        }
}

// ---------------------------------------------------------------------------
// Kernel 2: MFMA flash, merged nominal + 4 bound branches in one launch.
// 1D grid 960, XCD-aware: xcd=b%8 == bh%8 (R8: FETCH 279->31MB).
// LOAD-BALANCED pairs (pr, 15-pr) -> uniform 68 kt-iters.
// SWAPPED QK^T (P in registers); cvt_pk P pack; Ks pad 70 (odd bank stride).
// y written as BF16. Ping-pong LDS dbuf, ONE barrier/k-tile; T14 prefetch;
// T13 defer-max; setprio around MFMA.  (UNCHANGED from R11.)
// ---------------------------------------------------------------------------
__global__ __launch_bounds__(256) void flash_mfma(
    const short* __restrict__ qkvb, short* __restrict__ ybf,
    short* __restrict__ cand)
{
    const int b_  = blockIdx.x;            // 0..959
    const int xcd = b_ & 7;
    const int r_  = b_ >> 3;               // 0..119
    const int pr  = r_ & 7;                // 0..7
    const int r2  = r_ >> 3;               // 0..14
    const int z   = r2 % 5;
    const int bh  = xcd + 8 * (r2 / 5);    // 0..23
    const int t   = threadIdx.x;
    const int wv = t >> 6, lane = t & 63, quad = lane >> 4, l16 = lane & 15;
    const bool TWO = (z != 0);

    __shared__ short Ks[2][32 * 70];       // [buf][kpos][d] pad 70 (9.0 KB)
    __shared__ short Vs[2][2][64 * 40];    // [buf][sv][d][kpos] (20.5 KB)

    int sv, qvi, kvi, v0i, v1i;
    if (TWO) { sv = z; qvi = (sv + 1) >> 1; kvi = 2 - (sv & 1); v0i = 1; v1i = 2; }
    else     { sv = 0; qvi = 0; kvi = 0; v0i = 0; v1i = 0; }

    const size_t hb = (size_t)bh * (NT * 64);
    const short* Qp  = qkvb + (size_t)(qvi * 3 + 0) * BHTD + hb;  // [t][d] (pre-scaled)
    const short* Kp  = qkvb + (size_t)(kvi * 3 + 1) * BHTD + hb;  // [t][d]
    const short* V0p = qkvb + (size_t)(v0i * 3 + 2) * BHTD + hb;  // [d][t] !
    const short* V1p = qkvb + (size_t)(v1i * 3 + 2) * BHTD + hb;

    const int skr = t >> 3, skc = (t & 7) * 8;   // K stage: 32 x 64
    const int svd = t >> 2, svc = (t & 3) * 8;   // V stage: 64 x 32
    const int sig = (l16 >> 2) * 8 + (l16 & 3);  // K A-frag row permutation

    for (int half = 0; half < 2; ++half) {
        const int qt = half ? (15 - pr) : pr;
        const int q0 = qt * 128;

        // Q fragments (serve as the MFMA B operand in the swapped product)
        s8v qf[2][2];
#pragma unroll
        for (int mt = 0; mt < 2; ++mt)
#pragma unroll
            for (int ch = 0; ch < 2; ++ch)
                qf[mt][ch] = *(const s8v*)&Qp[(size_t)(q0 + 32 * wv + 16 * mt + l16) * 64 + ch * 32 + quad * 8];

        float mi[2], li[2];                // per-lane: row q = rowb + l16; li = quad-partial
        mi[0] = mi[1] = NEG; li[0] = li[1] = 0.f;
        f4 acc0[2][4], acc1[2][4];
#pragma unroll
        for (int mt = 0; mt < 2; ++mt)
#pragma unroll
            for (int i = 0; i < 4; ++i) { acc0[mt][i] = f4{0,0,0,0}; acc1[mt][i] = f4{0,0,0,0}; }

        const int ktn  = 4 * qt + 4;
        const int mykt = 4 * qt + wv + 1;  // last tile this wave's rows need

        // prologue: barrier (protect prior half's live buffers), tile 0 -> buf 0
        __syncthreads();
        s8v rK, rV0, rV1;
        rK  = *(const s8v*)&Kp[(size_t)skr * 64 + skc];
        rV0 = *(const s8v*)&V0p[(size_t)svd * NT + svc];
        if (TWO) rV1 = *(const s8v*)&V1p[(size_t)svd * NT + svc];
        *(s8v*)&Ks[0][skr * 70 + skc]    = rK;
        *(s8v*)&Vs[0][0][svd * 40 + svc] = rV0;
        if (TWO) *(s8v*)&Vs[0][1][svd * 40 + svc] = rV1;

        for (int kt = 0; kt < ktn; ++kt) {
            const int k0 = kt * 32;
            const int cb = kt & 1, nb = cb ^ 1;
            __syncthreads();               // buf[cb] complete for all waves
            const bool pf = (kt + 1 < ktn);
            if (pf) {                      // issue next-tile loads early
                const int k1 = k0 + 32;
                rK  = *(const s8v*)&Kp[(size_t)(k1 + skr) * 64 + skc];
                rV0 = *(const s8v*)&V0p[(size_t)svd * NT + k1 + svc];
                if (TWO) rV1 = *(const s8v*)&V1p[(size_t)svd * NT + k1 + svc];
            }
            if (kt < mykt) {
                // ---- S^T = K Q^T (log2 domain): s[mt][nt][r] =
                //      P[kpos = k0 + quad*8 + nt*4 + r][q = rowb + l16] ----
                f4 s[2][2];
#pragma unroll
                for (int mt = 0; mt < 2; ++mt) { s[mt][0] = f4{0,0,0,0}; s[mt][1] = f4{0,0,0,0}; }
                __builtin_amdgcn_s_setprio(1);
#pragma unroll
                for (int nt = 0; nt < 2; ++nt)
#pragma unroll
                    for (int ch = 0; ch < 2; ++ch) {
                        const s8v kf = *(const s8v*)&Ks[cb][(sig + nt * 4) * 70 + ch * 32 + quad * 8];
                        s[0][nt] = __builtin_amdgcn_mfma_f32_16x16x32_bf16(kf, qf[0][ch], s[0][nt], 0, 0, 0);
                        s[1][nt] = __builtin_amdgcn_mfma_f32_16x16x32_bf16(kf, qf[1][ch], s[1][nt], 0, 0, 0);
                    }
                __builtin_amdgcn_s_setprio(0);

                // ---- softmax + in-register P pack, per m-tile ----
                s8v pa[2];
#pragma unroll
                for (int mt = 0; mt < 2; ++mt) {
                    const int rowb = q0 + 32 * wv + 16 * mt;
                    const int qrow = rowb + l16;
                    float a[8];
#pragma unroll
                    for (int nt = 0; nt < 2; ++nt)
#pragma unroll
                        for (int r = 0; r < 4; ++r) a[nt * 4 + r] = s[mt][nt][r];
                    if (k0 + 31 > rowb) {
#pragma unroll
                        for (int nt = 0; nt < 2; ++nt)
#pragma unroll
                            for (int r = 0; r < 4; ++r)
                                if (k0 + quad * 8 + nt * 4 + r > qrow) a[nt * 4 + r] = NEG;
                    }
                    const float c = fmaxf(fmaxf(fmaxf(a[0], a[1]), fmaxf(a[2], a[3])),
                                          fmaxf(fmaxf(a[4], a[5]), fmaxf(a[6], a[7])));
                    if (__any(c - mi[mt] > 8.0f)) {     // rare: row max grew
                        const float mx = rowred_max(c); // full-row max, quad-consistent
                        const float nm = fmaxf(mi[mt], mx);
                        const float al = exp2fast(mi[mt] - nm);
                        mi[mt] = nm;
                        li[mt] *= al;
#pragma unroll
                        for (int r = 0; r < 4; ++r) {
                            // al lives at lane l16 = acc row; uniform across quads
                            const float alr = __shfl(al, (lane & 48) | (quad * 4 + r), 64);
#pragma unroll
                            for (int dt = 0; dt < 4; ++dt) acc0[mt][dt][r] *= alr;
                            if (TWO) {
#pragma unroll
                                for (int dt = 0; dt < 4; ++dt) acc1[mt][dt][r] *= alr;
                            }
                        }
                    }
                    float p[8];
#pragma unroll
                    for (int j = 0; j < 8; ++j) p[j] = exp2fast(a[j] - mi[mt]);  // <= 2^8
                    li[mt] += ((p[0] + p[1]) + (p[2] + p[3])) + ((p[4] + p[5]) + (p[6] + p[7]));
                    i4v pi;
#pragma unroll
                    for (int jj = 0; jj < 4; ++jj)
                        pi[jj] = cvtpk_bf16(p[2 * jj], p[2 * jj + 1]);
                    pa[mt] = __builtin_bit_cast(s8v, pi);
                }
                // ---- O += P V (pa is the A fragment directly) ----
                __builtin_amdgcn_s_setprio(1);
#pragma unroll
                for (int dt = 0; dt < 4; ++dt) {
                    const s8v vf0 = *(const s8v*)&Vs[cb][0][(dt * 16 + l16) * 40 + quad * 8];
                    acc0[0][dt] = __builtin_amdgcn_mfma_f32_16x16x32_bf16(pa[0], vf0, acc0[0][dt], 0, 0, 0);
                    acc0[1][dt] = __builtin_amdgcn_mfma_f32_16x16x32_bf16(pa[1], vf0, acc0[1][dt], 0, 0, 0);
                    if (TWO) {
                        const s8v vf1 = *(const s8v*)&Vs[cb][1][(dt * 16 + l16) * 40 + quad * 8];
                        acc1[0][dt] = __builtin_amdgcn_mfma_f32_16x16x32_bf16(pa[0], vf1, acc1[0][dt], 0, 0, 0);
                        acc1[1][dt] = __builtin_amdgcn_mfma_f32_16x16x32_bf16(pa[1], vf1, acc1[1][dt], 0, 0, 0);
                    }
                }
                __builtin_amdgcn_s_setprio(0);
            }
            if (pf) {                      // stage next tile into buf[nb]
                *(s8v*)&Ks[nb][skr * 70 + skc]    = rK;
                *(s8v*)&Vs[nb][0][svd * 40 + svc] = rV0;
                if (TWO) *(s8v*)&Vs[nb][1][svd * 40 + svc] = rV1;
            }
        }

#pragma unroll
        for (int mt = 0; mt < 2; ++mt) {
            // total row sum (uniform across quads after reduce), then redistribute
            const float invq = 1.f / rowred_sum(li[mt]);
            float inv[4];
#pragma unroll
            for (int r = 0; r < 4; ++r)
                inv[r] = __shfl(invq, (lane & 48) | (quad * 4 + r), 64);
#pragma unroll
            for (int dt = 0; dt < 4; ++dt)
#pragma unroll
                for (int r = 0; r < 4; ++r) {
                    const size_t o = hb + (size_t)(q0 + 32 * wv + 16 * mt + quad * 4 + r) * 64 + dt * 16 + l16;
                    if (!TWO) {
                        ybf[o] = bfbits(acc0[mt][dt][r] * inv[r]);
                    } else {
                        const float xa = acc0[mt][dt][r] * inv[r];
                        const float xb = acc1[mt][dt][r] * inv[r];
                        cand[(size_t)(sv - 1) * BHTD + o] = bfbits(fminf(xa, xb));
                        cand[(size_t)(3 + sv) * BHTD + o] = bfbits(fmaxf(xa, xb));
                    }
                }
        }
    }
}

// ---------------------------------------------------------------------------
// Kernel 2.5: fold the 4-way candidate min/max ONCE. In-place: lo4 -> cand
// stream 0, hi4 -> cand stream 4. min/max of exact-bf16 values is exact.
// ---------------------------------------------------------------------------
__global__ __launch_bounds__(256) void prep_out(short* __restrict__ cand)
{
    const size_t i = ((size_t)blockIdx.x * 256 + threadIdx.x) * 8;
    {
        const s8v c0 = *(const s8v*)&cand[i];
        const s8v c1 = *(const s8v*)&cand[(size_t)1 * BHTD + i];
        const s8v c2 = *(const s8v*)&cand[(size_t)2 * BHTD + i];
        const s8v c3 = *(const s8v*)&cand[(size_t)3 * BHTD + i];
        s8v lo;
#pragma unroll
        for (int j = 0; j < 8; j++) {
            const float v = fminf(fminf(bf2f(c0[j]), bf2f(c1[j])),
                                  fminf(bf2f(c2[j]), bf2f(c3[j])));
            lo[j] = (short)(__builtin_bit_cast(unsigned int, v) >> 16);
        }
        *(s8v*)&cand[i] = lo;
    }
    {
        const s8v c0 = *(const s8v*)&cand[(size_t)4 * BHTD + i];
        const s8v c1 = *(const s8v*)&cand[(size_t)5 * BHTD + i];
        const s8v c2 = *(const s8v*)&cand[(size_t)6 * BHTD + i];
        const s8v c3 = *(const s8v*)&cand[(size_t)7 * BHTD + i];
        s8v hi;
#pragma unroll
        for (int j = 0; j < 8; j++) {
            const float v = fmaxf(fmaxf(bf2f(c0[j]), bf2f(c1[j])),
                                  fmaxf(bf2f(c2[j]), bf2f(c3[j])));
            hi[j] = (short)(__builtin_bit_cast(unsigned int, v) >> 16);
        }
        *(s8v*)&cand[(size_t)4 * BHTD + i] = hi;
    }
}

// ---------------------------------------------------------------------------
// Kernel 3: MFMA output projection, M64 x N128 tile, global_load_lds staging
// (same linear+XOR-swizzle scheme as qkv; 12 segs/K-step, 3 gl_lds per wave).
// Pure bf16 GEMM. o=0: A=ybf; o=1: A=cand lo; o=2: A=cand hi.
// XCD-COLOCATED 1D grid (1152): xcd=b%8; s=b/8; o=s%3, jx=(s/3)%6 fastest,
// ny=xcd+8*(s/18). 2-pass epilogue. Ping-pong dbuf, 1 barrier/K-step.
// ---------------------------------------------------------------------------
__global__ __launch_bounds__(256) void out_proj_mfma(
    const short* __restrict__ ybf, const short* __restrict__ cand,
    const short* __restrict__ wpb, float* __restrict__ out)
{
    // per-buffer (shorts): As@0 ([64][32]=2048), Bs@2048 ([128][32]=4096)
    __shared__ short sm3[2][6144];          // 24.6 KB
    float* Eb = (float*)sm3;                // epilogue alias [64][68] floats (17.4 KB)

    const int b_  = blockIdx.x;             // 0..1151
    const int xcd = b_ & 7;
    const int s_  = b_ >> 3;                // 0..143
    const int o   = s_ % 3;
    const int jx  = (s_ / 3) % 6;
    const int ny  = xcd + 8 * (s_ / 18);    // 0..63
    const int j0 = jx * 128, n0 = ny * 64;
    const int t  = threadIdx.x;
    const int wv = t >> 6, lane = t & 63, quad = lane >> 4, l16 = lane & 15;

    const int srow = lane >> 2;
    const int cswz = (lane & 3) ^ (srow & 3);

    f4 acc[8];
#pragma unroll
    for (int i = 0; i < 8; i++) acc[i] = f4{0,0,0,0};

    // A per-lane base (head offset + in-head d added per iter)
    const int tokenS = n0 + wv * 16 + srow;
    const int bS = tokenS >> 11, ttS = tokenS & 2047;
    const size_t abase = ((size_t)(bS * 12) * NT + ttS) * 64 + cswz * 8;
    const size_t woff0 = (size_t)(j0 + wv * 16 + srow) * NC + cswz * 8;
    const size_t woff1 = (size_t)(j0 + 64 + wv * 16 + srow) * NC + cswz * 8;
    const int lws = wv * 512;
    const short* Ap = (o == 0) ? ybf : (o == 1) ? cand : cand + (size_t)4 * BHTD;

    // prologue: DMA tile 0 into buf 0
    {
        gl_lds16(&Ap[abase],   &sm3[0][0    + lws]);
        gl_lds16(&wpb[woff0],  &sm3[0][2048 + lws]);
        gl_lds16(&wpb[woff1],  &sm3[0][4096 + lws]);
    }

    const int rsw = (quad ^ (l16 & 3)) * 8;

    for (int it = 0; it < NC / 32; ++it) {
        const int cbuf = it & 1, nbuf = cbuf ^ 1;
        __syncthreads();                       // buf[cbuf] DMA complete
        if (it + 1 < NC / 32) {
            const int k1 = (it + 1) * 32;
            const int hh = k1 >> 6, d0 = k1 & 63;
            gl_lds16(&Ap[abase + (size_t)hh * (NT * 64) + d0], &sm3[nbuf][0    + lws]);
            gl_lds16(&wpb[woff0 + k1],                         &sm3[nbuf][2048 + lws]);
            gl_lds16(&wpb[woff1 + k1],                         &sm3[nbuf][4096 + lws]);
        }
        const s8v af = *(const s8v*)&sm3[cbuf][(wv * 16 + l16) * 32 + rsw];
#pragma unroll
        for (int nt = 0; nt < 8; ++nt) {
            const s8v bf = *(const s8v*)&sm3[cbuf][2048 + (nt * 16 + l16) * 32 + rsw];
            acc[nt] = __builtin_amdgcn_mfma_f32_16x16x32_bf16(af, bf, acc[nt], 0, 0, 0);
        }
    }
    const int rw = t >> 2, cc = (t & 3) * 16;
    const int token = n0 + rw;
    for (int h2 = 0; h2 < 2; ++h2) {
        __syncthreads();
#pragma unroll
        for (int nt4 = 0; nt4 < 4; ++nt4)
#pragma unroll
            for (int r = 0; r < 4; ++r)
                Eb[(wv * 16 + quad * 4 + r) * 68 + nt4 * 16 + l16] = acc[h2 * 4 + nt4][r];
        __syncthreads();
#pragma unroll
        for (int i = 0; i < 4; ++i) {
            const f4 vo = *(const f4*)&Eb[rw * 68 + cc + 4 * i];
            *(f4*)&out[(size_t)o * BTC + (size_t)token * NC + j0 + h2 * 64 + cc + 4 * i] = vo;
        }
    }
}

extern "C" void kernel_launch(void* const* d_in, const int* in_sizes, int n_in,
                              void* d_out, int out_size, void* d_ws, size_t ws_size,
                              hipStream_t stream)
{
    const float* x  = (const float*)d_in[0];
    const float* xl = (const float*)d_in[1];
    const float* xu = (const float*)d_in[2];
    const float* Wa = (const float*)d_in[3];
    const float* Wp = (const float*)d_in[4];
    float* out = (float*)d_out;

    short* qkvb = (short*)d_ws;                       // 9*BHTD bf16 = 56.6 MB
    short* ybf  = qkvb + (size_t)9 * BHTD;            // 1*BHTD bf16 =  6.3 MB
    short* cand = ybf + (size_t)BHTD;                 // 8*BHTD bf16 = 50.3 MB
    short* wpb  = cand + (size_t)8 * BHTD;            // NWP bf16   =  1.2 MB

    // prep aliases (inside cand; consumed by qkv before flash clobbers them)
    short* xn = cand;                      // BTC shorts
    short* xm = cand + (size_t)1 * BHTD;   // BTC shorts
    short* xr = cand + (size_t)2 * BHTD;   // BTC shorts
    short* wb = cand + (size_t)3 * BHTD;   // NWA shorts (fits in BHTD)

    prep_cvt     <<<dim3(1536), 256, 0, stream>>>(x, xl, xu, Wa, Wp, xn, xm, xr, wb, wpb);
    qkv_proj_mfma<<<dim3(1152), 256, 0, stream>>>(xn, xm, xr, wb, qkvb);
    flash_mfma   <<<dim3(960),  256, 0, stream>>>(qkvb, ybf, cand);
    prep_out     <<<dim3(1536), 256, 0, stream>>>(cand);
    out_proj_mfma<<<dim3(1152), 256, 0, stream>>>(ybf, cand, wpb, out);
}